// Round 1
// baseline (19503.448 us; speedup 1.0000x reference)
//
#include <hip/hip_runtime.h>

#define LEAKY(v) ((v) > 0.0f ? (v) : 0.01f * (v))

// ---------------- degree ----------------
__global__ void deg_kernel(const int* __restrict__ src, const int* __restrict__ dst,
                           float* __restrict__ deg_out, float* __restrict__ deg_in, int E) {
    int i = blockIdx.x * blockDim.x + threadIdx.x;
    int stride = gridDim.x * blockDim.x;
    for (; i < E; i += stride) {
        atomicAdd(&deg_out[src[i]], 1.0f);
        atomicAdd(&deg_in[dst[i]], 1.0f);
    }
}

__global__ void norm_kernel(const float* __restrict__ deg_out, const float* __restrict__ deg_in,
                            float* __restrict__ ns, float* __restrict__ nd, int n) {
    int i = blockIdx.x * blockDim.x + threadIdx.x;
    if (i < n) {
        float dov = deg_out[i];
        float div = deg_in[i];
        ns[i] = (dov > 0.0f) ? rsqrtf(fmaxf(dov, 1.0f)) : 0.0f;
        nd[i] = (div > 0.0f) ? rsqrtf(fmaxf(div, 1.0f)) : 0.0f;
    }
}

// ---------------- edge coefficient ----------------
__global__ void coef_kernel(const int* __restrict__ src, const float* __restrict__ edata,
                            const float* __restrict__ ns, const float* __restrict__ mu,
                            const float* __restrict__ sigma, float* __restrict__ coef, int E) {
    int i = blockIdx.x * blockDim.x + threadIdx.x;
    if (i < E) {
        float m = mu[0];
        float sg = sigma[0];
        float ed = edata[i];
        float d = ed - m;
        float w = (ed == 1.0f) ? ed : expf(-(d * d) / sg);
        coef[i] = ns[src[i]] * w;
    }
}

// ---------------- gather * coef, scatter-add ----------------
__global__ void scatter_kernel(const float* __restrict__ h, const int* __restrict__ src,
                               const int* __restrict__ dst, const float* __restrict__ coef,
                               float* __restrict__ agg, int E, int F) {
    long long total = (long long)E * F;
    long long stride = (long long)gridDim.x * blockDim.x;
    for (long long idx = (long long)blockIdx.x * blockDim.x + threadIdx.x; idx < total; idx += stride) {
        int e = (int)(idx / F);
        int f = (int)(idx - (long long)e * F);
        float v = h[(long long)src[e] * F + f] * coef[e];
        atomicAdd(&agg[(long long)dst[e] * F + f], v);
    }
}

// ---------------- (agg * nd) @ W + b, leaky relu ----------------
__global__ void matmul_kernel(const float* __restrict__ agg, const float* __restrict__ nd,
                              const float* __restrict__ W, const float* __restrict__ b,
                              float* __restrict__ out, int n, int fi, int fo) {
    long long total = (long long)n * fo;
    long long idx = (long long)blockIdx.x * blockDim.x + threadIdx.x;
    if (idx >= total) return;
    int i = (int)(idx / fo);
    int j = (int)(idx - (long long)i * fo);
    const float* arow = agg + (long long)i * fi;
    float s = 0.0f;
    for (int k = 0; k < fi; ++k) {
        s += arow[k] * W[(long long)k * fo + j];
    }
    float v = s * nd[i] + b[j];
    out[idx] = LEAKY(v);
}

// ---------------- mean over nodes (F=160) ----------------
__global__ void mean_kernel(const float* __restrict__ h, float* __restrict__ acc, int n, int F) {
    int f = threadIdx.x;   // blockDim.x == F (160)
    if (f >= F) return;
    float partial = 0.0f;
    for (int i = blockIdx.x; i < n; i += gridDim.x) {
        partial += h[(long long)i * F + f];
    }
    atomicAdd(&acc[f], partial);
}

// ---------------- head: mean -> leaky -> 160x140 -> leaky -> 140x2 -> sigmoid ----------------
__global__ void head_kernel(const float* __restrict__ acc, const float* __restrict__ Wd1,
                            const float* __restrict__ bd1, const float* __restrict__ Wd2,
                            const float* __restrict__ bd2, float* __restrict__ out, int n) {
    __shared__ float gm[160];
    __shared__ float h1[140];
    int tid = threadIdx.x;
    if (tid < 160) {
        float v = acc[tid] / (float)n;
        gm[tid] = LEAKY(v);
    }
    __syncthreads();
    if (tid < 140) {
        float s = bd1[tid];
        for (int k = 0; k < 160; ++k) s += gm[k] * Wd1[k * 140 + tid];
        h1[tid] = LEAKY(s);
    }
    __syncthreads();
    if (tid < 2) {
        float s = bd2[tid];
        for (int k = 0; k < 140; ++k) s += h1[k] * Wd2[k * 2 + tid];
        out[tid] = 1.0f / (1.0f + expf(-s));
    }
}

extern "C" void kernel_launch(void* const* d_in, const int* in_sizes, int n_in,
                              void* d_out, int out_size, void* d_ws, size_t ws_size,
                              hipStream_t stream) {
    static const int dims[12] = {64, 80, 160, 112, 160, 176, 96, 144, 96, 128, 96, 160};

    const float* x     = (const float*)d_in[0];
    const int*   src   = (const int*)d_in[1];
    const int*   dst   = (const int*)d_in[2];
    const float* edata = (const float*)d_in[3];
    const float* W[11];
    const float* B[11];
    for (int i = 0; i < 11; ++i) {
        W[i] = (const float*)d_in[4 + 2 * i];
        B[i] = (const float*)d_in[5 + 2 * i];
    }
    const float* Wd1   = (const float*)d_in[26];
    const float* bd1   = (const float*)d_in[27];
    const float* Wd2   = (const float*)d_in[28];
    const float* bd2   = (const float*)d_in[29];
    const float* mu    = (const float*)d_in[30];
    const float* sigma = (const float*)d_in[31];
    float* out = (float*)d_out;

    const int N = in_sizes[0] / 64;
    const int E = in_sizes[1];
    const int FMAX = 176;

    // workspace layout (floats)
    float* ws = (float*)d_ws;
    size_t o = 0;
    float* buf0   = ws + o; o += (size_t)N * FMAX;
    float* buf1   = ws + o; o += (size_t)N * FMAX;   // agg buffer
    float* buf2   = ws + o; o += (size_t)N * FMAX;
    float* coef   = ws + o; o += (size_t)E;
    float* degout = ws + o; o += (size_t)N;
    float* degin  = ws + o; o += (size_t)N;
    float* ns     = ws + o; o += (size_t)N;
    float* nd     = ws + o; o += (size_t)N;
    float* acc    = ws + o; o += 160;

    // degrees + norms + coef
    hipMemsetAsync(degout, 0, (size_t)N * sizeof(float), stream);
    hipMemsetAsync(degin, 0, (size_t)N * sizeof(float), stream);
    deg_kernel<<<(E + 255) / 256, 256, 0, stream>>>(src, dst, degout, degin, E);
    norm_kernel<<<(N + 255) / 256, 256, 0, stream>>>(degout, degin, ns, nd, N);
    coef_kernel<<<(E + 255) / 256, 256, 0, stream>>>(src, edata, ns, mu, sigma, coef, E);

    // 11 GCN layers
    const float* h = x;
    float* agg = buf1;
    float* ping = buf0;
    float* pong = buf2;
    for (int l = 0; l < 11; ++l) {
        int fi = dims[l];
        int fo = dims[l + 1];
        hipMemsetAsync(agg, 0, (size_t)N * fi * sizeof(float), stream);
        scatter_kernel<<<8192, 256, 0, stream>>>(h, src, dst, coef, agg, E, fi);
        long long total = (long long)N * fo;
        int blocks = (int)((total + 255) / 256);
        matmul_kernel<<<blocks, 256, 0, stream>>>(agg, nd, W[l], B[l], ping, N, fi, fo);
        h = ping;
        float* t = ping; ping = pong; pong = t;
    }

    // mean over nodes -> head
    hipMemsetAsync(acc, 0, 160 * sizeof(float), stream);
    mean_kernel<<<256, 160, 0, stream>>>(h, acc, N, 160);
    head_kernel<<<1, 256, 0, stream>>>(acc, Wd1, bd1, Wd2, bd2, out, N);
}

// Round 2
// 6700.758 us; speedup vs baseline: 2.9106x; 2.9106x over previous
//
#include <hip/hip_runtime.h>

#define LEAKY(v) ((v) > 0.0f ? (v) : 0.01f * (v))
#define SCAN_BLK 1024

// ---------------- degree (int) ----------------
__global__ void deg_kernel(const int* __restrict__ src, const int* __restrict__ dst,
                           int* __restrict__ deg_out, int* __restrict__ deg_in, int E) {
    int i = blockIdx.x * blockDim.x + threadIdx.x;
    if (i < E) {
        atomicAdd(&deg_out[src[i]], 1);
        atomicAdd(&deg_in[dst[i]], 1);
    }
}

__global__ void norm_kernel(const int* __restrict__ deg_out, const int* __restrict__ deg_in,
                            float* __restrict__ ns, float* __restrict__ nd, int n) {
    int i = blockIdx.x * blockDim.x + threadIdx.x;
    if (i < n) {
        float dov = (float)deg_out[i];
        float div = (float)deg_in[i];
        ns[i] = (dov > 0.0f) ? rsqrtf(fmaxf(dov, 1.0f)) : 0.0f;
        nd[i] = (div > 0.0f) ? rsqrtf(fmaxf(div, 1.0f)) : 0.0f;
    }
}

// ---------------- prefix scan (3-kernel) for row_ptr ----------------
__global__ void scan1_kernel(const int* __restrict__ deg, int* __restrict__ out,
                             int* __restrict__ bsums, int n) {
    __shared__ int sh[SCAN_BLK];
    int gid = blockIdx.x * SCAN_BLK + threadIdx.x;
    int v = (gid < n) ? deg[gid] : 0;
    sh[threadIdx.x] = v;
    __syncthreads();
    for (int off = 1; off < SCAN_BLK; off <<= 1) {
        int t = (threadIdx.x >= off) ? sh[threadIdx.x - off] : 0;
        __syncthreads();
        sh[threadIdx.x] += t;
        __syncthreads();
    }
    if (gid < n) out[gid + 1] = sh[threadIdx.x];       // inclusive, shifted
    if (threadIdx.x == SCAN_BLK - 1) bsums[blockIdx.x] = sh[threadIdx.x];
    if (gid == 0) out[0] = 0;
}

__global__ void scan2_kernel(int* __restrict__ bsums, int nb) {
    __shared__ int sh[SCAN_BLK];
    int v = (threadIdx.x < nb) ? bsums[threadIdx.x] : 0;
    sh[threadIdx.x] = v;
    __syncthreads();
    for (int off = 1; off < SCAN_BLK; off <<= 1) {
        int t = (threadIdx.x >= off) ? sh[threadIdx.x - off] : 0;
        __syncthreads();
        sh[threadIdx.x] += t;
        __syncthreads();
    }
    if (threadIdx.x < nb) bsums[threadIdx.x] = sh[threadIdx.x] - v;   // exclusive
}

__global__ void scan3_kernel(int* __restrict__ out, const int* __restrict__ bsums, int n) {
    int gid = blockIdx.x * SCAN_BLK + threadIdx.x;
    if (gid < n) out[gid + 1] += bsums[blockIdx.x];
}

__global__ void copy_kernel(const int* __restrict__ a, int* __restrict__ b, int n) {
    int i = blockIdx.x * blockDim.x + threadIdx.x;
    if (i < n) b[i] = a[i];
}

// ---------------- counting sort by dst, fusing coef computation ----------------
__global__ void sort_kernel(const int* __restrict__ src, const int* __restrict__ dst,
                            const float* __restrict__ edata, const float* __restrict__ ns,
                            const float* __restrict__ mu, const float* __restrict__ sigma,
                            int* __restrict__ cursor, int* __restrict__ src_s,
                            float* __restrict__ coef_s, int E) {
    int e = blockIdx.x * blockDim.x + threadIdx.x;
    if (e < E) {
        int d = dst[e];
        int pos = atomicAdd(&cursor[d], 1);
        int s = src[e];
        float ed = edata[e];
        float dd = ed - mu[0];
        float w = (ed == 1.0f) ? ed : expf(-(dd * dd) / sigma[0]);
        src_s[pos] = s;
        coef_s[pos] = ns[s] * w;
    }
}

// ---------------- CSR gather-sum aggregation (block per node) ----------------
// mode 0: out = agg            (pre-matmul ordering, A-order)
// mode 1: out = leaky(agg*nd + b)   (post-matmul ordering, B-order final)
__global__ void agg_kernel(const float* __restrict__ hsrc, const int* __restrict__ rowptr,
                           const int* __restrict__ srcs, const float* __restrict__ coefs,
                           const float* __restrict__ nd, const float* __restrict__ bias,
                           float* __restrict__ out, int F, int mode) {
    int i = blockIdx.x;
    int t = threadIdx.x;
    if (t >= F) return;
    int beg = rowptr[i];
    int end = rowptr[i + 1];
    float acc = 0.0f;
    for (int e = beg; e < end; ++e) {
        acc += hsrc[(long long)srcs[e] * F + t] * coefs[e];
    }
    if (mode) {
        float v = acc * nd[i] + bias[t];
        out[(long long)i * F + t] = LEAKY(v);
    } else {
        out[(long long)i * F + t] = acc;
    }
}

// ---------------- matmul: each thread 1 row x 4 cols ----------------
// mode 0: out = A @ W                      (no epilogue)
// mode 1: out = leaky((A @ W)*nd + b)      (fused epilogue)
__global__ void matmul_kernel(const float* __restrict__ A, const float* __restrict__ nd,
                              const float* __restrict__ W, const float* __restrict__ b,
                              float* __restrict__ out, int n, int fi, int fo, int mode) {
    int jt = fo >> 2;   // threads per row (fo divisible by 4)
    long long idx = (long long)blockIdx.x * blockDim.x + threadIdx.x;
    if (idx >= (long long)n * jt) return;
    int i = (int)(idx / jt);
    int j4 = (int)(idx - (long long)i * jt) << 2;
    const float* arow = A + (long long)i * fi;
    float sx = 0.f, sy = 0.f, sz = 0.f, sw = 0.f;
    for (int k = 0; k < fi; ++k) {
        float a = arow[k];
        const float4 w = *reinterpret_cast<const float4*>(&W[(long long)k * fo + j4]);
        sx += a * w.x; sy += a * w.y; sz += a * w.z; sw += a * w.w;
    }
    float4 r;
    if (mode) {
        float s = nd[i];
        float vx = sx * s + b[j4 + 0];
        float vy = sy * s + b[j4 + 1];
        float vz = sz * s + b[j4 + 2];
        float vw = sw * s + b[j4 + 3];
        r.x = LEAKY(vx); r.y = LEAKY(vy); r.z = LEAKY(vz); r.w = LEAKY(vw);
    } else {
        r.x = sx; r.y = sy; r.z = sz; r.w = sw;
    }
    *reinterpret_cast<float4*>(&out[(long long)i * fo + j4]) = r;
}

// ---------------- mean over nodes (F=160) ----------------
__global__ void mean_kernel(const float* __restrict__ h, float* __restrict__ acc, int n, int F) {
    int f = threadIdx.x;
    if (f >= F) return;
    float partial = 0.0f;
    for (int i = blockIdx.x; i < n; i += gridDim.x) {
        partial += h[(long long)i * F + f];
    }
    atomicAdd(&acc[f], partial);
}

// ---------------- head ----------------
__global__ void head_kernel(const float* __restrict__ acc, const float* __restrict__ Wd1,
                            const float* __restrict__ bd1, const float* __restrict__ Wd2,
                            const float* __restrict__ bd2, float* __restrict__ out, int n) {
    __shared__ float gm[160];
    __shared__ float h1[140];
    int tid = threadIdx.x;
    if (tid < 160) {
        float v = acc[tid] / (float)n;
        gm[tid] = LEAKY(v);
    }
    __syncthreads();
    if (tid < 140) {
        float s = bd1[tid];
        for (int k = 0; k < 160; ++k) s += gm[k] * Wd1[k * 140 + tid];
        h1[tid] = LEAKY(s);
    }
    __syncthreads();
    if (tid < 2) {
        float s = bd2[tid];
        for (int k = 0; k < 140; ++k) s += h1[k] * Wd2[k * 2 + tid];
        out[tid] = 1.0f / (1.0f + expf(-s));
    }
}

extern "C" void kernel_launch(void* const* d_in, const int* in_sizes, int n_in,
                              void* d_out, int out_size, void* d_ws, size_t ws_size,
                              hipStream_t stream) {
    static const int dims[12] = {64, 80, 160, 112, 160, 176, 96, 144, 96, 128, 96, 160};

    const float* x     = (const float*)d_in[0];
    const int*   src   = (const int*)d_in[1];
    const int*   dst   = (const int*)d_in[2];
    const float* edata = (const float*)d_in[3];
    const float* W[11];
    const float* B[11];
    for (int i = 0; i < 11; ++i) {
        W[i] = (const float*)d_in[4 + 2 * i];
        B[i] = (const float*)d_in[5 + 2 * i];
    }
    const float* Wd1   = (const float*)d_in[26];
    const float* bd1   = (const float*)d_in[27];
    const float* Wd2   = (const float*)d_in[28];
    const float* bd2   = (const float*)d_in[29];
    const float* mu    = (const float*)d_in[30];
    const float* sigma = (const float*)d_in[31];
    float* out = (float*)d_out;

    const int N = in_sizes[0] / 64;
    const int E = in_sizes[1];
    const int FMAX = 176;

    // workspace layout
    char* wsb = (char*)d_ws;
    size_t o = 0;
    auto alloc = [&](size_t bytes) { void* p = wsb + o; o += (bytes + 255) & ~(size_t)255; return p; };
    float* buf0    = (float*)alloc((size_t)N * FMAX * sizeof(float));
    float* buf1    = (float*)alloc((size_t)N * FMAX * sizeof(float));
    float* buf2    = (float*)alloc((size_t)N * FMAX * sizeof(float));
    int*   src_s   = (int*)  alloc((size_t)E * sizeof(int));
    float* coef_s  = (float*)alloc((size_t)E * sizeof(float));
    int*   rowptr  = (int*)  alloc((size_t)(N + 1) * sizeof(int));
    int*   cursor  = (int*)  alloc((size_t)N * sizeof(int));
    int*   degout  = (int*)  alloc((size_t)N * sizeof(int));
    int*   degin   = (int*)  alloc((size_t)N * sizeof(int));
    float* ns      = (float*)alloc((size_t)N * sizeof(float));
    float* nd      = (float*)alloc((size_t)N * sizeof(float));
    int*   bsums   = (int*)  alloc(2048 * sizeof(int));
    float* acc     = (float*)alloc(160 * sizeof(float));

    // ---- degrees, norms ----
    hipMemsetAsync(degout, 0, (size_t)N * sizeof(int), stream);
    hipMemsetAsync(degin, 0, (size_t)N * sizeof(int), stream);
    deg_kernel<<<(E + 255) / 256, 256, 0, stream>>>(src, dst, degout, degin, E);
    norm_kernel<<<(N + 255) / 256, 256, 0, stream>>>(degout, degin, ns, nd, N);

    // ---- CSR build: scan(deg_in) -> rowptr; counting sort by dst ----
    int nblk = (N + SCAN_BLK - 1) / SCAN_BLK;
    scan1_kernel<<<nblk, SCAN_BLK, 0, stream>>>(degin, rowptr, bsums, N);
    scan2_kernel<<<1, SCAN_BLK, 0, stream>>>(bsums, nblk);
    scan3_kernel<<<nblk, SCAN_BLK, 0, stream>>>(rowptr, bsums, N);
    copy_kernel<<<(N + 255) / 256, 256, 0, stream>>>(rowptr, cursor, N);
    sort_kernel<<<(E + 255) / 256, 256, 0, stream>>>(src, dst, edata, ns, mu, sigma,
                                                     cursor, src_s, coef_s, E);

    // ---- 11 GCN layers with agg/matmul reordering ----
    float* bufs[3] = {buf0, buf1, buf2};
    const float* h = x;
    for (int l = 0; l < 11; ++l) {
        int fi = dims[l];
        int fo = dims[l + 1];
        // pick two scratch buffers not aliasing h
        float* t1 = nullptr; float* t2 = nullptr;
        for (int q = 0; q < 3; ++q) {
            if ((const float*)bufs[q] == h) continue;
            if (!t1) t1 = bufs[q];
            else if (!t2) t2 = bufs[q];
        }
        if (fo >= fi) {
            // order A: aggregate at fi, then matmul with fused epilogue
            int bd = ((fi + 63) / 64) * 64;
            agg_kernel<<<N, bd, 0, stream>>>(h, rowptr, src_s, coef_s, nd, B[l], t1, fi, 0);
            long long tot = (long long)N * (fo >> 2);
            matmul_kernel<<<(int)((tot + 255) / 256), 256, 0, stream>>>(
                t1, nd, W[l], B[l], t2, N, fi, fo, 1);
        } else {
            // order B: matmul first (smaller fo), then aggregate with fused epilogue
            long long tot = (long long)N * (fo >> 2);
            matmul_kernel<<<(int)((tot + 255) / 256), 256, 0, stream>>>(
                h, nd, W[l], B[l], t1, N, fi, fo, 0);
            int bd = ((fo + 63) / 64) * 64;
            agg_kernel<<<N, bd, 0, stream>>>(t1, rowptr, src_s, coef_s, nd, B[l], t2, fo, 1);
        }
        h = t2;
    }

    // ---- mean over nodes -> head ----
    hipMemsetAsync(acc, 0, 160 * sizeof(float), stream);
    mean_kernel<<<256, 160, 0, stream>>>(h, acc, N, 160);
    head_kernel<<<1, 256, 0, stream>>>(acc, Wd1, bd1, Wd2, bd2, out, N);
}

// Round 3
// 5217.704 us; speedup vs baseline: 3.7379x; 1.2842x over previous
//
#include <hip/hip_runtime.h>

#define LEAKY(v) ((v) > 0.0f ? (v) : 0.01f * (v))
#define SCAN_BLK 1024

// ---------------- degree (int) ----------------
__global__ void deg_kernel(const int* __restrict__ src, const int* __restrict__ dst,
                           int* __restrict__ deg_out, int* __restrict__ deg_in, int E) {
    int i = blockIdx.x * blockDim.x + threadIdx.x;
    if (i < E) {
        atomicAdd(&deg_out[src[i]], 1);
        atomicAdd(&deg_in[dst[i]], 1);
    }
}

__global__ void norm_kernel(const int* __restrict__ deg_out, const int* __restrict__ deg_in,
                            float* __restrict__ ns, float* __restrict__ nd, int n) {
    int i = blockIdx.x * blockDim.x + threadIdx.x;
    if (i < n) {
        float dov = (float)deg_out[i];
        float div = (float)deg_in[i];
        ns[i] = (dov > 0.0f) ? rsqrtf(fmaxf(dov, 1.0f)) : 0.0f;
        nd[i] = (div > 0.0f) ? rsqrtf(fmaxf(div, 1.0f)) : 0.0f;
    }
}

// ---------------- prefix scan (3-kernel) for row_ptr ----------------
__global__ void scan1_kernel(const int* __restrict__ deg, int* __restrict__ out,
                             int* __restrict__ bsums, int n) {
    __shared__ int sh[SCAN_BLK];
    int gid = blockIdx.x * SCAN_BLK + threadIdx.x;
    int v = (gid < n) ? deg[gid] : 0;
    sh[threadIdx.x] = v;
    __syncthreads();
    for (int off = 1; off < SCAN_BLK; off <<= 1) {
        int t = (threadIdx.x >= off) ? sh[threadIdx.x - off] : 0;
        __syncthreads();
        sh[threadIdx.x] += t;
        __syncthreads();
    }
    if (gid < n) out[gid + 1] = sh[threadIdx.x];       // inclusive, shifted
    if (threadIdx.x == SCAN_BLK - 1) bsums[blockIdx.x] = sh[threadIdx.x];
    if (gid == 0) out[0] = 0;
}

__global__ void scan2_kernel(int* __restrict__ bsums, int nb) {
    __shared__ int sh[SCAN_BLK];
    int v = (threadIdx.x < nb) ? bsums[threadIdx.x] : 0;
    sh[threadIdx.x] = v;
    __syncthreads();
    for (int off = 1; off < SCAN_BLK; off <<= 1) {
        int t = (threadIdx.x >= off) ? sh[threadIdx.x - off] : 0;
        __syncthreads();
        sh[threadIdx.x] += t;
        __syncthreads();
    }
    if (threadIdx.x < nb) bsums[threadIdx.x] = sh[threadIdx.x] - v;   // exclusive
}

__global__ void scan3_kernel(int* __restrict__ out, const int* __restrict__ bsums, int n) {
    int gid = blockIdx.x * SCAN_BLK + threadIdx.x;
    if (gid < n) out[gid + 1] += bsums[blockIdx.x];
}

__global__ void copy_kernel(const int* __restrict__ a, int* __restrict__ b, int n) {
    int i = blockIdx.x * blockDim.x + threadIdx.x;
    if (i < n) b[i] = a[i];
}

// ---------------- counting sort by dst, fusing coef computation ----------------
__global__ void sort_kernel(const int* __restrict__ src, const int* __restrict__ dst,
                            const float* __restrict__ edata, const float* __restrict__ ns,
                            const float* __restrict__ mu, const float* __restrict__ sigma,
                            int* __restrict__ cursor, int* __restrict__ src_s,
                            float* __restrict__ coef_s, int E) {
    int e = blockIdx.x * blockDim.x + threadIdx.x;
    if (e < E) {
        int d = dst[e];
        int pos = atomicAdd(&cursor[d], 1);
        int s = src[e];
        float ed = edata[e];
        float dd = ed - mu[0];
        float w = (ed == 1.0f) ? ed : expf(-(dd * dd) / sigma[0]);
        src_s[pos] = s;
        coef_s[pos] = ns[s] * w;
    }
}

// ---------------- CSR gather-sum aggregation ----------------
// 256-thread block, split into ng groups of jt lanes; group g handles node
// blockIdx.x*ng+g; lane c covers features [4c, 4c+4). 4-way edge unroll for MLP.
// mode 0: out = agg
// mode 1: out = leaky(agg*nd + b)
__global__ void agg_kernel(const float* __restrict__ hsrc, const int* __restrict__ rowptr,
                           const int* __restrict__ srcs, const float* __restrict__ coefs,
                           const float* __restrict__ nd, const float* __restrict__ bias,
                           float* __restrict__ out, int n, int jt, int ng, int mode) {
    int g = threadIdx.x / jt;
    if (g >= ng) return;
    int c = (threadIdx.x - g * jt) << 2;     // feature offset
    int i = blockIdx.x * ng + g;
    if (i >= n) return;
    int F = jt << 2;
    int beg = rowptr[i];
    int end = rowptr[i + 1];
    float ax = 0.f, ay = 0.f, az = 0.f, aw = 0.f;
    int e = beg;
    for (; e + 4 <= end; e += 4) {
        int s0 = srcs[e + 0], s1 = srcs[e + 1], s2 = srcs[e + 2], s3 = srcs[e + 3];
        float c0 = coefs[e + 0], c1 = coefs[e + 1], c2 = coefs[e + 2], c3 = coefs[e + 3];
        float4 v0 = *reinterpret_cast<const float4*>(&hsrc[(size_t)s0 * F + c]);
        float4 v1 = *reinterpret_cast<const float4*>(&hsrc[(size_t)s1 * F + c]);
        float4 v2 = *reinterpret_cast<const float4*>(&hsrc[(size_t)s2 * F + c]);
        float4 v3 = *reinterpret_cast<const float4*>(&hsrc[(size_t)s3 * F + c]);
        ax += v0.x * c0 + v1.x * c1 + v2.x * c2 + v3.x * c3;
        ay += v0.y * c0 + v1.y * c1 + v2.y * c2 + v3.y * c3;
        az += v0.z * c0 + v1.z * c1 + v2.z * c2 + v3.z * c3;
        aw += v0.w * c0 + v1.w * c1 + v2.w * c2 + v3.w * c3;
    }
    for (; e < end; ++e) {
        int s0 = srcs[e];
        float c0 = coefs[e];
        float4 v0 = *reinterpret_cast<const float4*>(&hsrc[(size_t)s0 * F + c]);
        ax += v0.x * c0; ay += v0.y * c0; az += v0.z * c0; aw += v0.w * c0;
    }
    float4 r;
    if (mode) {
        float s = nd[i];
        float vx = ax * s + bias[c + 0];
        float vy = ay * s + bias[c + 1];
        float vz = az * s + bias[c + 2];
        float vw = aw * s + bias[c + 3];
        r.x = LEAKY(vx); r.y = LEAKY(vy); r.z = LEAKY(vz); r.w = LEAKY(vw);
    } else {
        r.x = ax; r.y = ay; r.z = az; r.w = aw;
    }
    *reinterpret_cast<float4*>(&out[(size_t)i * F + c]) = r;
}

// ---------------- matmul: each thread 1 row x 4 cols ----------------
// mode 0: out = A @ W
// mode 1: out = leaky((A @ W)*nd + b)
__global__ void matmul_kernel(const float* __restrict__ A, const float* __restrict__ nd,
                              const float* __restrict__ W, const float* __restrict__ b,
                              float* __restrict__ out, int n, int fi, int fo, int mode) {
    int jt = fo >> 2;   // threads per row (fo divisible by 4)
    long long idx = (long long)blockIdx.x * blockDim.x + threadIdx.x;
    if (idx >= (long long)n * jt) return;
    int i = (int)(idx / jt);
    int j4 = (int)(idx - (long long)i * jt) << 2;
    const float* arow = A + (long long)i * fi;
    float sx = 0.f, sy = 0.f, sz = 0.f, sw = 0.f;
    for (int k = 0; k < fi; ++k) {
        float a = arow[k];
        const float4 w = *reinterpret_cast<const float4*>(&W[(long long)k * fo + j4]);
        sx += a * w.x; sy += a * w.y; sz += a * w.z; sw += a * w.w;
    }
    float4 r;
    if (mode) {
        float s = nd[i];
        float vx = sx * s + b[j4 + 0];
        float vy = sy * s + b[j4 + 1];
        float vz = sz * s + b[j4 + 2];
        float vw = sw * s + b[j4 + 3];
        r.x = LEAKY(vx); r.y = LEAKY(vy); r.z = LEAKY(vz); r.w = LEAKY(vw);
    } else {
        r.x = sx; r.y = sy; r.z = sz; r.w = sw;
    }
    *reinterpret_cast<float4*>(&out[(long long)i * fo + j4]) = r;
}

// ---------------- mean over nodes (F=160) ----------------
__global__ void mean_kernel(const float* __restrict__ h, float* __restrict__ acc, int n, int F) {
    int f = threadIdx.x;
    if (f >= F) return;
    float partial = 0.0f;
    for (int i = blockIdx.x; i < n; i += gridDim.x) {
        partial += h[(long long)i * F + f];
    }
    atomicAdd(&acc[f], partial);
}

// ---------------- head ----------------
__global__ void head_kernel(const float* __restrict__ acc, const float* __restrict__ Wd1,
                            const float* __restrict__ bd1, const float* __restrict__ Wd2,
                            const float* __restrict__ bd2, float* __restrict__ out, int n) {
    __shared__ float gm[160];
    __shared__ float h1[140];
    int tid = threadIdx.x;
    if (tid < 160) {
        float v = acc[tid] / (float)n;
        gm[tid] = LEAKY(v);
    }
    __syncthreads();
    if (tid < 140) {
        float s = bd1[tid];
        for (int k = 0; k < 160; ++k) s += gm[k] * Wd1[k * 140 + tid];
        h1[tid] = LEAKY(s);
    }
    __syncthreads();
    if (tid < 2) {
        float s = bd2[tid];
        for (int k = 0; k < 140; ++k) s += h1[k] * Wd2[k * 2 + tid];
        out[tid] = 1.0f / (1.0f + expf(-s));
    }
}

extern "C" void kernel_launch(void* const* d_in, const int* in_sizes, int n_in,
                              void* d_out, int out_size, void* d_ws, size_t ws_size,
                              hipStream_t stream) {
    static const int dims[12] = {64, 80, 160, 112, 160, 176, 96, 144, 96, 128, 96, 160};

    const float* x     = (const float*)d_in[0];
    const int*   src   = (const int*)d_in[1];
    const int*   dst   = (const int*)d_in[2];
    const float* edata = (const float*)d_in[3];
    const float* W[11];
    const float* B[11];
    for (int i = 0; i < 11; ++i) {
        W[i] = (const float*)d_in[4 + 2 * i];
        B[i] = (const float*)d_in[5 + 2 * i];
    }
    const float* Wd1   = (const float*)d_in[26];
    const float* bd1   = (const float*)d_in[27];
    const float* Wd2   = (const float*)d_in[28];
    const float* bd2   = (const float*)d_in[29];
    const float* mu    = (const float*)d_in[30];
    const float* sigma = (const float*)d_in[31];
    float* out = (float*)d_out;

    const int N = in_sizes[0] / 64;
    const int E = in_sizes[1];
    const int FMAX = 176;

    // workspace layout
    char* wsb = (char*)d_ws;
    size_t o = 0;
    auto alloc = [&](size_t bytes) { void* p = wsb + o; o += (bytes + 255) & ~(size_t)255; return p; };
    float* buf0    = (float*)alloc((size_t)N * FMAX * sizeof(float));
    float* buf1    = (float*)alloc((size_t)N * FMAX * sizeof(float));
    float* buf2    = (float*)alloc((size_t)N * FMAX * sizeof(float));
    int*   src_s   = (int*)  alloc((size_t)E * sizeof(int));
    float* coef_s  = (float*)alloc((size_t)E * sizeof(float));
    int*   rowptr  = (int*)  alloc((size_t)(N + 1) * sizeof(int));
    int*   cursor  = (int*)  alloc((size_t)N * sizeof(int));
    int*   degout  = (int*)  alloc((size_t)N * sizeof(int));
    int*   degin   = (int*)  alloc((size_t)N * sizeof(int));
    float* ns      = (float*)alloc((size_t)N * sizeof(float));
    float* nd      = (float*)alloc((size_t)N * sizeof(float));
    int*   bsums   = (int*)  alloc(2048 * sizeof(int));
    float* acc     = (float*)alloc(160 * sizeof(float));

    // ---- degrees, norms ----
    hipMemsetAsync(degout, 0, (size_t)N * sizeof(int), stream);
    hipMemsetAsync(degin, 0, (size_t)N * sizeof(int), stream);
    deg_kernel<<<(E + 255) / 256, 256, 0, stream>>>(src, dst, degout, degin, E);
    norm_kernel<<<(N + 255) / 256, 256, 0, stream>>>(degout, degin, ns, nd, N);

    // ---- CSR build: scan(deg_in) -> rowptr; counting sort by dst ----
    int nblk = (N + SCAN_BLK - 1) / SCAN_BLK;
    scan1_kernel<<<nblk, SCAN_BLK, 0, stream>>>(degin, rowptr, bsums, N);
    scan2_kernel<<<1, SCAN_BLK, 0, stream>>>(bsums, nblk);
    scan3_kernel<<<nblk, SCAN_BLK, 0, stream>>>(rowptr, bsums, N);
    copy_kernel<<<(N + 255) / 256, 256, 0, stream>>>(rowptr, cursor, N);
    sort_kernel<<<(E + 255) / 256, 256, 0, stream>>>(src, dst, edata, ns, mu, sigma,
                                                     cursor, src_s, coef_s, E);

    // ---- 11 GCN layers with agg/matmul reordering ----
    float* bufs[3] = {buf0, buf1, buf2};
    const float* h = x;
    for (int l = 0; l < 11; ++l) {
        int fi = dims[l];
        int fo = dims[l + 1];
        // pick two scratch buffers not aliasing h
        float* t1 = nullptr; float* t2 = nullptr;
        for (int q = 0; q < 3; ++q) {
            if ((const float*)bufs[q] == h) continue;
            if (!t1) t1 = bufs[q];
            else if (!t2) t2 = bufs[q];
        }
        if (fo >= fi) {
            // order A: aggregate at fi, then matmul with fused epilogue
            int jt = fi >> 2;
            int ng = 256 / jt;
            agg_kernel<<<(N + ng - 1) / ng, 256, 0, stream>>>(
                h, rowptr, src_s, coef_s, nd, B[l], t1, N, jt, ng, 0);
            long long tot = (long long)N * (fo >> 2);
            matmul_kernel<<<(int)((tot + 255) / 256), 256, 0, stream>>>(
                t1, nd, W[l], B[l], t2, N, fi, fo, 1);
        } else {
            // order B: matmul first (smaller fo), then aggregate with fused epilogue
            long long tot = (long long)N * (fo >> 2);
            matmul_kernel<<<(int)((tot + 255) / 256), 256, 0, stream>>>(
                h, nd, W[l], B[l], t1, N, fi, fo, 0);
            int jt = fo >> 2;
            int ng = 256 / jt;
            agg_kernel<<<(N + ng - 1) / ng, 256, 0, stream>>>(
                t1, rowptr, src_s, coef_s, nd, B[l], t2, N, jt, ng, 1);
        }
        h = t2;
    }

    // ---- mean over nodes -> head ----
    hipMemsetAsync(acc, 0, 160 * sizeof(float), stream);
    mean_kernel<<<256, 160, 0, stream>>>(h, acc, N, 160);
    head_kernel<<<1, 256, 0, stream>>>(acc, Wd1, bd1, Wd2, bd2, out, N);
}

// Round 4
// 3209.353 us; speedup vs baseline: 6.0771x; 1.6258x over previous
//
#include <hip/hip_runtime.h>

#define LEAKY(v) ((v) > 0.0f ? (v) : 0.01f * (v))
#define SCAN_BLK 1024

// ---------------- degree (int) ----------------
__global__ void deg_kernel(const int* __restrict__ src, const int* __restrict__ dst,
                           int* __restrict__ deg_out, int* __restrict__ deg_in, int E) {
    int i = blockIdx.x * blockDim.x + threadIdx.x;
    if (i < E) {
        atomicAdd(&deg_out[src[i]], 1);
        atomicAdd(&deg_in[dst[i]], 1);
    }
}

__global__ void norm_kernel(const int* __restrict__ deg_out, const int* __restrict__ deg_in,
                            float* __restrict__ ns, float* __restrict__ nd, int n) {
    int i = blockIdx.x * blockDim.x + threadIdx.x;
    if (i < n) {
        float dov = (float)deg_out[i];
        float div = (float)deg_in[i];
        ns[i] = (dov > 0.0f) ? rsqrtf(fmaxf(dov, 1.0f)) : 0.0f;
        nd[i] = (div > 0.0f) ? rsqrtf(fmaxf(div, 1.0f)) : 0.0f;
    }
}

// ---------------- prefix scan (3-kernel) for row_ptr ----------------
__global__ void scan1_kernel(const int* __restrict__ deg, int* __restrict__ out,
                             int* __restrict__ bsums, int n) {
    __shared__ int sh[SCAN_BLK];
    int gid = blockIdx.x * SCAN_BLK + threadIdx.x;
    int v = (gid < n) ? deg[gid] : 0;
    sh[threadIdx.x] = v;
    __syncthreads();
    for (int off = 1; off < SCAN_BLK; off <<= 1) {
        int t = (threadIdx.x >= off) ? sh[threadIdx.x - off] : 0;
        __syncthreads();
        sh[threadIdx.x] += t;
        __syncthreads();
    }
    if (gid < n) out[gid + 1] = sh[threadIdx.x];       // inclusive, shifted
    if (threadIdx.x == SCAN_BLK - 1) bsums[blockIdx.x] = sh[threadIdx.x];
    if (gid == 0) out[0] = 0;
}

__global__ void scan2_kernel(int* __restrict__ bsums, int nb) {
    __shared__ int sh[SCAN_BLK];
    int v = (threadIdx.x < nb) ? bsums[threadIdx.x] : 0;
    sh[threadIdx.x] = v;
    __syncthreads();
    for (int off = 1; off < SCAN_BLK; off <<= 1) {
        int t = (threadIdx.x >= off) ? sh[threadIdx.x - off] : 0;
        __syncthreads();
        sh[threadIdx.x] += t;
        __syncthreads();
    }
    if (threadIdx.x < nb) bsums[threadIdx.x] = sh[threadIdx.x] - v;   // exclusive
}

__global__ void scan3_kernel(int* __restrict__ out, const int* __restrict__ bsums, int n) {
    int gid = blockIdx.x * SCAN_BLK + threadIdx.x;
    if (gid < n) out[gid + 1] += bsums[blockIdx.x];
}

__global__ void copy_kernel(const int* __restrict__ a, int* __restrict__ b, int n) {
    int i = blockIdx.x * blockDim.x + threadIdx.x;
    if (i < n) b[i] = a[i];
}

// ---------------- counting sort by dst, fusing coef computation ----------------
__global__ void sort_kernel(const int* __restrict__ src, const int* __restrict__ dst,
                            const float* __restrict__ edata, const float* __restrict__ ns,
                            const float* __restrict__ mu, const float* __restrict__ sigma,
                            int* __restrict__ cursor, int* __restrict__ src_s,
                            float* __restrict__ coef_s, int E) {
    int e = blockIdx.x * blockDim.x + threadIdx.x;
    if (e < E) {
        int d = dst[e];
        int pos = atomicAdd(&cursor[d], 1);
        int s = src[e];
        float ed = edata[e];
        float dd = ed - mu[0];
        float w = (ed == 1.0f) ? ed : expf(-(dd * dd) / sigma[0]);
        src_s[pos] = s;
        coef_s[pos] = ns[s] * w;
    }
}

// ---------------- CSR gather-sum aggregation ----------------
// 256-thread block, ng groups of jt lanes; group g -> node blockIdx.x*ng+g;
// lane c covers features [4c, 4c+4). 4-way edge unroll for MLP.
// mode 0: out = agg ; mode 1: out = leaky(agg*nd + b)
__global__ void agg_kernel(const float* __restrict__ hsrc, const int* __restrict__ rowptr,
                           const int* __restrict__ srcs, const float* __restrict__ coefs,
                           const float* __restrict__ nd, const float* __restrict__ bias,
                           float* __restrict__ out, int n, int jt, int ng, int mode) {
    int g = threadIdx.x / jt;
    if (g >= ng) return;
    int c = (threadIdx.x - g * jt) << 2;     // feature offset
    int i = blockIdx.x * ng + g;
    if (i >= n) return;
    int F = jt << 2;
    int beg = rowptr[i];
    int end = rowptr[i + 1];
    float ax = 0.f, ay = 0.f, az = 0.f, aw = 0.f;
    int e = beg;
    for (; e + 4 <= end; e += 4) {
        int s0 = srcs[e + 0], s1 = srcs[e + 1], s2 = srcs[e + 2], s3 = srcs[e + 3];
        float c0 = coefs[e + 0], c1 = coefs[e + 1], c2 = coefs[e + 2], c3 = coefs[e + 3];
        float4 v0 = *reinterpret_cast<const float4*>(&hsrc[(size_t)s0 * F + c]);
        float4 v1 = *reinterpret_cast<const float4*>(&hsrc[(size_t)s1 * F + c]);
        float4 v2 = *reinterpret_cast<const float4*>(&hsrc[(size_t)s2 * F + c]);
        float4 v3 = *reinterpret_cast<const float4*>(&hsrc[(size_t)s3 * F + c]);
        ax += v0.x * c0 + v1.x * c1 + v2.x * c2 + v3.x * c3;
        ay += v0.y * c0 + v1.y * c1 + v2.y * c2 + v3.y * c3;
        az += v0.z * c0 + v1.z * c1 + v2.z * c2 + v3.z * c3;
        aw += v0.w * c0 + v1.w * c1 + v2.w * c2 + v3.w * c3;
    }
    for (; e < end; ++e) {
        int s0 = srcs[e];
        float c0 = coefs[e];
        float4 v0 = *reinterpret_cast<const float4*>(&hsrc[(size_t)s0 * F + c]);
        ax += v0.x * c0; ay += v0.y * c0; az += v0.z * c0; aw += v0.w * c0;
    }
    float4 r;
    if (mode) {
        float s = nd[i];
        float vx = ax * s + bias[c + 0];
        float vy = ay * s + bias[c + 1];
        float vz = az * s + bias[c + 2];
        float vw = aw * s + bias[c + 3];
        r.x = LEAKY(vx); r.y = LEAKY(vy); r.z = LEAKY(vz); r.w = LEAKY(vw);
    } else {
        r.x = ax; r.y = ay; r.z = az; r.w = aw;
    }
    *reinterpret_cast<float4*>(&out[(size_t)i * F + c]) = r;
}

// ---------------- tiled matmul (templated on dims) ----------------
// BM=64 rows/block, BK=16. blockDim = 4*FO = 16 rowgroups x FO/4 colgroups.
// Each thread: 4 rows x 4 cols register accumulator.
// MODE 0: out = A @ W ; MODE 1: out = leaky((A@W)*nd + b)
template<int FI, int FO, int MODE>
__global__ __launch_bounds__(4 * FO) void mm_tile_kernel(
    const float* __restrict__ A, const float* __restrict__ nd,
    const float* __restrict__ W, const float* __restrict__ bias,
    float* __restrict__ out, int n)
{
    constexpr int BM = 64;
    constexpr int BK = 16;
    constexpr int APAD = 68;              // 64 + 4 pad (kills staging write conflicts)
    constexpr int CG = FO / 4;            // col groups
    __shared__ float As[BK][APAD];        // As[k][m] = A[row0+m][k0+k]
    __shared__ float Ws[BK][FO];

    const int t = threadIdx.x;
    const int row0 = blockIdx.x * BM;
    const int cg = t % CG;
    const int rg = t / CG;                // 0..15
    const int c0 = cg << 2;
    const int m0 = rg << 2;

    float acc[4][4] = {};

    for (int k0 = 0; k0 < FI; k0 += BK) {
        // stage A (threads 0..255): thread -> row m = t>>2, k-quad kq = (t&3)*4
        if (t < 256) {
            int m = t >> 2;
            int kq = (t & 3) << 2;
            int grow = row0 + m;
            float4 a;
            if (grow < n) a = *reinterpret_cast<const float4*>(&A[(size_t)grow * FI + k0 + kq]);
            else a = make_float4(0.f, 0.f, 0.f, 0.f);
            As[kq + 0][m] = a.x;
            As[kq + 1][m] = a.y;
            As[kq + 2][m] = a.z;
            As[kq + 3][m] = a.w;
        }
        // stage W (all 4*FO threads, exactly one float4 each)
        {
            int k = t / CG;
            int cq = (t % CG) << 2;
            *reinterpret_cast<float4*>(&Ws[k][cq]) =
                *reinterpret_cast<const float4*>(&W[(size_t)(k0 + k) * FO + cq]);
        }
        __syncthreads();
        #pragma unroll
        for (int k = 0; k < BK; ++k) {
            float4 a = *reinterpret_cast<const float4*>(&As[k][m0]);
            float4 w = *reinterpret_cast<const float4*>(&Ws[k][c0]);
            acc[0][0] += a.x * w.x; acc[0][1] += a.x * w.y; acc[0][2] += a.x * w.z; acc[0][3] += a.x * w.w;
            acc[1][0] += a.y * w.x; acc[1][1] += a.y * w.y; acc[1][2] += a.y * w.z; acc[1][3] += a.y * w.w;
            acc[2][0] += a.z * w.x; acc[2][1] += a.z * w.y; acc[2][2] += a.z * w.z; acc[2][3] += a.z * w.w;
            acc[3][0] += a.w * w.x; acc[3][1] += a.w * w.y; acc[3][2] += a.w * w.z; acc[3][3] += a.w * w.w;
        }
        __syncthreads();
    }

    #pragma unroll
    for (int r = 0; r < 4; ++r) {
        int grow = row0 + m0 + r;
        if (grow < n) {
            float4 v;
            if (MODE) {
                float s = nd[grow];
                float vx = acc[r][0] * s + bias[c0 + 0];
                float vy = acc[r][1] * s + bias[c0 + 1];
                float vz = acc[r][2] * s + bias[c0 + 2];
                float vw = acc[r][3] * s + bias[c0 + 3];
                v.x = LEAKY(vx); v.y = LEAKY(vy); v.z = LEAKY(vz); v.w = LEAKY(vw);
            } else {
                v.x = acc[r][0]; v.y = acc[r][1]; v.z = acc[r][2]; v.w = acc[r][3];
            }
            *reinterpret_cast<float4*>(&out[(size_t)grow * FO + c0]) = v;
        }
    }
}

// ---------------- mean over nodes (F=160) ----------------
__global__ void mean_kernel(const float* __restrict__ h, float* __restrict__ acc, int n, int F) {
    int f = threadIdx.x;
    if (f >= F) return;
    float partial = 0.0f;
    for (int i = blockIdx.x; i < n; i += gridDim.x) {
        partial += h[(long long)i * F + f];
    }
    atomicAdd(&acc[f], partial);
}

// ---------------- head ----------------
__global__ void head_kernel(const float* __restrict__ acc, const float* __restrict__ Wd1,
                            const float* __restrict__ bd1, const float* __restrict__ Wd2,
                            const float* __restrict__ bd2, float* __restrict__ out, int n) {
    __shared__ float gm[160];
    __shared__ float h1[140];
    int tid = threadIdx.x;
    if (tid < 160) {
        float v = acc[tid] / (float)n;
        gm[tid] = LEAKY(v);
    }
    __syncthreads();
    if (tid < 140) {
        float s = bd1[tid];
        for (int k = 0; k < 160; ++k) s += gm[k] * Wd1[k * 140 + tid];
        h1[tid] = LEAKY(s);
    }
    __syncthreads();
    if (tid < 2) {
        float s = bd2[tid];
        for (int k = 0; k < 140; ++k) s += h1[k] * Wd2[k * 2 + tid];
        out[tid] = 1.0f / (1.0f + expf(-s));
    }
}

extern "C" void kernel_launch(void* const* d_in, const int* in_sizes, int n_in,
                              void* d_out, int out_size, void* d_ws, size_t ws_size,
                              hipStream_t stream) {
    const float* x     = (const float*)d_in[0];
    const int*   src   = (const int*)d_in[1];
    const int*   dst   = (const int*)d_in[2];
    const float* edata = (const float*)d_in[3];
    const float* W[11];
    const float* B[11];
    for (int i = 0; i < 11; ++i) {
        W[i] = (const float*)d_in[4 + 2 * i];
        B[i] = (const float*)d_in[5 + 2 * i];
    }
    const float* Wd1   = (const float*)d_in[26];
    const float* bd1   = (const float*)d_in[27];
    const float* Wd2   = (const float*)d_in[28];
    const float* bd2   = (const float*)d_in[29];
    const float* mu    = (const float*)d_in[30];
    const float* sigma = (const float*)d_in[31];
    float* out = (float*)d_out;

    const int N = in_sizes[0] / 64;
    const int E = in_sizes[1];
    const int FMAX = 176;

    // workspace layout
    char* wsb = (char*)d_ws;
    size_t o = 0;
    auto alloc = [&](size_t bytes) { void* p = wsb + o; o += (bytes + 255) & ~(size_t)255; return p; };
    float* buf0    = (float*)alloc((size_t)N * FMAX * sizeof(float));
    float* buf1    = (float*)alloc((size_t)N * FMAX * sizeof(float));
    float* buf2    = (float*)alloc((size_t)N * FMAX * sizeof(float));
    int*   src_s   = (int*)  alloc((size_t)E * sizeof(int));
    float* coef_s  = (float*)alloc((size_t)E * sizeof(float));
    int*   rowptr  = (int*)  alloc((size_t)(N + 1) * sizeof(int));
    int*   cursor  = (int*)  alloc((size_t)N * sizeof(int));
    int*   degout  = (int*)  alloc((size_t)N * sizeof(int));
    int*   degin   = (int*)  alloc((size_t)N * sizeof(int));
    float* ns      = (float*)alloc((size_t)N * sizeof(float));
    float* nd      = (float*)alloc((size_t)N * sizeof(float));
    int*   bsums   = (int*)  alloc(2048 * sizeof(int));
    float* acc     = (float*)alloc(160 * sizeof(float));

    // ---- degrees, norms ----
    hipMemsetAsync(degout, 0, (size_t)N * sizeof(int), stream);
    hipMemsetAsync(degin, 0, (size_t)N * sizeof(int), stream);
    deg_kernel<<<(E + 255) / 256, 256, 0, stream>>>(src, dst, degout, degin, E);
    norm_kernel<<<(N + 255) / 256, 256, 0, stream>>>(degout, degin, ns, nd, N);

    // ---- CSR build ----
    int nblk = (N + SCAN_BLK - 1) / SCAN_BLK;
    scan1_kernel<<<nblk, SCAN_BLK, 0, stream>>>(degin, rowptr, bsums, N);
    scan2_kernel<<<1, SCAN_BLK, 0, stream>>>(bsums, nblk);
    scan3_kernel<<<nblk, SCAN_BLK, 0, stream>>>(rowptr, bsums, N);
    copy_kernel<<<(N + 255) / 256, 256, 0, stream>>>(rowptr, cursor, N);
    sort_kernel<<<(E + 255) / 256, 256, 0, stream>>>(src, dst, edata, ns, mu, sigma,
                                                     cursor, src_s, coef_s, E);

    // ---- 11 GCN layers ----
    float* bufs[3] = {buf0, buf1, buf2};
    const float* h = x;
    const int mmgrid = (N + 63) / 64;

    auto pick = [&](const float* hh, float*& t1, float*& t2) {
        t1 = nullptr; t2 = nullptr;
        for (int q = 0; q < 3; ++q) {
            if ((const float*)bufs[q] == hh) continue;
            if (!t1) t1 = bufs[q];
            else if (!t2) t2 = bufs[q];
        }
    };

    // order A: agg at FI, then mm with fused epilogue (FO >= FI)
    #define DO_A(FI, FO, l) { \
        float *t1, *t2; pick(h, t1, t2); \
        constexpr int jt = FI / 4; constexpr int ng = 256 / jt; \
        agg_kernel<<<(N + ng - 1) / ng, 256, 0, stream>>>( \
            h, rowptr, src_s, coef_s, nd, B[l], t1, N, jt, ng, 0); \
        mm_tile_kernel<FI, FO, 1><<<mmgrid, 4 * FO, 0, stream>>>( \
            t1, nd, W[l], B[l], t2, N); \
        h = t2; }

    // order B: mm first (FO < FI), then agg with fused epilogue
    #define DO_B(FI, FO, l) { \
        float *t1, *t2; pick(h, t1, t2); \
        mm_tile_kernel<FI, FO, 0><<<mmgrid, 4 * FO, 0, stream>>>( \
            h, nd, W[l], B[l], t1, N); \
        constexpr int jt = FO / 4; constexpr int ng = 256 / jt; \
        agg_kernel<<<(N + ng - 1) / ng, 256, 0, stream>>>( \
            t1, rowptr, src_s, coef_s, nd, B[l], t2, N, jt, ng, 1); \
        h = t2; }

    DO_A(64, 80, 0)
    DO_A(80, 160, 1)
    DO_B(160, 112, 2)
    DO_A(112, 160, 3)
    DO_A(160, 176, 4)
    DO_B(176, 96, 5)
    DO_A(96, 144, 6)
    DO_B(144, 96, 7)
    DO_A(96, 128, 8)
    DO_B(128, 96, 9)
    DO_A(96, 160, 10)

    #undef DO_A
    #undef DO_B

    // ---- mean over nodes -> head ----
    hipMemsetAsync(acc, 0, 160 * sizeof(float), stream);
    mean_kernel<<<256, 160, 0, stream>>>(h, acc, N, 160);
    head_kernel<<<1, 256, 0, stream>>>(acc, Wd1, bd1, Wd2, bd2, out, N);
}

// Round 5
// 2501.190 us; speedup vs baseline: 7.7977x; 1.2831x over previous
//
#include <hip/hip_runtime.h>

#define LEAKY(v) ((v) > 0.0f ? (v) : 0.01f * (v))
#define SCAN_BLK 1024

// ---------------- bf16 helpers (RNE) ----------------
__device__ inline float bflo(unsigned int u) { return __uint_as_float(u << 16); }
__device__ inline float bfhi(unsigned int u) { return __uint_as_float(u & 0xFFFF0000u); }
__device__ inline unsigned int pack2bf(float lo, float hi) {
    unsigned int a = __float_as_uint(lo);
    unsigned int b = __float_as_uint(hi);
    a = (a + 0x7FFFu + ((a >> 16) & 1u)) >> 16;
    b = (b + 0x7FFFu + ((b >> 16) & 1u)) & 0xFFFF0000u;
    return a | b;
}
__device__ inline unsigned short f2bf(float f) {
    unsigned int u = __float_as_uint(f);
    return (unsigned short)((u + 0x7FFFu + ((u >> 16) & 1u)) >> 16);
}

// ---------------- degree (int) ----------------
__global__ void deg_kernel(const int* __restrict__ src, const int* __restrict__ dst,
                           int* __restrict__ deg_out, int* __restrict__ deg_in, int E) {
    int i = blockIdx.x * blockDim.x + threadIdx.x;
    if (i < E) {
        atomicAdd(&deg_out[src[i]], 1);
        atomicAdd(&deg_in[dst[i]], 1);
    }
}

__global__ void norm_kernel(const int* __restrict__ deg_out, const int* __restrict__ deg_in,
                            float* __restrict__ ns, float* __restrict__ nd, int n) {
    int i = blockIdx.x * blockDim.x + threadIdx.x;
    if (i < n) {
        float dov = (float)deg_out[i];
        float div = (float)deg_in[i];
        ns[i] = (dov > 0.0f) ? rsqrtf(fmaxf(dov, 1.0f)) : 0.0f;
        nd[i] = (div > 0.0f) ? rsqrtf(fmaxf(div, 1.0f)) : 0.0f;
    }
}

// ---------------- prefix scan (3-kernel) for row_ptr ----------------
__global__ void scan1_kernel(const int* __restrict__ deg, int* __restrict__ out,
                             int* __restrict__ bsums, int n) {
    __shared__ int sh[SCAN_BLK];
    int gid = blockIdx.x * SCAN_BLK + threadIdx.x;
    int v = (gid < n) ? deg[gid] : 0;
    sh[threadIdx.x] = v;
    __syncthreads();
    for (int off = 1; off < SCAN_BLK; off <<= 1) {
        int t = (threadIdx.x >= off) ? sh[threadIdx.x - off] : 0;
        __syncthreads();
        sh[threadIdx.x] += t;
        __syncthreads();
    }
    if (gid < n) out[gid + 1] = sh[threadIdx.x];
    if (threadIdx.x == SCAN_BLK - 1) bsums[blockIdx.x] = sh[threadIdx.x];
    if (gid == 0) out[0] = 0;
}

__global__ void scan2_kernel(int* __restrict__ bsums, int nb) {
    __shared__ int sh[SCAN_BLK];
    int v = (threadIdx.x < nb) ? bsums[threadIdx.x] : 0;
    sh[threadIdx.x] = v;
    __syncthreads();
    for (int off = 1; off < SCAN_BLK; off <<= 1) {
        int t = (threadIdx.x >= off) ? sh[threadIdx.x - off] : 0;
        __syncthreads();
        sh[threadIdx.x] += t;
        __syncthreads();
    }
    if (threadIdx.x < nb) bsums[threadIdx.x] = sh[threadIdx.x] - v;
}

__global__ void scan3_kernel(int* __restrict__ out, const int* __restrict__ bsums, int n) {
    int gid = blockIdx.x * SCAN_BLK + threadIdx.x;
    if (gid < n) out[gid + 1] += bsums[blockIdx.x];
}

__global__ void copy_kernel(const int* __restrict__ a, int* __restrict__ b, int n) {
    int i = blockIdx.x * blockDim.x + threadIdx.x;
    if (i < n) b[i] = a[i];
}

// ---------------- counting sort by dst, fused coef; packed (src, coef) ----------------
__global__ void sort_kernel(const int* __restrict__ src, const int* __restrict__ dst,
                            const float* __restrict__ edata, const float* __restrict__ ns,
                            const float* __restrict__ mu, const float* __restrict__ sigma,
                            int* __restrict__ cursor, int2* __restrict__ es, int E) {
    int e = blockIdx.x * blockDim.x + threadIdx.x;
    if (e < E) {
        int d = dst[e];
        int pos = atomicAdd(&cursor[d], 1);
        int s = src[e];
        float ed = edata[e];
        float dd = ed - mu[0];
        float w = (ed == 1.0f) ? ed : expf(-(dd * dd) / sigma[0]);
        es[pos] = make_int2(s, __float_as_int(ns[s] * w));
    }
}

// ---------------- x -> bf16 ----------------
__global__ void x2bf_kernel(const float* __restrict__ x, unsigned short* __restrict__ o,
                            long long total4) {
    long long i = (long long)blockIdx.x * blockDim.x + threadIdx.x;
    if (i < total4) {
        float4 v = *reinterpret_cast<const float4*>(&x[i * 4]);
        uint2 p;
        p.x = pack2bf(v.x, v.y);
        p.y = pack2bf(v.z, v.w);
        *reinterpret_cast<uint2*>(&o[i * 4]) = p;
    }
}

// ---------------- CSR gather-sum aggregation (bf16 in) ----------------
// 256-thread block, ng groups of jt lanes; lane covers 8 features (uint4 = 8 bf16).
// MODE 0: out32 = agg (fp32) ; MODE 1: out16 = bf16(leaky(agg*nd + b))
#define FMA8(v, cc) \
    a0 = fmaf(bflo((v).x), cc, a0); a1 = fmaf(bfhi((v).x), cc, a1); \
    a2 = fmaf(bflo((v).y), cc, a2); a3 = fmaf(bfhi((v).y), cc, a3); \
    a4 = fmaf(bflo((v).z), cc, a4); a5 = fmaf(bfhi((v).z), cc, a5); \
    a6 = fmaf(bflo((v).w), cc, a6); a7 = fmaf(bfhi((v).w), cc, a7);

template<int MODE>
__global__ void agg_kernel(const unsigned short* __restrict__ hb,
                           const int* __restrict__ rowptr, const int2* __restrict__ es,
                           const float* __restrict__ nd, const float* __restrict__ bias,
                           float* __restrict__ out32, unsigned short* __restrict__ out16,
                           int n, int jt, int ng) {
    int g = threadIdx.x / jt;
    if (g >= ng) return;
    int i = blockIdx.x * ng + g;
    if (i >= n) return;
    int c = (threadIdx.x - g * jt) << 3;   // feature offset (8 per lane)
    int F = jt << 3;
    int beg = rowptr[i], end = rowptr[i + 1];
    float a0 = 0, a1 = 0, a2 = 0, a3 = 0, a4 = 0, a5 = 0, a6 = 0, a7 = 0;
    int e = beg;
    for (; e + 4 <= end; e += 4) {
        int2 e0 = es[e + 0], e1 = es[e + 1], e2 = es[e + 2], e3 = es[e + 3];
        uint4 v0 = *reinterpret_cast<const uint4*>(&hb[(size_t)e0.x * F + c]);
        uint4 v1 = *reinterpret_cast<const uint4*>(&hb[(size_t)e1.x * F + c]);
        uint4 v2 = *reinterpret_cast<const uint4*>(&hb[(size_t)e2.x * F + c]);
        uint4 v3 = *reinterpret_cast<const uint4*>(&hb[(size_t)e3.x * F + c]);
        float c0 = __int_as_float(e0.y), c1 = __int_as_float(e1.y);
        float c2 = __int_as_float(e2.y), c3 = __int_as_float(e3.y);
        FMA8(v0, c0)
        FMA8(v1, c1)
        FMA8(v2, c2)
        FMA8(v3, c3)
    }
    for (; e < end; ++e) {
        int2 e0 = es[e];
        uint4 v0 = *reinterpret_cast<const uint4*>(&hb[(size_t)e0.x * F + c]);
        float c0 = __int_as_float(e0.y);
        FMA8(v0, c0)
    }
    if (MODE) {
        float s = nd[i];
        float b0 = a0 * s + bias[c + 0]; b0 = LEAKY(b0);
        float b1 = a1 * s + bias[c + 1]; b1 = LEAKY(b1);
        float b2 = a2 * s + bias[c + 2]; b2 = LEAKY(b2);
        float b3 = a3 * s + bias[c + 3]; b3 = LEAKY(b3);
        float b4 = a4 * s + bias[c + 4]; b4 = LEAKY(b4);
        float b5 = a5 * s + bias[c + 5]; b5 = LEAKY(b5);
        float b6 = a6 * s + bias[c + 6]; b6 = LEAKY(b6);
        float b7 = a7 * s + bias[c + 7]; b7 = LEAKY(b7);
        uint4 p;
        p.x = pack2bf(b0, b1); p.y = pack2bf(b2, b3);
        p.z = pack2bf(b4, b5); p.w = pack2bf(b6, b7);
        *reinterpret_cast<uint4*>(&out16[(size_t)i * F + c]) = p;
    } else {
        *reinterpret_cast<float4*>(&out32[(size_t)i * F + c]) = make_float4(a0, a1, a2, a3);
        *reinterpret_cast<float4*>(&out32[(size_t)i * F + c + 4]) = make_float4(a4, a5, a6, a7);
    }
}

// ---------------- tiled matmul (templated) ----------------
// BM=64, BK=16, blockDim = 4*FO. Output always bf16.
// ABF: A operand dtype (0=fp32, 1=bf16). MODE 1: fused leaky((A@W)*nd+b).
template<int FI, int FO, int MODE, int ABF>
__global__ __launch_bounds__(4 * FO) void mm_tile_kernel(
    const float* __restrict__ Af, const unsigned short* __restrict__ Ab,
    const float* __restrict__ nd, const float* __restrict__ W,
    const float* __restrict__ bias, unsigned short* __restrict__ out, int n)
{
    constexpr int BM = 64;
    constexpr int BK = 16;
    constexpr int APAD = 68;
    constexpr int CG = FO / 4;
    __shared__ float As[BK][APAD];
    __shared__ float Ws[BK][FO];

    const int t = threadIdx.x;
    const int row0 = blockIdx.x * BM;
    const int cg = t % CG;
    const int rg = t / CG;
    const int c0 = cg << 2;
    const int m0 = rg << 2;

    float acc[4][4] = {};

    for (int k0 = 0; k0 < FI; k0 += BK) {
        if (t < 256) {
            int m = t >> 2;
            int kq = (t & 3) << 2;
            int grow = row0 + m;
            float4 a;
            if (grow < n) {
                if (ABF) {
                    uint2 u = *reinterpret_cast<const uint2*>(&Ab[(size_t)grow * FI + k0 + kq]);
                    a.x = bflo(u.x); a.y = bfhi(u.x); a.z = bflo(u.y); a.w = bfhi(u.y);
                } else {
                    a = *reinterpret_cast<const float4*>(&Af[(size_t)grow * FI + k0 + kq]);
                }
            } else a = make_float4(0.f, 0.f, 0.f, 0.f);
            As[kq + 0][m] = a.x;
            As[kq + 1][m] = a.y;
            As[kq + 2][m] = a.z;
            As[kq + 3][m] = a.w;
        }
        {
            int k = t / CG;
            int cq = (t % CG) << 2;
            *reinterpret_cast<float4*>(&Ws[k][cq]) =
                *reinterpret_cast<const float4*>(&W[(size_t)(k0 + k) * FO + cq]);
        }
        __syncthreads();
        #pragma unroll
        for (int k = 0; k < BK; ++k) {
            float4 a = *reinterpret_cast<const float4*>(&As[k][m0]);
            float4 w = *reinterpret_cast<const float4*>(&Ws[k][c0]);
            acc[0][0] += a.x * w.x; acc[0][1] += a.x * w.y; acc[0][2] += a.x * w.z; acc[0][3] += a.x * w.w;
            acc[1][0] += a.y * w.x; acc[1][1] += a.y * w.y; acc[1][2] += a.y * w.z; acc[1][3] += a.y * w.w;
            acc[2][0] += a.z * w.x; acc[2][1] += a.z * w.y; acc[2][2] += a.z * w.z; acc[2][3] += a.z * w.w;
            acc[3][0] += a.w * w.x; acc[3][1] += a.w * w.y; acc[3][2] += a.w * w.z; acc[3][3] += a.w * w.w;
        }
        __syncthreads();
    }

    #pragma unroll
    for (int r = 0; r < 4; ++r) {
        int grow = row0 + m0 + r;
        if (grow < n) {
            float vx, vy, vz, vw;
            if (MODE) {
                float s = nd[grow];
                vx = acc[r][0] * s + bias[c0 + 0]; vx = LEAKY(vx);
                vy = acc[r][1] * s + bias[c0 + 1]; vy = LEAKY(vy);
                vz = acc[r][2] * s + bias[c0 + 2]; vz = LEAKY(vz);
                vw = acc[r][3] * s + bias[c0 + 3]; vw = LEAKY(vw);
            } else {
                vx = acc[r][0]; vy = acc[r][1]; vz = acc[r][2]; vw = acc[r][3];
            }
            uint2 p;
            p.x = pack2bf(vx, vy);
            p.y = pack2bf(vz, vw);
            *reinterpret_cast<uint2*>(&out[(size_t)grow * FO + c0]) = p;
        }
    }
}

// ---------------- mean over nodes (bf16 in, F=160) ----------------
__global__ void mean_kernel(const unsigned short* __restrict__ h, float* __restrict__ acc,
                            int n, int F) {
    int f = threadIdx.x;
    if (f >= F) return;
    float partial = 0.0f;
    for (int i = blockIdx.x; i < n; i += gridDim.x) {
        partial += __uint_as_float(((unsigned int)h[(size_t)i * F + f]) << 16);
    }
    atomicAdd(&acc[f], partial);
}

// ---------------- head ----------------
__global__ void head_kernel(const float* __restrict__ acc, const float* __restrict__ Wd1,
                            const float* __restrict__ bd1, const float* __restrict__ Wd2,
                            const float* __restrict__ bd2, float* __restrict__ out, int n) {
    __shared__ float gm[160];
    __shared__ float h1[140];
    int tid = threadIdx.x;
    if (tid < 160) {
        float v = acc[tid] / (float)n;
        gm[tid] = LEAKY(v);
    }
    __syncthreads();
    if (tid < 140) {
        float s = bd1[tid];
        for (int k = 0; k < 160; ++k) s += gm[k] * Wd1[k * 140 + tid];
        h1[tid] = LEAKY(s);
    }
    __syncthreads();
    if (tid < 2) {
        float s = bd2[tid];
        for (int k = 0; k < 140; ++k) s += h1[k] * Wd2[k * 2 + tid];
        out[tid] = 1.0f / (1.0f + expf(-s));
    }
}

extern "C" void kernel_launch(void* const* d_in, const int* in_sizes, int n_in,
                              void* d_out, int out_size, void* d_ws, size_t ws_size,
                              hipStream_t stream) {
    const float* x     = (const float*)d_in[0];
    const int*   src   = (const int*)d_in[1];
    const int*   dst   = (const int*)d_in[2];
    const float* edata = (const float*)d_in[3];
    const float* W[11];
    const float* B[11];
    for (int i = 0; i < 11; ++i) {
        W[i] = (const float*)d_in[4 + 2 * i];
        B[i] = (const float*)d_in[5 + 2 * i];
    }
    const float* Wd1   = (const float*)d_in[26];
    const float* bd1   = (const float*)d_in[27];
    const float* Wd2   = (const float*)d_in[28];
    const float* bd2   = (const float*)d_in[29];
    const float* mu    = (const float*)d_in[30];
    const float* sigma = (const float*)d_in[31];
    float* out = (float*)d_out;

    const int N = in_sizes[0] / 64;
    const int E = in_sizes[1];
    const int FMAX = 176;

    // workspace layout
    char* wsb = (char*)d_ws;
    size_t o = 0;
    auto alloc = [&](size_t bytes) { void* p = wsb + o; o += (bytes + 255) & ~(size_t)255; return p; };
    unsigned short* hb0 = (unsigned short*)alloc((size_t)N * FMAX * 2);
    unsigned short* hb1 = (unsigned short*)alloc((size_t)N * FMAX * 2);
    float* t32     = (float*)alloc((size_t)N * FMAX * sizeof(float));
    int2*  es      = (int2*) alloc((size_t)E * sizeof(int2));
    int*   rowptr  = (int*)  alloc((size_t)(N + 1) * sizeof(int));
    int*   cursor  = (int*)  alloc((size_t)N * sizeof(int));
    int*   degout  = (int*)  alloc((size_t)N * sizeof(int));
    int*   degin   = (int*)  alloc((size_t)N * sizeof(int));
    float* ns      = (float*)alloc((size_t)N * sizeof(float));
    float* nd      = (float*)alloc((size_t)N * sizeof(float));
    int*   bsums   = (int*)  alloc(2048 * sizeof(int));
    float* acc     = (float*)alloc(160 * sizeof(float));

    // ---- degrees, norms ----
    hipMemsetAsync(degout, 0, (size_t)N * sizeof(int), stream);
    hipMemsetAsync(degin, 0, (size_t)N * sizeof(int), stream);
    deg_kernel<<<(E + 255) / 256, 256, 0, stream>>>(src, dst, degout, degin, E);
    norm_kernel<<<(N + 255) / 256, 256, 0, stream>>>(degout, degin, ns, nd, N);

    // ---- CSR build ----
    int nblk = (N + SCAN_BLK - 1) / SCAN_BLK;
    scan1_kernel<<<nblk, SCAN_BLK, 0, stream>>>(degin, rowptr, bsums, N);
    scan2_kernel<<<1, SCAN_BLK, 0, stream>>>(bsums, nblk);
    scan3_kernel<<<nblk, SCAN_BLK, 0, stream>>>(rowptr, bsums, N);
    copy_kernel<<<(N + 255) / 256, 256, 0, stream>>>(rowptr, cursor, N);
    sort_kernel<<<(E + 255) / 256, 256, 0, stream>>>(src, dst, edata, ns, mu, sigma,
                                                     cursor, es, E);

    // ---- x -> bf16 ----
    long long x4 = (long long)N * 64 / 4;
    x2bf_kernel<<<(int)((x4 + 255) / 256), 256, 0, stream>>>(x, hb0, x4);

    // ---- 11 GCN layers ----
    unsigned short* hcur = hb0;
    unsigned short* halt = hb1;
    const int mmgrid = (N + 63) / 64;

    // order A (FO >= FI): agg at FI (bf16 -> fp32), mm fp32-A with fused epilogue -> bf16
    #define DO_A(FI, FO, l) { \
        constexpr int jt = FI / 8; constexpr int ng = 256 / jt; \
        agg_kernel<0><<<(N + ng - 1) / ng, 256, 0, stream>>>( \
            hcur, rowptr, es, nd, B[l], t32, nullptr, N, jt, ng); \
        mm_tile_kernel<FI, FO, 1, 0><<<mmgrid, 4 * FO, 0, stream>>>( \
            t32, nullptr, nd, W[l], B[l], halt, N); \
        unsigned short* tmp = hcur; hcur = halt; halt = tmp; }

    // order B (FO < FI): mm bf16-A -> bf16, agg at FO with fused epilogue -> bf16
    #define DO_B(FI, FO, l) { \
        mm_tile_kernel<FI, FO, 0, 1><<<mmgrid, 4 * FO, 0, stream>>>( \
            nullptr, hcur, nd, W[l], B[l], halt, N); \
        constexpr int jt = FO / 8; constexpr int ng = 256 / jt; \
        agg_kernel<1><<<(N + ng - 1) / ng, 256, 0, stream>>>( \
            halt, rowptr, es, nd, B[l], nullptr, hcur, N, jt, ng); }

    DO_A(64, 80, 0)
    DO_A(80, 160, 1)
    DO_B(160, 112, 2)
    DO_A(112, 160, 3)
    DO_A(160, 176, 4)
    DO_B(176, 96, 5)
    DO_A(96, 144, 6)
    DO_B(144, 96, 7)
    DO_A(96, 128, 8)
    DO_B(128, 96, 9)
    DO_A(96, 160, 10)

    #undef DO_A
    #undef DO_B

    // ---- mean over nodes -> head ----
    hipMemsetAsync(acc, 0, 160 * sizeof(float), stream);
    mean_kernel<<<256, 160, 0, stream>>>(hcur, acc, N, 160);
    head_kernel<<<1, 256, 0, stream>>>(acc, Wd1, bd1, Wd2, bd2, out, N);
}

// Round 6
// 2057.672 us; speedup vs baseline: 9.4784x; 1.2155x over previous
//
#include <hip/hip_runtime.h>

#define LEAKY(v) ((v) > 0.0f ? (v) : 0.01f * (v))
#define SCAN_BLK 1024

typedef __bf16 bf16x8 __attribute__((ext_vector_type(8)));
typedef float f32x4 __attribute__((ext_vector_type(4)));

// ---------------- bf16 helpers (RNE) ----------------
__device__ inline float bflo(unsigned int u) { return __uint_as_float(u << 16); }
__device__ inline float bfhi(unsigned int u) { return __uint_as_float(u & 0xFFFF0000u); }
__device__ inline unsigned int pack2bf(float lo, float hi) {
    unsigned int a = __float_as_uint(lo);
    unsigned int b = __float_as_uint(hi);
    a = (a + 0x7FFFu + ((a >> 16) & 1u)) >> 16;
    b = (b + 0x7FFFu + ((b >> 16) & 1u)) & 0xFFFF0000u;
    return a | b;
}
__device__ inline unsigned short f2bf(float f) {
    unsigned int u = __float_as_uint(f);
    return (unsigned short)((u + 0x7FFFu + ((u >> 16) & 1u)) >> 16);
}

// ---------------- degree (int) ----------------
__global__ void deg_kernel(const int* __restrict__ src, const int* __restrict__ dst,
                           int* __restrict__ deg_out, int* __restrict__ deg_in, int E) {
    int i = blockIdx.x * blockDim.x + threadIdx.x;
    if (i < E) {
        atomicAdd(&deg_out[src[i]], 1);
        atomicAdd(&deg_in[dst[i]], 1);
    }
}

__global__ void norm_kernel(const int* __restrict__ deg_out, const int* __restrict__ deg_in,
                            float* __restrict__ ns, float* __restrict__ nd, int n) {
    int i = blockIdx.x * blockDim.x + threadIdx.x;
    if (i < n) {
        float dov = (float)deg_out[i];
        float div = (float)deg_in[i];
        ns[i] = (dov > 0.0f) ? rsqrtf(fmaxf(dov, 1.0f)) : 0.0f;
        nd[i] = (div > 0.0f) ? rsqrtf(fmaxf(div, 1.0f)) : 0.0f;
    }
}

// ---------------- prefix scan (3-kernel) for row_ptr ----------------
__global__ void scan1_kernel(const int* __restrict__ deg, int* __restrict__ out,
                             int* __restrict__ bsums, int n) {
    __shared__ int sh[SCAN_BLK];
    int gid = blockIdx.x * SCAN_BLK + threadIdx.x;
    int v = (gid < n) ? deg[gid] : 0;
    sh[threadIdx.x] = v;
    __syncthreads();
    for (int off = 1; off < SCAN_BLK; off <<= 1) {
        int t = (threadIdx.x >= off) ? sh[threadIdx.x - off] : 0;
        __syncthreads();
        sh[threadIdx.x] += t;
        __syncthreads();
    }
    if (gid < n) out[gid + 1] = sh[threadIdx.x];
    if (threadIdx.x == SCAN_BLK - 1) bsums[blockIdx.x] = sh[threadIdx.x];
    if (gid == 0) out[0] = 0;
}

__global__ void scan2_kernel(int* __restrict__ bsums, int nb) {
    __shared__ int sh[SCAN_BLK];
    int v = (threadIdx.x < nb) ? bsums[threadIdx.x] : 0;
    sh[threadIdx.x] = v;
    __syncthreads();
    for (int off = 1; off < SCAN_BLK; off <<= 1) {
        int t = (threadIdx.x >= off) ? sh[threadIdx.x - off] : 0;
        __syncthreads();
        sh[threadIdx.x] += t;
        __syncthreads();
    }
    if (threadIdx.x < nb) bsums[threadIdx.x] = sh[threadIdx.x] - v;
}

__global__ void scan3_kernel(int* __restrict__ out, const int* __restrict__ bsums, int n) {
    int gid = blockIdx.x * SCAN_BLK + threadIdx.x;
    if (gid < n) out[gid + 1] += bsums[blockIdx.x];
}

__global__ void copy_kernel(const int* __restrict__ a, int* __restrict__ b, int n) {
    int i = blockIdx.x * blockDim.x + threadIdx.x;
    if (i < n) b[i] = a[i];
}

// ---------------- counting sort by dst, fused coef; packed (src, coef) ----------------
__global__ void sort_kernel(const int* __restrict__ src, const int* __restrict__ dst,
                            const float* __restrict__ edata, const float* __restrict__ ns,
                            const float* __restrict__ mu, const float* __restrict__ sigma,
                            int* __restrict__ cursor, int2* __restrict__ es, int E) {
    int e = blockIdx.x * blockDim.x + threadIdx.x;
    if (e < E) {
        int d = dst[e];
        int pos = atomicAdd(&cursor[d], 1);
        int s = src[e];
        float ed = edata[e];
        float dd = ed - mu[0];
        float w = (ed == 1.0f) ? ed : expf(-(dd * dd) / sigma[0]);
        es[pos] = make_int2(s, __float_as_int(ns[s] * w));
    }
}

// ---------------- x -> bf16 ----------------
__global__ void x2bf_kernel(const float* __restrict__ x, unsigned short* __restrict__ o,
                            long long total4) {
    long long i = (long long)blockIdx.x * blockDim.x + threadIdx.x;
    if (i < total4) {
        float4 v = *reinterpret_cast<const float4*>(&x[i * 4]);
        uint2 p;
        p.x = pack2bf(v.x, v.y);
        p.y = pack2bf(v.z, v.w);
        *reinterpret_cast<uint2*>(&o[i * 4]) = p;
    }
}

// ---------------- pack W (fp32, row-major FIxFO) -> bf16 MFMA B-fragment layout ----------------
// tile = nb*KB + kb ; lane l: col n = nb*16 + (l&15), k0 = kb*32 + (l>>4)*8
// Wp[(tile*64 + l)*8 + j] = bf16(W[k0+j][n]), zero for k0+j >= FI (K padded to 32)
__global__ void packW_kernel(const float* __restrict__ W, unsigned short* __restrict__ Wp,
                             int FI, int FO) {
    int KB = (FI + 31) / 32;
    int NB = FO / 16;
    int gid = blockIdx.x * blockDim.x + threadIdx.x;
    if (gid >= KB * NB * 64) return;
    int l = gid & 63;
    int tile = gid >> 6;
    int kb = tile % KB;
    int nb = tile / KB;
    int n = nb * 16 + (l & 15);
    int k0 = kb * 32 + (l >> 4) * 8;
    unsigned short tmp[8];
    #pragma unroll
    for (int j = 0; j < 8; ++j) {
        int k = k0 + j;
        tmp[j] = (k < FI) ? f2bf(W[(size_t)k * FO + n]) : (unsigned short)0;
    }
    *reinterpret_cast<uint4*>(&Wp[(size_t)gid * 8]) = *reinterpret_cast<uint4*>(tmp);
}

// ---------------- CSR gather-sum aggregation (bf16 in, bf16 out) ----------------
// 256-thread block, ng groups of jt lanes; lane covers 8 features (uint4 = 8 bf16).
// MODE 0: out = bf16(agg) ; MODE 1: out = bf16(leaky(agg*nd + b))
#define FMA8(v, cc) \
    a0 = fmaf(bflo((v).x), cc, a0); a1 = fmaf(bfhi((v).x), cc, a1); \
    a2 = fmaf(bflo((v).y), cc, a2); a3 = fmaf(bfhi((v).y), cc, a3); \
    a4 = fmaf(bflo((v).z), cc, a4); a5 = fmaf(bfhi((v).z), cc, a5); \
    a6 = fmaf(bflo((v).w), cc, a6); a7 = fmaf(bfhi((v).w), cc, a7);

template<int MODE>
__global__ void agg_kernel(const unsigned short* __restrict__ hb,
                           const int* __restrict__ rowptr, const int2* __restrict__ es,
                           const float* __restrict__ nd, const float* __restrict__ bias,
                           unsigned short* __restrict__ out16,
                           int n, int jt, int ng) {
    int g = threadIdx.x / jt;
    if (g >= ng) return;
    int i = blockIdx.x * ng + g;
    if (i >= n) return;
    int c = (threadIdx.x - g * jt) << 3;   // feature offset (8 per lane)
    int F = jt << 3;
    int beg = rowptr[i], end = rowptr[i + 1];
    float a0 = 0, a1 = 0, a2 = 0, a3 = 0, a4 = 0, a5 = 0, a6 = 0, a7 = 0;
    int e = beg;
    for (; e + 4 <= end; e += 4) {
        int2 e0 = es[e + 0], e1 = es[e + 1], e2 = es[e + 2], e3 = es[e + 3];
        uint4 v0 = *reinterpret_cast<const uint4*>(&hb[(size_t)e0.x * F + c]);
        uint4 v1 = *reinterpret_cast<const uint4*>(&hb[(size_t)e1.x * F + c]);
        uint4 v2 = *reinterpret_cast<const uint4*>(&hb[(size_t)e2.x * F + c]);
        uint4 v3 = *reinterpret_cast<const uint4*>(&hb[(size_t)e3.x * F + c]);
        float c0 = __int_as_float(e0.y), c1 = __int_as_float(e1.y);
        float c2 = __int_as_float(e2.y), c3 = __int_as_float(e3.y);
        FMA8(v0, c0)
        FMA8(v1, c1)
        FMA8(v2, c2)
        FMA8(v3, c3)
    }
    for (; e < end; ++e) {
        int2 e0 = es[e];
        uint4 v0 = *reinterpret_cast<const uint4*>(&hb[(size_t)e0.x * F + c]);
        float c0 = __int_as_float(e0.y);
        FMA8(v0, c0)
    }
    if (MODE) {
        float s = nd[i];
        a0 = a0 * s + bias[c + 0]; a0 = LEAKY(a0);
        a1 = a1 * s + bias[c + 1]; a1 = LEAKY(a1);
        a2 = a2 * s + bias[c + 2]; a2 = LEAKY(a2);
        a3 = a3 * s + bias[c + 3]; a3 = LEAKY(a3);
        a4 = a4 * s + bias[c + 4]; a4 = LEAKY(a4);
        a5 = a5 * s + bias[c + 5]; a5 = LEAKY(a5);
        a6 = a6 * s + bias[c + 6]; a6 = LEAKY(a6);
        a7 = a7 * s + bias[c + 7]; a7 = LEAKY(a7);
    }
    uint4 p;
    p.x = pack2bf(a0, a1); p.y = pack2bf(a2, a3);
    p.z = pack2bf(a4, a5); p.w = pack2bf(a6, a7);
    *reinterpret_cast<uint4*>(&out16[(size_t)i * F + c]) = p;
}

// ---------------- MFMA matmul: out[n x FO] = A[n x FI] @ W ----------------
// 64 rows/block, 4 waves; wave w computes rows [w*16, w*16+16) x all FO cols.
// A staged in LDS (K zero-padded to 32, row pad +8 bf16 -> 2-way-only bank alias).
// B from packed Wp (L2-resident). fp32 accum via v_mfma_f32_16x16x32_bf16.
// MODE 1: fused leaky((A@W)*nd + b). Output bf16.
template<int FI, int FO, int MODE>
__global__ __launch_bounds__(256) void mm_mfma_kernel(
    const unsigned short* __restrict__ Ab, const float* __restrict__ nd,
    const unsigned short* __restrict__ Wp, const float* __restrict__ bias,
    unsigned short* __restrict__ out, int n)
{
    constexpr int FIP = (FI + 31) / 32 * 32;
    constexpr int KB = FIP / 32;
    constexpr int NB = FO / 16;
    constexpr int LDA = FIP + 8;
    constexpr int RW = FIP / 8;            // uint4 slots per row
    __shared__ unsigned short As[64 * LDA];

    const int t = threadIdx.x;
    const int row0 = blockIdx.x * 64;

    // stage A tile (zero-pad K tail and rows past n)
    for (int idx = t; idx < 64 * RW; idx += 256) {
        int r = idx / RW;
        int c8 = (idx - r * RW) * 8;
        int grow = row0 + r;
        uint4 v = make_uint4(0u, 0u, 0u, 0u);
        if (grow < n && c8 < FI)
            v = *reinterpret_cast<const uint4*>(&Ab[(size_t)grow * FI + c8]);
        *reinterpret_cast<uint4*>(&As[r * LDA + c8]) = v;
    }
    __syncthreads();

    const int w = t >> 6;
    const int l = t & 63;
    const int arow = (w << 4) + (l & 15);
    const int koff = (l >> 4) << 3;

    bf16x8 a[KB];
    #pragma unroll
    for (int kb = 0; kb < KB; ++kb)
        a[kb] = *reinterpret_cast<const bf16x8*>(&As[arow * LDA + kb * 32 + koff]);

    f32x4 acc[NB] = {};
    #pragma unroll
    for (int nb = 0; nb < NB; ++nb) {
        #pragma unroll
        for (int kb = 0; kb < KB; ++kb) {
            bf16x8 b = *reinterpret_cast<const bf16x8*>(&Wp[(size_t)((nb * KB + kb) * 64 + l) * 8]);
            acc[nb] = __builtin_amdgcn_mfma_f32_16x16x32_bf16(a[kb], b, acc[nb], 0, 0, 0);
        }
    }

    // epilogue: C/D layout col = l&15, row = (l>>4)*4 + r
    const int col = l & 15;
    const int rb = (l >> 4) << 2;
    #pragma unroll
    for (int r = 0; r < 4; ++r) {
        int grow = row0 + (w << 4) + rb + r;
        if (grow < n) {
            float s = MODE ? nd[grow] : 1.0f;
            #pragma unroll
            for (int nb = 0; nb < NB; ++nb) {
                float v = acc[nb][r];
                if (MODE) {
                    v = v * s + bias[nb * 16 + col];
                    v = LEAKY(v);
                }
                out[(size_t)grow * FO + nb * 16 + col] = f2bf(v);
            }
        }
    }
}

// ---------------- mean over nodes (bf16 in, F=160) ----------------
__global__ void mean_kernel(const unsigned short* __restrict__ h, float* __restrict__ acc,
                            int n, int F) {
    int f = threadIdx.x;
    if (f >= F) return;
    float partial = 0.0f;
    for (int i = blockIdx.x; i < n; i += gridDim.x) {
        partial += __uint_as_float(((unsigned int)h[(size_t)i * F + f]) << 16);
    }
    atomicAdd(&acc[f], partial);
}

// ---------------- head ----------------
__global__ void head_kernel(const float* __restrict__ acc, const float* __restrict__ Wd1,
                            const float* __restrict__ bd1, const float* __restrict__ Wd2,
                            const float* __restrict__ bd2, float* __restrict__ out, int n) {
    __shared__ float gm[160];
    __shared__ float h1[140];
    int tid = threadIdx.x;
    if (tid < 160) {
        float v = acc[tid] / (float)n;
        gm[tid] = LEAKY(v);
    }
    __syncthreads();
    if (tid < 140) {
        float s = bd1[tid];
        for (int k = 0; k < 160; ++k) s += gm[k] * Wd1[k * 140 + tid];
        h1[tid] = LEAKY(s);
    }
    __syncthreads();
    if (tid < 2) {
        float s = bd2[tid];
        for (int k = 0; k < 140; ++k) s += h1[k] * Wd2[k * 2 + tid];
        out[tid] = 1.0f / (1.0f + expf(-s));
    }
}

extern "C" void kernel_launch(void* const* d_in, const int* in_sizes, int n_in,
                              void* d_out, int out_size, void* d_ws, size_t ws_size,
                              hipStream_t stream) {
    static const int dims[12] = {64, 80, 160, 112, 160, 176, 96, 144, 96, 128, 96, 160};

    const float* x     = (const float*)d_in[0];
    const int*   src   = (const int*)d_in[1];
    const int*   dst   = (const int*)d_in[2];
    const float* edata = (const float*)d_in[3];
    const float* W[11];
    const float* B[11];
    for (int i = 0; i < 11; ++i) {
        W[i] = (const float*)d_in[4 + 2 * i];
        B[i] = (const float*)d_in[5 + 2 * i];
    }
    const float* Wd1   = (const float*)d_in[26];
    const float* bd1   = (const float*)d_in[27];
    const float* Wd2   = (const float*)d_in[28];
    const float* bd2   = (const float*)d_in[29];
    const float* mu    = (const float*)d_in[30];
    const float* sigma = (const float*)d_in[31];
    float* out = (float*)d_out;

    const int N = in_sizes[0] / 64;
    const int E = in_sizes[1];
    const int FMAX = 176;

    // packed-W offsets (elements), K padded to 32
    size_t woff[11];
    size_t wtot = 0;
    for (int l = 0; l < 11; ++l) {
        woff[l] = wtot;
        int fip = (dims[l] + 31) / 32 * 32;
        wtot += (size_t)fip * dims[l + 1];
    }

    // workspace layout
    char* wsb = (char*)d_ws;
    size_t o = 0;
    auto alloc = [&](size_t bytes) { void* p = wsb + o; o += (bytes + 255) & ~(size_t)255; return p; };
    unsigned short* hb0 = (unsigned short*)alloc((size_t)N * FMAX * 2);
    unsigned short* hb1 = (unsigned short*)alloc((size_t)N * FMAX * 2);
    unsigned short* Wp  = (unsigned short*)alloc(wtot * 2);
    int2*  es      = (int2*) alloc((size_t)E * sizeof(int2));
    int*   rowptr  = (int*)  alloc((size_t)(N + 1) * sizeof(int));
    int*   cursor  = (int*)  alloc((size_t)N * sizeof(int));
    int*   degout  = (int*)  alloc((size_t)N * sizeof(int));
    int*   degin   = (int*)  alloc((size_t)N * sizeof(int));
    float* ns      = (float*)alloc((size_t)N * sizeof(float));
    float* nd      = (float*)alloc((size_t)N * sizeof(float));
    int*   bsums   = (int*)  alloc(2048 * sizeof(int));
    float* acc     = (float*)alloc(160 * sizeof(float));

    // ---- degrees, norms ----
    hipMemsetAsync(degout, 0, (size_t)N * sizeof(int), stream);
    hipMemsetAsync(degin, 0, (size_t)N * sizeof(int), stream);
    deg_kernel<<<(E + 255) / 256, 256, 0, stream>>>(src, dst, degout, degin, E);
    norm_kernel<<<(N + 255) / 256, 256, 0, stream>>>(degout, degin, ns, nd, N);

    // ---- CSR build ----
    int nblk = (N + SCAN_BLK - 1) / SCAN_BLK;
    scan1_kernel<<<nblk, SCAN_BLK, 0, stream>>>(degin, rowptr, bsums, N);
    scan2_kernel<<<1, SCAN_BLK, 0, stream>>>(bsums, nblk);
    scan3_kernel<<<nblk, SCAN_BLK, 0, stream>>>(rowptr, bsums, N);
    copy_kernel<<<(N + 255) / 256, 256, 0, stream>>>(rowptr, cursor, N);
    sort_kernel<<<(E + 255) / 256, 256, 0, stream>>>(src, dst, edata, ns, mu, sigma,
                                                     cursor, es, E);

    // ---- x -> bf16 ; W -> packed bf16 fragments ----
    long long x4 = (long long)N * 64 / 4;
    x2bf_kernel<<<(int)((x4 + 255) / 256), 256, 0, stream>>>(x, hb0, x4);
    for (int l = 0; l < 11; ++l) {
        int fip = (dims[l] + 31) / 32 * 32;
        int threads = (fip / 32) * (dims[l + 1] / 16) * 64;
        packW_kernel<<<(threads + 255) / 256, 256, 0, stream>>>(W[l], Wp + woff[l],
                                                                dims[l], dims[l + 1]);
    }

    // ---- 11 GCN layers (hcur -> halt -> hcur each layer) ----
    unsigned short* hcur = hb0;
    unsigned short* halt = hb1;
    const int mmgrid = (N + 63) / 64;

    // order A (FO >= FI): agg at FI (bf16->bf16), MFMA mm with fused epilogue
    #define DO_A(FI, FO, l) { \
        constexpr int jt = FI / 8; constexpr int ng = 256 / jt; \
        agg_kernel<0><<<(N + ng - 1) / ng, 256, 0, stream>>>( \
            hcur, rowptr, es, nd, B[l], halt, N, jt, ng); \
        mm_mfma_kernel<FI, FO, 1><<<mmgrid, 256, 0, stream>>>( \
            halt, nd, Wp + woff[l], B[l], hcur, N); }

    // order B (FO < FI): MFMA mm plain, then agg at FO with fused epilogue
    #define DO_B(FI, FO, l) { \
        mm_mfma_kernel<FI, FO, 0><<<mmgrid, 256, 0, stream>>>( \
            hcur, nd, Wp + woff[l], B[l], halt, N); \
        constexpr int jt = FO / 8; constexpr int ng = 256 / jt; \
        agg_kernel<1><<<(N + ng - 1) / ng, 256, 0, stream>>>( \
            halt, rowptr, es, nd, B[l], hcur, N, jt, ng); }

    DO_A(64, 80, 0)
    DO_A(80, 160, 1)
    DO_B(160, 112, 2)
    DO_A(112, 160, 3)
    DO_A(160, 176, 4)
    DO_B(176, 96, 5)
    DO_A(96, 144, 6)
    DO_B(144, 96, 7)
    DO_A(96, 128, 8)
    DO_B(128, 96, 9)
    DO_A(96, 160, 10)

    #undef DO_A
    #undef DO_B

    // ---- mean over nodes -> head ----
    hipMemsetAsync(acc, 0, 160 * sizeof(float), stream);
    mean_kernel<<<256, 160, 0, stream>>>(hcur, acc, N, 160);
    head_kernel<<<1, 256, 0, stream>>>(acc, Wd1, bd1, Wd2, bd2, out, N);
}

// Round 7
// 1537.118 us; speedup vs baseline: 12.6883x; 1.3387x over previous
//
#include <hip/hip_runtime.h>

#define LEAKY(v) ((v) > 0.0f ? (v) : 0.01f * (v))
#define SCAN_BLK 1024

typedef __bf16 bf16x8 __attribute__((ext_vector_type(8)));
typedef float f32x4 __attribute__((ext_vector_type(4)));

// ---------------- bf16 helpers (RNE) ----------------
__device__ inline float bflo(unsigned int u) { return __uint_as_float(u << 16); }
__device__ inline float bfhi(unsigned int u) { return __uint_as_float(u & 0xFFFF0000u); }
__device__ inline unsigned int pack2bf(float lo, float hi) {
    unsigned int a = __float_as_uint(lo);
    unsigned int b = __float_as_uint(hi);
    a = (a + 0x7FFFu + ((a >> 16) & 1u)) >> 16;
    b = (b + 0x7FFFu + ((b >> 16) & 1u)) & 0xFFFF0000u;
    return a | b;
}
__device__ inline unsigned short f2bf(float f) {
    unsigned int u = __float_as_uint(f);
    return (unsigned short)((u + 0x7FFFu + ((u >> 16) & 1u)) >> 16);
}

// ---------------- fp8 e4m3 helpers (HW cvt, OCP on gfx950) ----------------
__device__ inline unsigned char f2f8(float v) {
    return (unsigned char)(__builtin_amdgcn_cvt_pk_fp8_f32(v, 0.0f, 0u, false) & 0xFFu);
}
// pack 8 floats -> uint2 of fp8
__device__ inline uint2 pack8f8(float v0, float v1, float v2, float v3,
                                float v4, float v5, float v6, float v7) {
    uint2 q;
    q.x = __builtin_amdgcn_cvt_pk_fp8_f32(v0, v1, 0u, false);
    q.x = __builtin_amdgcn_cvt_pk_fp8_f32(v2, v3, q.x, true);
    q.y = __builtin_amdgcn_cvt_pk_fp8_f32(v4, v5, 0u, false);
    q.y = __builtin_amdgcn_cvt_pk_fp8_f32(v6, v7, q.y, true);
    return q;
}

// ---------------- degree (int) + slot recording ----------------
__global__ void deg_kernel(const int* __restrict__ src, const int* __restrict__ dst,
                           int* __restrict__ deg_out, int* __restrict__ deg_in,
                           int* __restrict__ slot, int E) {
    int i = blockIdx.x * blockDim.x + threadIdx.x;
    if (i < E) {
        slot[i] = atomicAdd(&deg_in[dst[i]], 1);
        atomicAdd(&deg_out[src[i]], 1);
    }
}

__global__ void norm_kernel(const int* __restrict__ deg_out, const int* __restrict__ deg_in,
                            float* __restrict__ ns, float* __restrict__ nd, int n) {
    int i = blockIdx.x * blockDim.x + threadIdx.x;
    if (i < n) {
        float dov = (float)deg_out[i];
        float div = (float)deg_in[i];
        ns[i] = (dov > 0.0f) ? rsqrtf(fmaxf(dov, 1.0f)) : 0.0f;
        nd[i] = (div > 0.0f) ? rsqrtf(fmaxf(div, 1.0f)) : 0.0f;
    }
}

// ---------------- prefix scan (3-kernel) for row_ptr ----------------
__global__ void scan1_kernel(const int* __restrict__ deg, int* __restrict__ out,
                             int* __restrict__ bsums, int n) {
    __shared__ int sh[SCAN_BLK];
    int gid = blockIdx.x * SCAN_BLK + threadIdx.x;
    int v = (gid < n) ? deg[gid] : 0;
    sh[threadIdx.x] = v;
    __syncthreads();
    for (int off = 1; off < SCAN_BLK; off <<= 1) {
        int t = (threadIdx.x >= off) ? sh[threadIdx.x - off] : 0;
        __syncthreads();
        sh[threadIdx.x] += t;
        __syncthreads();
    }
    if (gid < n) out[gid + 1] = sh[threadIdx.x];
    if (threadIdx.x == SCAN_BLK - 1) bsums[blockIdx.x] = sh[threadIdx.x];
    if (gid == 0) out[0] = 0;
}

__global__ void scan2_kernel(int* __restrict__ bsums, int nb) {
    __shared__ int sh[SCAN_BLK];
    int v = (threadIdx.x < nb) ? bsums[threadIdx.x] : 0;
    sh[threadIdx.x] = v;
    __syncthreads();
    for (int off = 1; off < SCAN_BLK; off <<= 1) {
        int t = (threadIdx.x >= off) ? sh[threadIdx.x - off] : 0;
        __syncthreads();
        sh[threadIdx.x] += t;
        __syncthreads();
    }
    if (threadIdx.x < nb) bsums[threadIdx.x] = sh[threadIdx.x] - v;
}

__global__ void scan3_kernel(int* __restrict__ out, const int* __restrict__ bsums, int n) {
    int gid = blockIdx.x * SCAN_BLK + threadIdx.x;
    if (gid < n) out[gid + 1] += bsums[blockIdx.x];
}

// ---------------- placement (no atomics): pos = rowptr[dst] + slot ----------------
__global__ void place_kernel(const int* __restrict__ src, const int* __restrict__ dst,
                             const float* __restrict__ edata, const float* __restrict__ ns,
                             const float* __restrict__ mu, const float* __restrict__ sigma,
                             const int* __restrict__ rowptr, const int* __restrict__ slot,
                             int2* __restrict__ es, int E) {
    int e = blockIdx.x * blockDim.x + threadIdx.x;
    if (e < E) {
        int d = dst[e];
        int s = src[e];
        float ed = edata[e];
        float dd = ed - mu[0];
        float w = (ed == 1.0f) ? ed : expf(-(dd * dd) / sigma[0]);
        int pos = rowptr[d] + slot[e];
        es[pos] = make_int2(s, __float_as_int(ns[s] * w));
    }
}

// ---------------- x -> bf16 + fp8 ----------------
__global__ void x2bf_kernel(const float* __restrict__ x, unsigned short* __restrict__ o16,
                            unsigned char* __restrict__ o8, long long total4) {
    long long i = (long long)blockIdx.x * blockDim.x + threadIdx.x;
    if (i < total4) {
        float4 v = *reinterpret_cast<const float4*>(&x[i * 4]);
        uint2 p;
        p.x = pack2bf(v.x, v.y);
        p.y = pack2bf(v.z, v.w);
        *reinterpret_cast<uint2*>(&o16[i * 4]) = p;
        unsigned int q = __builtin_amdgcn_cvt_pk_fp8_f32(v.x, v.y, 0u, false);
        q = __builtin_amdgcn_cvt_pk_fp8_f32(v.z, v.w, q, true);
        *reinterpret_cast<unsigned int*>(&o8[i * 4]) = q;
    }
}

// ---------------- pack W (fp32, row-major FIxFO) -> bf16 MFMA B-fragment layout ----------------
__global__ void packW_kernel(const float* __restrict__ W, unsigned short* __restrict__ Wp,
                             int FI, int FO) {
    int KB = (FI + 31) / 32;
    int NB = FO / 16;
    int gid = blockIdx.x * blockDim.x + threadIdx.x;
    if (gid >= KB * NB * 64) return;
    int l = gid & 63;
    int tile = gid >> 6;
    int kb = tile % KB;
    int nb = tile / KB;
    int n = nb * 16 + (l & 15);
    int k0 = kb * 32 + (l >> 4) * 8;
    unsigned short tmp[8];
    #pragma unroll
    for (int j = 0; j < 8; ++j) {
        int k = k0 + j;
        tmp[j] = (k < FI) ? f2bf(W[(size_t)k * FO + n]) : (unsigned short)0;
    }
    *reinterpret_cast<uint4*>(&Wp[(size_t)gid * 8]) = *reinterpret_cast<uint4*>(tmp);
}

// ---------------- CSR gather-sum aggregation (fp8 in) ----------------
// 256-thread block, ng groups of jt lanes; lane covers 8 features (uint2 = 8 fp8).
// MODE 0: out16 = bf16(agg)            (consumed sequentially by mm)
// MODE 1: out16+out8 = leaky(agg*nd+b) (becomes next-layer h)
#define F8ACC(v, cc) { \
    auto p01 = __builtin_amdgcn_cvt_pk_f32_fp8((v).x, false); \
    auto p23 = __builtin_amdgcn_cvt_pk_f32_fp8((v).x, true);  \
    auto p45 = __builtin_amdgcn_cvt_pk_f32_fp8((v).y, false); \
    auto p67 = __builtin_amdgcn_cvt_pk_f32_fp8((v).y, true);  \
    a0 = fmaf(p01[0], cc, a0); a1 = fmaf(p01[1], cc, a1); \
    a2 = fmaf(p23[0], cc, a2); a3 = fmaf(p23[1], cc, a3); \
    a4 = fmaf(p45[0], cc, a4); a5 = fmaf(p45[1], cc, a5); \
    a6 = fmaf(p67[0], cc, a6); a7 = fmaf(p67[1], cc, a7); }

template<int MODE>
__global__ void agg_kernel(const unsigned char* __restrict__ h8,
                           const int* __restrict__ rowptr, const int2* __restrict__ es,
                           const float* __restrict__ nd, const float* __restrict__ bias,
                           unsigned short* __restrict__ out16, unsigned char* __restrict__ out8,
                           int n, int jt, int ng) {
    int g = threadIdx.x / jt;
    if (g >= ng) return;
    int i = blockIdx.x * ng + g;
    if (i >= n) return;
    int c = (threadIdx.x - g * jt) << 3;   // feature offset (8 per lane)
    int F = jt << 3;
    int beg = rowptr[i], end = rowptr[i + 1];
    float a0 = 0, a1 = 0, a2 = 0, a3 = 0, a4 = 0, a5 = 0, a6 = 0, a7 = 0;
    int e = beg;
    for (; e + 4 <= end; e += 4) {
        int2 e0 = es[e + 0], e1 = es[e + 1], e2 = es[e + 2], e3 = es[e + 3];
        uint2 v0 = *reinterpret_cast<const uint2*>(&h8[(size_t)e0.x * F + c]);
        uint2 v1 = *reinterpret_cast<const uint2*>(&h8[(size_t)e1.x * F + c]);
        uint2 v2 = *reinterpret_cast<const uint2*>(&h8[(size_t)e2.x * F + c]);
        uint2 v3 = *reinterpret_cast<const uint2*>(&h8[(size_t)e3.x * F + c]);
        float c0 = __int_as_float(e0.y), c1 = __int_as_float(e1.y);
        float c2 = __int_as_float(e2.y), c3 = __int_as_float(e3.y);
        F8ACC(v0, c0)
        F8ACC(v1, c1)
        F8ACC(v2, c2)
        F8ACC(v3, c3)
    }
    for (; e < end; ++e) {
        int2 e0 = es[e];
        uint2 v0 = *reinterpret_cast<const uint2*>(&h8[(size_t)e0.x * F + c]);
        float c0 = __int_as_float(e0.y);
        F8ACC(v0, c0)
    }
    if (MODE) {
        float s = nd[i];
        a0 = a0 * s + bias[c + 0]; a0 = LEAKY(a0);
        a1 = a1 * s + bias[c + 1]; a1 = LEAKY(a1);
        a2 = a2 * s + bias[c + 2]; a2 = LEAKY(a2);
        a3 = a3 * s + bias[c + 3]; a3 = LEAKY(a3);
        a4 = a4 * s + bias[c + 4]; a4 = LEAKY(a4);
        a5 = a5 * s + bias[c + 5]; a5 = LEAKY(a5);
        a6 = a6 * s + bias[c + 6]; a6 = LEAKY(a6);
        a7 = a7 * s + bias[c + 7]; a7 = LEAKY(a7);
    }
    uint4 p;
    p.x = pack2bf(a0, a1); p.y = pack2bf(a2, a3);
    p.z = pack2bf(a4, a5); p.w = pack2bf(a6, a7);
    *reinterpret_cast<uint4*>(&out16[(size_t)i * F + c]) = p;
    if (MODE) {
        uint2 q = pack8f8(a0, a1, a2, a3, a4, a5, a6, a7);
        *reinterpret_cast<uint2*>(&out8[(size_t)i * F + c]) = q;
    }
}

// ---------------- MFMA matmul: out[n x FO] = A[n x FI] @ W ----------------
// 64 rows/block, 4 waves. A (bf16) staged in LDS, B from packed Wp, fp32 accum.
// MODE 1 (A-layer): fused leaky((A@W)*nd+b), writes bf16 + fp8.
// MODE 0 (B-layer): plain A@W, writes fp8 only (consumed by gather).
template<int FI, int FO, int MODE>
__global__ __launch_bounds__(256) void mm_mfma_kernel(
    const unsigned short* __restrict__ Ab, const float* __restrict__ nd,
    const unsigned short* __restrict__ Wp, const float* __restrict__ bias,
    unsigned short* __restrict__ out16, unsigned char* __restrict__ out8, int n)
{
    constexpr int FIP = (FI + 31) / 32 * 32;
    constexpr int KB = FIP / 32;
    constexpr int NB = FO / 16;
    constexpr int LDA = FIP + 8;
    constexpr int RW = FIP / 8;
    __shared__ unsigned short As[64 * LDA];

    const int t = threadIdx.x;
    const int row0 = blockIdx.x * 64;

    for (int idx = t; idx < 64 * RW; idx += 256) {
        int r = idx / RW;
        int c8 = (idx - r * RW) * 8;
        int grow = row0 + r;
        uint4 v = make_uint4(0u, 0u, 0u, 0u);
        if (grow < n && c8 < FI)
            v = *reinterpret_cast<const uint4*>(&Ab[(size_t)grow * FI + c8]);
        *reinterpret_cast<uint4*>(&As[r * LDA + c8]) = v;
    }
    __syncthreads();

    const int w = t >> 6;
    const int l = t & 63;
    const int arow = (w << 4) + (l & 15);
    const int koff = (l >> 4) << 3;

    bf16x8 a[KB];
    #pragma unroll
    for (int kb = 0; kb < KB; ++kb)
        a[kb] = *reinterpret_cast<const bf16x8*>(&As[arow * LDA + kb * 32 + koff]);

    f32x4 acc[NB] = {};
    #pragma unroll
    for (int nb = 0; nb < NB; ++nb) {
        #pragma unroll
        for (int kb = 0; kb < KB; ++kb) {
            bf16x8 b = *reinterpret_cast<const bf16x8*>(&Wp[(size_t)((nb * KB + kb) * 64 + l) * 8]);
            acc[nb] = __builtin_amdgcn_mfma_f32_16x16x32_bf16(a[kb], b, acc[nb], 0, 0, 0);
        }
    }

    const int col = l & 15;
    const int rb = (l >> 4) << 2;
    #pragma unroll
    for (int r = 0; r < 4; ++r) {
        int grow = row0 + (w << 4) + rb + r;
        if (grow < n) {
            float s = MODE ? nd[grow] : 1.0f;
            #pragma unroll
            for (int nb = 0; nb < NB; ++nb) {
                float v = acc[nb][r];
                if (MODE) {
                    v = v * s + bias[nb * 16 + col];
                    v = LEAKY(v);
                    out16[(size_t)grow * FO + nb * 16 + col] = f2bf(v);
                    out8[(size_t)grow * FO + nb * 16 + col] = f2f8(v);
                } else {
                    out8[(size_t)grow * FO + nb * 16 + col] = f2f8(v);
                }
            }
        }
    }
}

// ---------------- mean over nodes (bf16 in, F=160) ----------------
__global__ void mean_kernel(const unsigned short* __restrict__ h, float* __restrict__ acc,
                            int n, int F) {
    int f = threadIdx.x;
    if (f >= F) return;
    float partial = 0.0f;
    for (int i = blockIdx.x; i < n; i += gridDim.x) {
        partial += __uint_as_float(((unsigned int)h[(size_t)i * F + f]) << 16);
    }
    atomicAdd(&acc[f], partial);
}

// ---------------- head ----------------
__global__ void head_kernel(const float* __restrict__ acc, const float* __restrict__ Wd1,
                            const float* __restrict__ bd1, const float* __restrict__ Wd2,
                            const float* __restrict__ bd2, float* __restrict__ out, int n) {
    __shared__ float gm[160];
    __shared__ float h1[140];
    int tid = threadIdx.x;
    if (tid < 160) {
        float v = acc[tid] / (float)n;
        gm[tid] = LEAKY(v);
    }
    __syncthreads();
    if (tid < 140) {
        float s = bd1[tid];
        for (int k = 0; k < 160; ++k) s += gm[k] * Wd1[k * 140 + tid];
        h1[tid] = LEAKY(s);
    }
    __syncthreads();
    if (tid < 2) {
        float s = bd2[tid];
        for (int k = 0; k < 140; ++k) s += h1[k] * Wd2[k * 2 + tid];
        out[tid] = 1.0f / (1.0f + expf(-s));
    }
}

extern "C" void kernel_launch(void* const* d_in, const int* in_sizes, int n_in,
                              void* d_out, int out_size, void* d_ws, size_t ws_size,
                              hipStream_t stream) {
    static const int dims[12] = {64, 80, 160, 112, 160, 176, 96, 144, 96, 128, 96, 160};

    const float* x     = (const float*)d_in[0];
    const int*   src   = (const int*)d_in[1];
    const int*   dst   = (const int*)d_in[2];
    const float* edata = (const float*)d_in[3];
    const float* W[11];
    const float* B[11];
    for (int i = 0; i < 11; ++i) {
        W[i] = (const float*)d_in[4 + 2 * i];
        B[i] = (const float*)d_in[5 + 2 * i];
    }
    const float* Wd1   = (const float*)d_in[26];
    const float* bd1   = (const float*)d_in[27];
    const float* Wd2   = (const float*)d_in[28];
    const float* bd2   = (const float*)d_in[29];
    const float* mu    = (const float*)d_in[30];
    const float* sigma = (const float*)d_in[31];
    float* out = (float*)d_out;

    const int N = in_sizes[0] / 64;
    const int E = in_sizes[1];
    const int FMAX = 176;

    // packed-W offsets (elements), K padded to 32
    size_t woff[11];
    size_t wtot = 0;
    for (int l = 0; l < 11; ++l) {
        woff[l] = wtot;
        int fip = (dims[l] + 31) / 32 * 32;
        wtot += (size_t)fip * dims[l + 1];
    }

    // workspace layout
    char* wsb = (char*)d_ws;
    size_t o = 0;
    auto alloc = [&](size_t bytes) { void* p = wsb + o; o += (bytes + 255) & ~(size_t)255; return p; };
    unsigned short* hb_main = (unsigned short*)alloc((size_t)N * FMAX * 2);
    unsigned short* hb_t    = (unsigned short*)alloc((size_t)N * FMAX * 2);
    unsigned char*  h8_main = (unsigned char*) alloc((size_t)N * FMAX);
    unsigned char*  h8_t    = (unsigned char*) alloc((size_t)N * FMAX);
    unsigned short* Wp  = (unsigned short*)alloc(wtot * 2);
    int2*  es      = (int2*) alloc((size_t)E * sizeof(int2));
    int*   slot    = (int*)  alloc((size_t)E * sizeof(int));
    int*   rowptr  = (int*)  alloc((size_t)(N + 1) * sizeof(int));
    int*   degout  = (int*)  alloc((size_t)N * sizeof(int));
    int*   degin   = (int*)  alloc((size_t)N * sizeof(int));
    float* ns      = (float*)alloc((size_t)N * sizeof(float));
    float* nd      = (float*)alloc((size_t)N * sizeof(float));
    int*   bsums   = (int*)  alloc(2048 * sizeof(int));
    float* acc     = (float*)alloc(160 * sizeof(float));

    // ---- degrees (+slot), norms ----
    hipMemsetAsync(degout, 0, (size_t)N * sizeof(int), stream);
    hipMemsetAsync(degin, 0, (size_t)N * sizeof(int), stream);
    deg_kernel<<<(E + 255) / 256, 256, 0, stream>>>(src, dst, degout, degin, slot, E);
    norm_kernel<<<(N + 255) / 256, 256, 0, stream>>>(degout, degin, ns, nd, N);

    // ---- CSR build: scan -> rowptr; atomic-free placement ----
    int nblk = (N + SCAN_BLK - 1) / SCAN_BLK;
    scan1_kernel<<<nblk, SCAN_BLK, 0, stream>>>(degin, rowptr, bsums, N);
    scan2_kernel<<<1, SCAN_BLK, 0, stream>>>(bsums, nblk);
    scan3_kernel<<<nblk, SCAN_BLK, 0, stream>>>(rowptr, bsums, N);
    place_kernel<<<(E + 255) / 256, 256, 0, stream>>>(src, dst, edata, ns, mu, sigma,
                                                      rowptr, slot, es, E);

    // ---- x -> bf16+fp8 ; W -> packed bf16 fragments ----
    long long x4 = (long long)N * 64 / 4;
    x2bf_kernel<<<(int)((x4 + 255) / 256), 256, 0, stream>>>(x, hb_main, h8_main, x4);
    for (int l = 0; l < 11; ++l) {
        int fip = (dims[l] + 31) / 32 * 32;
        int threads = (fip / 32) * (dims[l + 1] / 16) * 64;
        packW_kernel<<<(threads + 255) / 256, 256, 0, stream>>>(W[l], Wp + woff[l],
                                                                dims[l], dims[l + 1]);
    }

    // ---- 11 GCN layers (fixed buffer roles, no swap) ----
    const int mmgrid = (N + 63) / 64;

    // order A (FO >= FI): agg gathers h8_main -> hb_t (bf16);
    //                     mm(hb_t) fused epilogue -> hb_main + h8_main
    #define DO_A(FI, FO, l) { \
        constexpr int jt = FI / 8; constexpr int ng = 256 / jt; \
        agg_kernel<0><<<(N + ng - 1) / ng, 256, 0, stream>>>( \
            h8_main, rowptr, es, nd, B[l], hb_t, nullptr, N, jt, ng); \
        mm_mfma_kernel<FI, FO, 1><<<mmgrid, 256, 0, stream>>>( \
            hb_t, nd, Wp + woff[l], B[l], hb_main, h8_main, N); }

    // order B (FO < FI): mm(hb_main) -> h8_t (fp8);
    //                    agg gathers h8_t, fused epilogue -> hb_main + h8_main
    #define DO_B(FI, FO, l) { \
        mm_mfma_kernel<FI, FO, 0><<<mmgrid, 256, 0, stream>>>( \
            hb_main, nd, Wp + woff[l], B[l], nullptr, h8_t, N); \
        constexpr int jt = FO / 8; constexpr int ng = 256 / jt; \
        agg_kernel<1><<<(N + ng - 1) / ng, 256, 0, stream>>>( \
            h8_t, rowptr, es, nd, B[l], hb_main, h8_main, N, jt, ng); }

    DO_A(64, 80, 0)
    DO_A(80, 160, 1)
    DO_B(160, 112, 2)
    DO_A(112, 160, 3)
    DO_A(160, 176, 4)
    DO_B(176, 96, 5)
    DO_A(96, 144, 6)
    DO_B(144, 96, 7)
    DO_A(96, 128, 8)
    DO_B(128, 96, 9)
    DO_A(96, 160, 10)

    #undef DO_A
    #undef DO_B

    // ---- mean over nodes -> head ----
    hipMemsetAsync(acc, 0, 160 * sizeof(float), stream);
    mean_kernel<<<256, 160, 0, stream>>>(hb_main, acc, N, 160);
    head_kernel<<<1, 256, 0, stream>>>(acc, Wd1, bd1, Wd2, bd2, out, N);
}

// Round 8
// 1379.391 us; speedup vs baseline: 14.1392x; 1.1143x over previous
//
#include <hip/hip_runtime.h>

#define LEAKY(v) ((v) > 0.0f ? (v) : 0.01f * (v))
#define SCAN_BLK 1024
#define EPB 4096          // edges per block in bucket pipeline
#define BKN 256           // nodes per bucket

typedef __bf16 bf16x8 __attribute__((ext_vector_type(8)));
typedef float f32x4 __attribute__((ext_vector_type(4)));

// ---------------- bf16 helpers (RNE) ----------------
__device__ inline float bflo(unsigned int u) { return __uint_as_float(u << 16); }
__device__ inline float bfhi(unsigned int u) { return __uint_as_float(u & 0xFFFF0000u); }
__device__ inline unsigned int pack2bf(float lo, float hi) {
    unsigned int a = __float_as_uint(lo);
    unsigned int b = __float_as_uint(hi);
    a = (a + 0x7FFFu + ((a >> 16) & 1u)) >> 16;
    b = (b + 0x7FFFu + ((b >> 16) & 1u)) & 0xFFFF0000u;
    return a | b;
}
__device__ inline unsigned short f2bf(float f) {
    unsigned int u = __float_as_uint(f);
    return (unsigned short)((u + 0x7FFFu + ((u >> 16) & 1u)) >> 16);
}

// ---------------- fp8 e4m3 helpers (HW cvt, OCP on gfx950) ----------------
__device__ inline unsigned char f2f8(float v) {
    return (unsigned char)(__builtin_amdgcn_cvt_pk_fp8_f32(v, 0.0f, 0u, false) & 0xFFu);
}
__device__ inline uint2 pack8f8(float v0, float v1, float v2, float v3,
                                float v4, float v5, float v6, float v7) {
    uint2 q;
    q.x = __builtin_amdgcn_cvt_pk_fp8_f32(v0, v1, 0u, false);
    q.x = __builtin_amdgcn_cvt_pk_fp8_f32(v2, v3, q.x, true);
    q.y = __builtin_amdgcn_cvt_pk_fp8_f32(v4, v5, 0u, false);
    q.y = __builtin_amdgcn_cvt_pk_fp8_f32(v6, v7, q.y, true);
    return q;
}

// ================= bucket-sort CSR pipeline (no global atomics) =================

// K1: dual per-block LDS histogram over 256-node buckets
__global__ void histo_kernel(const int* __restrict__ src, const int* __restrict__ dst,
                             int* __restrict__ bh_src, int* __restrict__ bh_dst,
                             int E, int NBK, int NBLK) {
    extern __shared__ int lds[];           // 2*NBK ints
    int* hs = lds;
    int* hd = lds + NBK;
    for (int j = threadIdx.x; j < 2 * NBK; j += 256) lds[j] = 0;
    __syncthreads();
    int b = blockIdx.x;
    int e0 = b * EPB, e1 = min(e0 + EPB, E);
    for (int e = e0 + threadIdx.x; e < e1; e += 256) {
        atomicAdd(&hs[src[e] >> 8], 1);
        atomicAdd(&hd[dst[e] >> 8], 1);
    }
    __syncthreads();
    for (int j = threadIdx.x; j < NBK; j += 256) {
        bh_src[j * NBLK + b] = hs[j];
        bh_dst[j * NBLK + b] = hd[j];
    }
}

// ---------------- prefix scan (3-kernel), exclusive into out[0..n] ----------------
__global__ void scan1_kernel(const int* __restrict__ deg, int* __restrict__ out,
                             int* __restrict__ bsums, int n) {
    __shared__ int sh[SCAN_BLK];
    int gid = blockIdx.x * SCAN_BLK + threadIdx.x;
    int v = (gid < n) ? deg[gid] : 0;
    sh[threadIdx.x] = v;
    __syncthreads();
    for (int off = 1; off < SCAN_BLK; off <<= 1) {
        int t = (threadIdx.x >= off) ? sh[threadIdx.x - off] : 0;
        __syncthreads();
        sh[threadIdx.x] += t;
        __syncthreads();
    }
    if (gid < n) out[gid + 1] = sh[threadIdx.x];
    if (threadIdx.x == SCAN_BLK - 1) bsums[blockIdx.x] = sh[threadIdx.x];
    if (gid == 0) out[0] = 0;
}

__global__ void scan2_kernel(int* __restrict__ bsums, int nb) {
    __shared__ int sh[SCAN_BLK];
    int v = (threadIdx.x < nb) ? bsums[threadIdx.x] : 0;
    sh[threadIdx.x] = v;
    __syncthreads();
    for (int off = 1; off < SCAN_BLK; off <<= 1) {
        int t = (threadIdx.x >= off) ? sh[threadIdx.x - off] : 0;
        __syncthreads();
        sh[threadIdx.x] += t;
        __syncthreads();
    }
    if (threadIdx.x < nb) bsums[threadIdx.x] = sh[threadIdx.x] - v;
}

__global__ void scan3_kernel(int* __restrict__ out, const int* __restrict__ bsums, int n) {
    int gid = blockIdx.x * SCAN_BLK + threadIdx.x;
    if (gid < n) out[gid + 1] += bsums[blockIdx.x];
}

// K3': scatter src ids into buckets (LDS cursors)
__global__ void scat_src_kernel(const int* __restrict__ src, const int* __restrict__ bhs_src,
                                int* __restrict__ srcb, int E, int NBK, int NBLK) {
    extern __shared__ int cur[];           // NBK ints
    int b = blockIdx.x;
    for (int j = threadIdx.x; j < NBK; j += 256) cur[j] = bhs_src[j * NBLK + b];
    __syncthreads();
    int e0 = b * EPB, e1 = min(e0 + EPB, E);
    for (int e = e0 + threadIdx.x; e < e1; e += 256) {
        int s = src[e];
        int pos = atomicAdd(&cur[s >> 8], 1);
        srcb[pos] = s;
    }
}

// K4': per-bucket LDS count of src -> ns
__global__ void ns_kernel(const int* __restrict__ srcb, const int* __restrict__ bhs_src,
                          float* __restrict__ ns, int n, int NBLK) {
    __shared__ int cnt[BKN];
    int b = blockIdx.x;
    int j = threadIdx.x;
    cnt[j] = 0;
    __syncthreads();
    int base = bhs_src[b * NBLK];
    int endp = bhs_src[(b + 1) * NBLK];
    for (int e = base + j; e < endp; e += 256)
        atomicAdd(&cnt[srcb[e] & 255], 1);
    __syncthreads();
    int node = b * BKN + j;
    if (node < n) {
        int c = cnt[j];
        ns[node] = (c > 0) ? rsqrtf((float)c) : 0.0f;
    }
}

// K3: scatter (dst,src) + coef into dst buckets (ns ready -> coef fused)
__global__ void scat_dst_kernel(const int* __restrict__ src, const int* __restrict__ dst,
                                const float* __restrict__ edata, const float* __restrict__ ns,
                                const float* __restrict__ mu, const float* __restrict__ sigma,
                                const int* __restrict__ bhs_dst, int2* __restrict__ pay,
                                float* __restrict__ payw, int E, int NBK, int NBLK) {
    extern __shared__ int cur[];           // NBK ints
    int b = blockIdx.x;
    for (int j = threadIdx.x; j < NBK; j += 256) cur[j] = bhs_dst[j * NBLK + b];
    __syncthreads();
    int e0 = b * EPB, e1 = min(e0 + EPB, E);
    for (int e = e0 + threadIdx.x; e < e1; e += 256) {
        int d = dst[e];
        int s = src[e];
        float ed = edata[e];
        float dd = ed - mu[0];
        float w = (ed == 1.0f) ? ed : expf(-(dd * dd) / sigma[0]);
        int pos = atomicAdd(&cur[d >> 8], 1);
        pay[pos] = make_int2(d, s);
        payw[pos] = ns[s] * w;
    }
}

// K4: per-bucket count + LDS scan -> rowptr, nd; place es (final CSR)
__global__ void csr_kernel(const int2* __restrict__ pay, const float* __restrict__ payw,
                           const int* __restrict__ bhs_dst, int* __restrict__ rowptr,
                           float* __restrict__ nd, int2* __restrict__ es,
                           int n, int E, int NBK, int NBLK) {
    __shared__ int cnt[BKN];
    __shared__ int cur[BKN];
    int b = blockIdx.x;
    int j = threadIdx.x;
    cnt[j] = 0;
    __syncthreads();
    int base = bhs_dst[b * NBLK];
    int endp = bhs_dst[(b + 1) * NBLK];
    for (int e = base + j; e < endp; e += 256)
        atomicAdd(&cnt[pay[e].x & 255], 1);
    __syncthreads();
    int c0 = cnt[j];
    // inclusive scan over 256
    for (int off = 1; off < 256; off <<= 1) {
        int t = (j >= off) ? cnt[j - off] : 0;
        __syncthreads();
        cnt[j] += t;
        __syncthreads();
    }
    int excl = cnt[j] - c0;
    cur[j] = base + excl;
    int node = b * BKN + j;
    if (node < n) {
        rowptr[node] = base + excl;
        nd[node] = (c0 > 0) ? rsqrtf((float)c0) : 0.0f;
    }
    if (b == NBK - 1 && j == 0) rowptr[n] = E;
    __syncthreads();
    for (int e = base + j; e < endp; e += 256) {
        int2 p = pay[e];
        int pos = atomicAdd(&cur[p.x & 255], 1);
        es[pos] = make_int2(p.y, __float_as_int(payw[e]));
    }
}

// ================= dense compute =================

// ---------------- x -> bf16 + fp8 ----------------
__global__ void x2bf_kernel(const float* __restrict__ x, unsigned short* __restrict__ o16,
                            unsigned char* __restrict__ o8, long long total4) {
    long long i = (long long)blockIdx.x * blockDim.x + threadIdx.x;
    if (i < total4) {
        float4 v = *reinterpret_cast<const float4*>(&x[i * 4]);
        uint2 p;
        p.x = pack2bf(v.x, v.y);
        p.y = pack2bf(v.z, v.w);
        *reinterpret_cast<uint2*>(&o16[i * 4]) = p;
        unsigned int q = __builtin_amdgcn_cvt_pk_fp8_f32(v.x, v.y, 0u, false);
        q = __builtin_amdgcn_cvt_pk_fp8_f32(v.z, v.w, q, true);
        *reinterpret_cast<unsigned int*>(&o8[i * 4]) = q;
    }
}

// ---------------- pack W (fp32, row-major FIxFO) -> bf16 MFMA B-fragment layout ----------------
__global__ void packW_kernel(const float* __restrict__ W, unsigned short* __restrict__ Wp,
                             int FI, int FO) {
    int KB = (FI + 31) / 32;
    int NB = FO / 16;
    int gid = blockIdx.x * blockDim.x + threadIdx.x;
    if (gid >= KB * NB * 64) return;
    int l = gid & 63;
    int tile = gid >> 6;
    int kb = tile % KB;
    int nb = tile / KB;
    int n = nb * 16 + (l & 15);
    int k0 = kb * 32 + (l >> 4) * 8;
    unsigned short tmp[8];
    #pragma unroll
    for (int j = 0; j < 8; ++j) {
        int k = k0 + j;
        tmp[j] = (k < FI) ? f2bf(W[(size_t)k * FO + n]) : (unsigned short)0;
    }
    *reinterpret_cast<uint4*>(&Wp[(size_t)gid * 8]) = *reinterpret_cast<uint4*>(tmp);
}

// ---------------- CSR gather-sum aggregation (fp8 in) ----------------
#define F8ACC(v, cc) { \
    auto p01 = __builtin_amdgcn_cvt_pk_f32_fp8((v).x, false); \
    auto p23 = __builtin_amdgcn_cvt_pk_f32_fp8((v).x, true);  \
    auto p45 = __builtin_amdgcn_cvt_pk_f32_fp8((v).y, false); \
    auto p67 = __builtin_amdgcn_cvt_pk_f32_fp8((v).y, true);  \
    a0 = fmaf(p01[0], cc, a0); a1 = fmaf(p01[1], cc, a1); \
    a2 = fmaf(p23[0], cc, a2); a3 = fmaf(p23[1], cc, a3); \
    a4 = fmaf(p45[0], cc, a4); a5 = fmaf(p45[1], cc, a5); \
    a6 = fmaf(p67[0], cc, a6); a7 = fmaf(p67[1], cc, a7); }

template<int MODE>
__global__ void agg_kernel(const unsigned char* __restrict__ h8,
                           const int* __restrict__ rowptr, const int2* __restrict__ es,
                           const float* __restrict__ nd, const float* __restrict__ bias,
                           unsigned short* __restrict__ out16, unsigned char* __restrict__ out8,
                           int n, int jt, int ng) {
    int g = threadIdx.x / jt;
    if (g >= ng) return;
    int i = blockIdx.x * ng + g;
    if (i >= n) return;
    int c = (threadIdx.x - g * jt) << 3;   // feature offset (8 per lane)
    int F = jt << 3;
    int beg = rowptr[i], end = rowptr[i + 1];
    float a0 = 0, a1 = 0, a2 = 0, a3 = 0, a4 = 0, a5 = 0, a6 = 0, a7 = 0;
    int e = beg;
    for (; e + 4 <= end; e += 4) {
        int2 e0 = es[e + 0], e1 = es[e + 1], e2 = es[e + 2], e3 = es[e + 3];
        uint2 v0 = *reinterpret_cast<const uint2*>(&h8[(size_t)e0.x * F + c]);
        uint2 v1 = *reinterpret_cast<const uint2*>(&h8[(size_t)e1.x * F + c]);
        uint2 v2 = *reinterpret_cast<const uint2*>(&h8[(size_t)e2.x * F + c]);
        uint2 v3 = *reinterpret_cast<const uint2*>(&h8[(size_t)e3.x * F + c]);
        float c0 = __int_as_float(e0.y), c1 = __int_as_float(e1.y);
        float c2 = __int_as_float(e2.y), c3 = __int_as_float(e3.y);
        F8ACC(v0, c0)
        F8ACC(v1, c1)
        F8ACC(v2, c2)
        F8ACC(v3, c3)
    }
    for (; e < end; ++e) {
        int2 e0 = es[e];
        uint2 v0 = *reinterpret_cast<const uint2*>(&h8[(size_t)e0.x * F + c]);
        float c0 = __int_as_float(e0.y);
        F8ACC(v0, c0)
    }
    if (MODE) {
        float s = nd[i];
        a0 = a0 * s + bias[c + 0]; a0 = LEAKY(a0);
        a1 = a1 * s + bias[c + 1]; a1 = LEAKY(a1);
        a2 = a2 * s + bias[c + 2]; a2 = LEAKY(a2);
        a3 = a3 * s + bias[c + 3]; a3 = LEAKY(a3);
        a4 = a4 * s + bias[c + 4]; a4 = LEAKY(a4);
        a5 = a5 * s + bias[c + 5]; a5 = LEAKY(a5);
        a6 = a6 * s + bias[c + 6]; a6 = LEAKY(a6);
        a7 = a7 * s + bias[c + 7]; a7 = LEAKY(a7);
    }
    uint4 p;
    p.x = pack2bf(a0, a1); p.y = pack2bf(a2, a3);
    p.z = pack2bf(a4, a5); p.w = pack2bf(a6, a7);
    *reinterpret_cast<uint4*>(&out16[(size_t)i * F + c]) = p;
    if (MODE) {
        uint2 q = pack8f8(a0, a1, a2, a3, a4, a5, a6, a7);
        *reinterpret_cast<uint2*>(&out8[(size_t)i * F + c]) = q;
    }
}

// ---------------- MFMA matmul: out[n x FO] = A[n x FI] @ W ----------------
template<int FI, int FO, int MODE>
__global__ __launch_bounds__(256) void mm_mfma_kernel(
    const unsigned short* __restrict__ Ab, const float* __restrict__ nd,
    const unsigned short* __restrict__ Wp, const float* __restrict__ bias,
    unsigned short* __restrict__ out16, unsigned char* __restrict__ out8, int n)
{
    constexpr int FIP = (FI + 31) / 32 * 32;
    constexpr int KB = FIP / 32;
    constexpr int NB = FO / 16;
    constexpr int LDA = FIP + 8;
    constexpr int RW = FIP / 8;
    __shared__ unsigned short As[64 * LDA];

    const int t = threadIdx.x;
    const int row0 = blockIdx.x * 64;

    for (int idx = t; idx < 64 * RW; idx += 256) {
        int r = idx / RW;
        int c8 = (idx - r * RW) * 8;
        int grow = row0 + r;
        uint4 v = make_uint4(0u, 0u, 0u, 0u);
        if (grow < n && c8 < FI)
            v = *reinterpret_cast<const uint4*>(&Ab[(size_t)grow * FI + c8]);
        *reinterpret_cast<uint4*>(&As[r * LDA + c8]) = v;
    }
    __syncthreads();

    const int w = t >> 6;
    const int l = t & 63;
    const int arow = (w << 4) + (l & 15);
    const int koff = (l >> 4) << 3;

    bf16x8 a[KB];
    #pragma unroll
    for (int kb = 0; kb < KB; ++kb)
        a[kb] = *reinterpret_cast<const bf16x8*>(&As[arow * LDA + kb * 32 + koff]);

    f32x4 acc[NB] = {};
    #pragma unroll
    for (int nb = 0; nb < NB; ++nb) {
        #pragma unroll
        for (int kb = 0; kb < KB; ++kb) {
            bf16x8 b = *reinterpret_cast<const bf16x8*>(&Wp[(size_t)((nb * KB + kb) * 64 + l) * 8]);
            acc[nb] = __builtin_amdgcn_mfma_f32_16x16x32_bf16(a[kb], b, acc[nb], 0, 0, 0);
        }
    }

    const int col = l & 15;
    const int rb = (l >> 4) << 2;
    #pragma unroll
    for (int r = 0; r < 4; ++r) {
        int grow = row0 + (w << 4) + rb + r;
        if (grow < n) {
            float s = MODE ? nd[grow] : 1.0f;
            #pragma unroll
            for (int nb = 0; nb < NB; ++nb) {
                float v = acc[nb][r];
                if (MODE) {
                    v = v * s + bias[nb * 16 + col];
                    v = LEAKY(v);
                    out16[(size_t)grow * FO + nb * 16 + col] = f2bf(v);
                    out8[(size_t)grow * FO + nb * 16 + col] = f2f8(v);
                } else {
                    out8[(size_t)grow * FO + nb * 16 + col] = f2f8(v);
                }
            }
        }
    }
}

// ---------------- mean over nodes (bf16 in, F=160) ----------------
__global__ void mean_kernel(const unsigned short* __restrict__ h, float* __restrict__ acc,
                            int n, int F) {
    int f = threadIdx.x;
    if (f >= F) return;
    float partial = 0.0f;
    for (int i = blockIdx.x; i < n; i += gridDim.x) {
        partial += __uint_as_float(((unsigned int)h[(size_t)i * F + f]) << 16);
    }
    atomicAdd(&acc[f], partial);
}

// ---------------- head ----------------
__global__ void head_kernel(const float* __restrict__ acc, const float* __restrict__ Wd1,
                            const float* __restrict__ bd1, const float* __restrict__ Wd2,
                            const float* __restrict__ bd2, float* __restrict__ out, int n) {
    __shared__ float gm[160];
    __shared__ float h1[140];
    int tid = threadIdx.x;
    if (tid < 160) {
        float v = acc[tid] / (float)n;
        gm[tid] = LEAKY(v);
    }
    __syncthreads();
    if (tid < 140) {
        float s = bd1[tid];
        for (int k = 0; k < 160; ++k) s += gm[k] * Wd1[k * 140 + tid];
        h1[tid] = LEAKY(s);
    }
    __syncthreads();
    if (tid < 2) {
        float s = bd2[tid];
        for (int k = 0; k < 140; ++k) s += h1[k] * Wd2[k * 2 + tid];
        out[tid] = 1.0f / (1.0f + expf(-s));
    }
}

extern "C" void kernel_launch(void* const* d_in, const int* in_sizes, int n_in,
                              void* d_out, int out_size, void* d_ws, size_t ws_size,
                              hipStream_t stream) {
    static const int dims[12] = {64, 80, 160, 112, 160, 176, 96, 144, 96, 128, 96, 160};

    const float* x     = (const float*)d_in[0];
    const int*   src   = (const int*)d_in[1];
    const int*   dst   = (const int*)d_in[2];
    const float* edata = (const float*)d_in[3];
    const float* W[11];
    const float* B[11];
    for (int i = 0; i < 11; ++i) {
        W[i] = (const float*)d_in[4 + 2 * i];
        B[i] = (const float*)d_in[5 + 2 * i];
    }
    const float* Wd1   = (const float*)d_in[26];
    const float* bd1   = (const float*)d_in[27];
    const float* Wd2   = (const float*)d_in[28];
    const float* bd2   = (const float*)d_in[29];
    const float* mu    = (const float*)d_in[30];
    const float* sigma = (const float*)d_in[31];
    float* out = (float*)d_out;

    const int N = in_sizes[0] / 64;
    const int E = in_sizes[1];
    const int FMAX = 176;

    const int NBK  = (N + BKN - 1) / BKN;           // buckets (256 nodes each)
    const int NBLK = (E + EPB - 1) / EPB;           // edge blocks
    const int LEN  = NBK * NBLK;                    // histogram entries

    // packed-W offsets (elements), K padded to 32
    size_t woff[11];
    size_t wtot = 0;
    for (int l = 0; l < 11; ++l) {
        woff[l] = wtot;
        int fip = (dims[l] + 31) / 32 * 32;
        wtot += (size_t)fip * dims[l + 1];
    }

    // workspace layout
    char* wsb = (char*)d_ws;
    size_t o = 0;
    auto alloc = [&](size_t bytes) { void* p = wsb + o; o += (bytes + 255) & ~(size_t)255; return p; };
    unsigned short* hb_main = (unsigned short*)alloc((size_t)N * FMAX * 2);
    unsigned short* hb_t    = (unsigned short*)alloc((size_t)N * FMAX * 2);
    unsigned char*  h8_main = (unsigned char*) alloc((size_t)N * FMAX);
    unsigned char*  h8_t    = (unsigned char*) alloc((size_t)N * FMAX);
    unsigned short* Wp  = (unsigned short*)alloc(wtot * 2);
    int2*  es      = (int2*) alloc((size_t)E * sizeof(int2));
    int2*  pay     = (int2*) alloc((size_t)E * sizeof(int2));
    float* payw    = (float*)alloc((size_t)E * sizeof(float));
    int*   srcb    = (int*)  alloc((size_t)E * sizeof(int));
    int*   bh_src  = (int*)  alloc((size_t)LEN * sizeof(int));
    int*   bhs_src = (int*)  alloc((size_t)(LEN + 1) * sizeof(int));
    int*   bh_dst  = (int*)  alloc((size_t)LEN * sizeof(int));
    int*   bhs_dst = (int*)  alloc((size_t)(LEN + 1) * sizeof(int));
    int*   rowptr  = (int*)  alloc((size_t)(N + 1) * sizeof(int));
    float* ns      = (float*)alloc((size_t)N * sizeof(float));
    float* nd      = (float*)alloc((size_t)N * sizeof(float));
    int*   bsums   = (int*)  alloc(2048 * sizeof(int));
    float* acc     = (float*)alloc(160 * sizeof(float));

    // ---- bucket-sort CSR pipeline ----
    histo_kernel<<<NBLK, 256, 2 * NBK * sizeof(int), stream>>>(src, dst, bh_src, bh_dst,
                                                               E, NBK, NBLK);
    int snb = (LEN + SCAN_BLK - 1) / SCAN_BLK;
    scan1_kernel<<<snb, SCAN_BLK, 0, stream>>>(bh_src, bhs_src, bsums, LEN);
    scan2_kernel<<<1, SCAN_BLK, 0, stream>>>(bsums, snb);
    scan3_kernel<<<snb, SCAN_BLK, 0, stream>>>(bhs_src, bsums, LEN);
    scan1_kernel<<<snb, SCAN_BLK, 0, stream>>>(bh_dst, bhs_dst, bsums, LEN);
    scan2_kernel<<<1, SCAN_BLK, 0, stream>>>(bsums, snb);
    scan3_kernel<<<snb, SCAN_BLK, 0, stream>>>(bhs_dst, bsums, LEN);
    scat_src_kernel<<<NBLK, 256, NBK * sizeof(int), stream>>>(src, bhs_src, srcb, E, NBK, NBLK);
    ns_kernel<<<NBK, 256, 0, stream>>>(srcb, bhs_src, ns, N, NBLK);
    scat_dst_kernel<<<NBLK, 256, NBK * sizeof(int), stream>>>(src, dst, edata, ns, mu, sigma,
                                                              bhs_dst, pay, payw, E, NBK, NBLK);
    csr_kernel<<<NBK, 256, 0, stream>>>(pay, payw, bhs_dst, rowptr, nd, es, N, E, NBK, NBLK);

    // ---- x -> bf16+fp8 ; W -> packed bf16 fragments ----
    long long x4 = (long long)N * 64 / 4;
    x2bf_kernel<<<(int)((x4 + 255) / 256), 256, 0, stream>>>(x, hb_main, h8_main, x4);
    for (int l = 0; l < 11; ++l) {
        int fip = (dims[l] + 31) / 32 * 32;
        int threads = (fip / 32) * (dims[l + 1] / 16) * 64;
        packW_kernel<<<(threads + 255) / 256, 256, 0, stream>>>(W[l], Wp + woff[l],
                                                                dims[l], dims[l + 1]);
    }

    // ---- 11 GCN layers (fixed buffer roles) ----
    const int mmgrid = (N + 63) / 64;

    #define DO_A(FI, FO, l) { \
        constexpr int jt = FI / 8; constexpr int ng = 256 / jt; \
        agg_kernel<0><<<(N + ng - 1) / ng, 256, 0, stream>>>( \
            h8_main, rowptr, es, nd, B[l], hb_t, nullptr, N, jt, ng); \
        mm_mfma_kernel<FI, FO, 1><<<mmgrid, 256, 0, stream>>>( \
            hb_t, nd, Wp + woff[l], B[l], hb_main, h8_main, N); }

    #define DO_B(FI, FO, l) { \
        mm_mfma_kernel<FI, FO, 0><<<mmgrid, 256, 0, stream>>>( \
            hb_main, nd, Wp + woff[l], B[l], nullptr, h8_t, N); \
        constexpr int jt = FO / 8; constexpr int ng = 256 / jt; \
        agg_kernel<1><<<(N + ng - 1) / ng, 256, 0, stream>>>( \
            h8_t, rowptr, es, nd, B[l], hb_main, h8_main, N, jt, ng); }

    DO_A(64, 80, 0)
    DO_A(80, 160, 1)
    DO_B(160, 112, 2)
    DO_A(112, 160, 3)
    DO_A(160, 176, 4)
    DO_B(176, 96, 5)
    DO_A(96, 144, 6)
    DO_B(144, 96, 7)
    DO_A(96, 128, 8)
    DO_B(128, 96, 9)
    DO_A(96, 160, 10)

    #undef DO_A
    #undef DO_B

    // ---- mean over nodes -> head ----
    hipMemsetAsync(acc, 0, 160 * sizeof(float), stream);
    mean_kernel<<<256, 160, 0, stream>>>(hb_main, acc, N, 160);
    head_kernel<<<1, 256, 0, stream>>>(acc, Wd1, bd1, Wd2, bd2, out, N);
}

// Round 9
// 1349.291 us; speedup vs baseline: 14.4546x; 1.0223x over previous
//
#include <hip/hip_runtime.h>

#define LEAKY(v) ((v) > 0.0f ? (v) : 0.01f * (v))
#define SCAN_BLK 1024
#define EPB 4096          // edges per block in bucket pipeline
#define BKN 256           // nodes per bucket

typedef __bf16 bf16x8 __attribute__((ext_vector_type(8)));
typedef float f32x4 __attribute__((ext_vector_type(4)));

// ---------------- bf16 helpers (RNE) ----------------
__device__ inline float bflo(unsigned int u) { return __uint_as_float(u << 16); }
__device__ inline float bfhi(unsigned int u) { return __uint_as_float(u & 0xFFFF0000u); }
__device__ inline unsigned int pack2bf(float lo, float hi) {
    unsigned int a = __float_as_uint(lo);
    unsigned int b = __float_as_uint(hi);
    a = (a + 0x7FFFu + ((a >> 16) & 1u)) >> 16;
    b = (b + 0x7FFFu + ((b >> 16) & 1u)) & 0xFFFF0000u;
    return a | b;
}
__device__ inline unsigned short f2bf(float f) {
    unsigned int u = __float_as_uint(f);
    return (unsigned short)((u + 0x7FFFu + ((u >> 16) & 1u)) >> 16);
}

// ---------------- fp8 e4m3 helpers (HW cvt, OCP on gfx950) ----------------
__device__ inline unsigned char f2f8(float v) {
    return (unsigned char)(__builtin_amdgcn_cvt_pk_fp8_f32(v, 0.0f, 0u, false) & 0xFFu);
}
__device__ inline uint2 pack8f8(float v0, float v1, float v2, float v3,
                                float v4, float v5, float v6, float v7) {
    uint2 q;
    q.x = __builtin_amdgcn_cvt_pk_fp8_f32(v0, v1, 0u, false);
    q.x = __builtin_amdgcn_cvt_pk_fp8_f32(v2, v3, q.x, true);
    q.y = __builtin_amdgcn_cvt_pk_fp8_f32(v4, v5, 0u, false);
    q.y = __builtin_amdgcn_cvt_pk_fp8_f32(v6, v7, q.y, true);
    return q;
}

// ================= bucket-sort CSR pipeline (no global atomics) =================

// K1: dual per-block LDS histogram over 256-node buckets
__global__ void histo_kernel(const int* __restrict__ src, const int* __restrict__ dst,
                             int* __restrict__ bh, int E, int NBK, int NBLK, int LEN) {
    extern __shared__ int lds[];           // 2*NBK ints
    int* hs = lds;
    int* hd = lds + NBK;
    for (int j = threadIdx.x; j < 2 * NBK; j += 512) lds[j] = 0;
    __syncthreads();
    int b = blockIdx.x;
    int e0 = b * EPB, e1 = min(e0 + EPB, E);
    for (int e = e0 + threadIdx.x; e < e1; e += 512) {
        atomicAdd(&hs[src[e] >> 8], 1);
        atomicAdd(&hd[dst[e] >> 8], 1);
    }
    __syncthreads();
    for (int j = threadIdx.x; j < NBK; j += 512) {
        bh[j * NBLK + b] = hs[j];
        bh[LEN + j * NBLK + b] = hd[j];
    }
}

// ---------------- prefix scan (3-kernel), exclusive into out[0..n] ----------------
__global__ void scan1_kernel(const int* __restrict__ deg, int* __restrict__ out,
                             int* __restrict__ bsums, int n) {
    __shared__ int sh[SCAN_BLK];
    int gid = blockIdx.x * SCAN_BLK + threadIdx.x;
    int v = (gid < n) ? deg[gid] : 0;
    sh[threadIdx.x] = v;
    __syncthreads();
    for (int off = 1; off < SCAN_BLK; off <<= 1) {
        int t = (threadIdx.x >= off) ? sh[threadIdx.x - off] : 0;
        __syncthreads();
        sh[threadIdx.x] += t;
        __syncthreads();
    }
    if (gid < n) out[gid + 1] = sh[threadIdx.x];
    if (threadIdx.x == SCAN_BLK - 1) bsums[blockIdx.x] = sh[threadIdx.x];
    if (gid == 0) out[0] = 0;
}

__global__ void scan2_kernel(int* __restrict__ bsums, int nb) {
    __shared__ int sh[SCAN_BLK];
    int v = (threadIdx.x < nb) ? bsums[threadIdx.x] : 0;
    sh[threadIdx.x] = v;
    __syncthreads();
    for (int off = 1; off < SCAN_BLK; off <<= 1) {
        int t = (threadIdx.x >= off) ? sh[threadIdx.x - off] : 0;
        __syncthreads();
        sh[threadIdx.x] += t;
        __syncthreads();
    }
    if (threadIdx.x < nb) bsums[threadIdx.x] = sh[threadIdx.x] - v;
}

__global__ void scan3_kernel(int* __restrict__ out, const int* __restrict__ bsums, int n) {
    int gid = blockIdx.x * SCAN_BLK + threadIdx.x;
    if (gid < n) out[gid + 1] += bsums[blockIdx.x];
}

// K3: merged scatter — src ids (1B) into src buckets, (s|(d&255)<<24, w) into dst buckets
__global__ void scat_kernel(const int* __restrict__ src, const int* __restrict__ dst,
                            const float* __restrict__ edata,
                            const float* __restrict__ mu, const float* __restrict__ sigma,
                            const int* __restrict__ bhs, unsigned char* __restrict__ srcb8,
                            int2* __restrict__ pay, int E, int NBK, int NBLK, int LEN) {
    extern __shared__ int cur[];           // 2*NBK ints
    int* cs = cur;
    int* cd = cur + NBK;
    int b = blockIdx.x;
    for (int j = threadIdx.x; j < NBK; j += 512) {
        cs[j] = bhs[j * NBLK + b];
        cd[j] = bhs[LEN + j * NBLK + b] - E;
    }
    __syncthreads();
    int e0 = b * EPB, e1 = min(e0 + EPB, E);
    for (int e = e0 + threadIdx.x; e < e1; e += 512) {
        int s = src[e];
        int d = dst[e];
        float ed = edata[e];
        float dd = ed - mu[0];
        float w = (ed == 1.0f) ? ed : expf(-(dd * dd) / sigma[0]);
        int ps = atomicAdd(&cs[s >> 8], 1);
        srcb8[ps] = (unsigned char)(s & 255);
        int pd = atomicAdd(&cd[d >> 8], 1);
        pay[pd] = make_int2(s | ((d & 255) << 24), __float_as_int(w));
    }
}

// K4': per-bucket count of src bytes -> ns
__global__ void ns_kernel(const unsigned char* __restrict__ srcb8, const int* __restrict__ bhs,
                          float* __restrict__ ns, int n, int NBLK) {
    __shared__ int cnt[BKN];
    int b = blockIdx.x;
    int j = threadIdx.x;
    cnt[j] = 0;
    __syncthreads();
    int base = bhs[b * NBLK];
    int endp = bhs[(b + 1) * NBLK];
    for (int e = base + j; e < endp; e += 256)
        atomicAdd(&cnt[srcb8[e]], 1);
    __syncthreads();
    int node = b * BKN + j;
    if (node < n) {
        int c = cnt[j];
        ns[node] = (c > 0) ? rsqrtf((float)c) : 0.0f;
    }
}

// K4: per-bucket count + LDS scan -> rowptr, nd; place es with coef = ns[s]*w
__global__ void csr_kernel(const int2* __restrict__ pay, const float* __restrict__ ns,
                           const int* __restrict__ bhs, int* __restrict__ rowptr,
                           float* __restrict__ nd, int2* __restrict__ es,
                           int n, int E, int NBK, int NBLK, int LEN) {
    __shared__ int cnt[BKN];
    __shared__ int cur[BKN];
    int b = blockIdx.x;
    int j = threadIdx.x;
    cnt[j] = 0;
    __syncthreads();
    int base = bhs[LEN + b * NBLK] - E;
    int endp = bhs[LEN + (b + 1) * NBLK] - E;
    for (int e = base + j; e < endp; e += 256)
        atomicAdd(&cnt[(pay[e].x >> 24) & 255], 1);
    __syncthreads();
    int c0 = cnt[j];
    for (int off = 1; off < 256; off <<= 1) {
        int t = (j >= off) ? cnt[j - off] : 0;
        __syncthreads();
        cnt[j] += t;
        __syncthreads();
    }
    int excl = cnt[j] - c0;
    cur[j] = base + excl;
    int node = b * BKN + j;
    if (node < n) {
        rowptr[node] = base + excl;
        nd[node] = (c0 > 0) ? rsqrtf((float)c0) : 0.0f;
    }
    if (b == NBK - 1 && j == 0) rowptr[n] = E;
    __syncthreads();
    for (int e = base + j; e < endp; e += 256) {
        int2 p = pay[e];
        int s = p.x & 0x00FFFFFF;
        float coef = ns[s] * __int_as_float(p.y);
        int pos = atomicAdd(&cur[(p.x >> 24) & 255], 1);
        es[pos] = make_int2(s, __float_as_int(coef));
    }
}

// ================= dense compute =================

// ---------------- x -> bf16 + fp8 ----------------
__global__ void x2bf_kernel(const float* __restrict__ x, unsigned short* __restrict__ o16,
                            unsigned char* __restrict__ o8, long long total4) {
    long long i = (long long)blockIdx.x * blockDim.x + threadIdx.x;
    if (i < total4) {
        float4 v = *reinterpret_cast<const float4*>(&x[i * 4]);
        uint2 p;
        p.x = pack2bf(v.x, v.y);
        p.y = pack2bf(v.z, v.w);
        *reinterpret_cast<uint2*>(&o16[i * 4]) = p;
        unsigned int q = __builtin_amdgcn_cvt_pk_fp8_f32(v.x, v.y, 0u, false);
        q = __builtin_amdgcn_cvt_pk_fp8_f32(v.z, v.w, q, true);
        *reinterpret_cast<unsigned int*>(&o8[i * 4]) = q;
    }
}

// ---------------- pack W (fp32, row-major FIxFO) -> bf16 MFMA B-fragment layout ----------------
__global__ void packW_kernel(const float* __restrict__ W, unsigned short* __restrict__ Wp,
                             int FI, int FO) {
    int KB = (FI + 31) / 32;
    int NB = FO / 16;
    int gid = blockIdx.x * blockDim.x + threadIdx.x;
    if (gid >= KB * NB * 64) return;
    int l = gid & 63;
    int tile = gid >> 6;
    int kb = tile % KB;
    int nb = tile / KB;
    int n = nb * 16 + (l & 15);
    int k0 = kb * 32 + (l >> 4) * 8;
    unsigned short tmp[8];
    #pragma unroll
    for (int j = 0; j < 8; ++j) {
        int k = k0 + j;
        tmp[j] = (k < FI) ? f2bf(W[(size_t)k * FO + n]) : (unsigned short)0;
    }
    *reinterpret_cast<uint4*>(&Wp[(size_t)gid * 8]) = *reinterpret_cast<uint4*>(tmp);
}

// ---------------- CSR gather-sum aggregation (fp8 in), 8-deep edge unroll ----------------
#define F8ACC(v, cc) { \
    auto p01 = __builtin_amdgcn_cvt_pk_f32_fp8((v).x, false); \
    auto p23 = __builtin_amdgcn_cvt_pk_f32_fp8((v).x, true);  \
    auto p45 = __builtin_amdgcn_cvt_pk_f32_fp8((v).y, false); \
    auto p67 = __builtin_amdgcn_cvt_pk_f32_fp8((v).y, true);  \
    a0 = fmaf(p01[0], cc, a0); a1 = fmaf(p01[1], cc, a1); \
    a2 = fmaf(p23[0], cc, a2); a3 = fmaf(p23[1], cc, a3); \
    a4 = fmaf(p45[0], cc, a4); a5 = fmaf(p45[1], cc, a5); \
    a6 = fmaf(p67[0], cc, a6); a7 = fmaf(p67[1], cc, a7); }

template<int MODE>
__global__ void agg_kernel(const unsigned char* __restrict__ h8,
                           const int* __restrict__ rowptr, const int2* __restrict__ es,
                           const float* __restrict__ nd, const float* __restrict__ bias,
                           unsigned short* __restrict__ out16, unsigned char* __restrict__ out8,
                           int n, int jt, int ng) {
    int g = threadIdx.x / jt;
    if (g >= ng) return;
    int i = blockIdx.x * ng + g;
    if (i >= n) return;
    int c = (threadIdx.x - g * jt) << 3;   // feature offset (8 per lane)
    int F = jt << 3;
    int beg = rowptr[i], end = rowptr[i + 1];
    float a0 = 0, a1 = 0, a2 = 0, a3 = 0, a4 = 0, a5 = 0, a6 = 0, a7 = 0;
    int e = beg;
    for (; e + 8 <= end; e += 8) {
        int2 ee[8];
        uint2 vv[8];
        #pragma unroll
        for (int q = 0; q < 8; ++q) ee[q] = es[e + q];
        #pragma unroll
        for (int q = 0; q < 8; ++q)
            vv[q] = *reinterpret_cast<const uint2*>(&h8[(size_t)ee[q].x * F + c]);
        #pragma unroll
        for (int q = 0; q < 8; ++q) {
            float cc = __int_as_float(ee[q].y);
            F8ACC(vv[q], cc)
        }
    }
    for (; e < end; ++e) {
        int2 e0 = es[e];
        uint2 v0 = *reinterpret_cast<const uint2*>(&h8[(size_t)e0.x * F + c]);
        float c0 = __int_as_float(e0.y);
        F8ACC(v0, c0)
    }
    if (MODE) {
        float s = nd[i];
        a0 = a0 * s + bias[c + 0]; a0 = LEAKY(a0);
        a1 = a1 * s + bias[c + 1]; a1 = LEAKY(a1);
        a2 = a2 * s + bias[c + 2]; a2 = LEAKY(a2);
        a3 = a3 * s + bias[c + 3]; a3 = LEAKY(a3);
        a4 = a4 * s + bias[c + 4]; a4 = LEAKY(a4);
        a5 = a5 * s + bias[c + 5]; a5 = LEAKY(a5);
        a6 = a6 * s + bias[c + 6]; a6 = LEAKY(a6);
        a7 = a7 * s + bias[c + 7]; a7 = LEAKY(a7);
    }
    uint4 p;
    p.x = pack2bf(a0, a1); p.y = pack2bf(a2, a3);
    p.z = pack2bf(a4, a5); p.w = pack2bf(a6, a7);
    *reinterpret_cast<uint4*>(&out16[(size_t)i * F + c]) = p;
    if (MODE) {
        uint2 q = pack8f8(a0, a1, a2, a3, a4, a5, a6, a7);
        *reinterpret_cast<uint2*>(&out8[(size_t)i * F + c]) = q;
    }
}

// ---------------- MFMA matmul: out[n x FO] = A[n x FI] @ W ----------------
template<int FI, int FO, int MODE>
__global__ __launch_bounds__(256) void mm_mfma_kernel(
    const unsigned short* __restrict__ Ab, const float* __restrict__ nd,
    const unsigned short* __restrict__ Wp, const float* __restrict__ bias,
    unsigned short* __restrict__ out16, unsigned char* __restrict__ out8, int n)
{
    constexpr int FIP = (FI + 31) / 32 * 32;
    constexpr int KB = FIP / 32;
    constexpr int NB = FO / 16;
    constexpr int LDA = FIP + 8;
    constexpr int RW = FIP / 8;
    __shared__ unsigned short As[64 * LDA];

    const int t = threadIdx.x;
    const int row0 = blockIdx.x * 64;

    for (int idx = t; idx < 64 * RW; idx += 256) {
        int r = idx / RW;
        int c8 = (idx - r * RW) * 8;
        int grow = row0 + r;
        uint4 v = make_uint4(0u, 0u, 0u, 0u);
        if (grow < n && c8 < FI)
            v = *reinterpret_cast<const uint4*>(&Ab[(size_t)grow * FI + c8]);
        *reinterpret_cast<uint4*>(&As[r * LDA + c8]) = v;
    }
    __syncthreads();

    const int w = t >> 6;
    const int l = t & 63;
    const int arow = (w << 4) + (l & 15);
    const int koff = (l >> 4) << 3;

    bf16x8 a[KB];
    #pragma unroll
    for (int kb = 0; kb < KB; ++kb)
        a[kb] = *reinterpret_cast<const bf16x8*>(&As[arow * LDA + kb * 32 + koff]);

    f32x4 acc[NB] = {};
    #pragma unroll
    for (int nb = 0; nb < NB; ++nb) {
        #pragma unroll
        for (int kb = 0; kb < KB; ++kb) {
            bf16x8 b = *reinterpret_cast<const bf16x8*>(&Wp[(size_t)((nb * KB + kb) * 64 + l) * 8]);
            acc[nb] = __builtin_amdgcn_mfma_f32_16x16x32_bf16(a[kb], b, acc[nb], 0, 0, 0);
        }
    }

    const int col = l & 15;
    const int rb = (l >> 4) << 2;
    #pragma unroll
    for (int r = 0; r < 4; ++r) {
        int grow = row0 + (w << 4) + rb + r;
        if (grow < n) {
            float s = MODE ? nd[grow] : 1.0f;
            #pragma unroll
            for (int nb = 0; nb < NB; ++nb) {
                float v = acc[nb][r];
                if (MODE) {
                    v = v * s + bias[nb * 16 + col];
                    v = LEAKY(v);
                    out16[(size_t)grow * FO + nb * 16 + col] = f2bf(v);
                    out8[(size_t)grow * FO + nb * 16 + col] = f2f8(v);
                } else {
                    out8[(size_t)grow * FO + nb * 16 + col] = f2f8(v);
                }
            }
        }
    }
}

// ---------------- mean over nodes (bf16 in, F=160) ----------------
__global__ void mean_kernel(const unsigned short* __restrict__ h, float* __restrict__ acc,
                            int n, int F) {
    int f = threadIdx.x;
    if (f >= F) return;
    float partial = 0.0f;
    for (int i = blockIdx.x; i < n; i += gridDim.x) {
        partial += __uint_as_float(((unsigned int)h[(size_t)i * F + f]) << 16);
    }
    atomicAdd(&acc[f], partial);
}

// ---------------- head ----------------
__global__ void head_kernel(const float* __restrict__ acc, const float* __restrict__ Wd1,
                            const float* __restrict__ bd1, const float* __restrict__ Wd2,
                            const float* __restrict__ bd2, float* __restrict__ out, int n) {
    __shared__ float gm[160];
    __shared__ float h1[140];
    int tid = threadIdx.x;
    if (tid < 160) {
        float v = acc[tid] / (float)n;
        gm[tid] = LEAKY(v);
    }
    __syncthreads();
    if (tid < 140) {
        float s = bd1[tid];
        for (int k = 0; k < 160; ++k) s += gm[k] * Wd1[k * 140 + tid];
        h1[tid] = LEAKY(s);
    }
    __syncthreads();
    if (tid < 2) {
        float s = bd2[tid];
        for (int k = 0; k < 140; ++k) s += h1[k] * Wd2[k * 2 + tid];
        out[tid] = 1.0f / (1.0f + expf(-s));
    }
}

extern "C" void kernel_launch(void* const* d_in, const int* in_sizes, int n_in,
                              void* d_out, int out_size, void* d_ws, size_t ws_size,
                              hipStream_t stream) {
    static const int dims[12] = {64, 80, 160, 112, 160, 176, 96, 144, 96, 128, 96, 160};

    const float* x     = (const float*)d_in[0];
    const int*   src   = (const int*)d_in[1];
    const int*   dst   = (const int*)d_in[2];
    const float* edata = (const float*)d_in[3];
    const float* W[11];
    const float* B[11];
    for (int i = 0; i < 11; ++i) {
        W[i] = (const float*)d_in[4 + 2 * i];
        B[i] = (const float*)d_in[5 + 2 * i];
    }
    const float* Wd1   = (const float*)d_in[26];
    const float* bd1   = (const float*)d_in[27];
    const float* Wd2   = (const float*)d_in[28];
    const float* bd2   = (const float*)d_in[29];
    const float* mu    = (const float*)d_in[30];
    const float* sigma = (const float*)d_in[31];
    float* out = (float*)d_out;

    const int N = in_sizes[0] / 64;
    const int E = in_sizes[1];
    const int FMAX = 176;

    const int NBK  = (N + BKN - 1) / BKN;           // buckets (256 nodes each)
    const int NBLK = (E + EPB - 1) / EPB;           // edge blocks
    const int LEN  = NBK * NBLK;                    // histogram entries per side

    // packed-W offsets (elements), K padded to 32
    size_t woff[11];
    size_t wtot = 0;
    for (int l = 0; l < 11; ++l) {
        woff[l] = wtot;
        int fip = (dims[l] + 31) / 32 * 32;
        wtot += (size_t)fip * dims[l + 1];
    }

    // workspace layout
    char* wsb = (char*)d_ws;
    size_t o = 0;
    auto alloc = [&](size_t bytes) { void* p = wsb + o; o += (bytes + 255) & ~(size_t)255; return p; };
    unsigned short* hb_main = (unsigned short*)alloc((size_t)N * FMAX * 2);
    unsigned short* hb_t    = (unsigned short*)alloc((size_t)N * FMAX * 2);
    unsigned char*  h8_main = (unsigned char*) alloc((size_t)N * FMAX);
    unsigned char*  h8_t    = (unsigned char*) alloc((size_t)N * FMAX);
    unsigned short* Wp  = (unsigned short*)alloc(wtot * 2);
    int2*  es      = (int2*) alloc((size_t)E * sizeof(int2));
    int2*  pay     = (int2*) alloc((size_t)E * sizeof(int2));
    unsigned char* srcb8 = (unsigned char*)alloc((size_t)E);
    int*   bh      = (int*)  alloc((size_t)(2 * LEN) * sizeof(int));
    int*   bhs     = (int*)  alloc((size_t)(2 * LEN + 1) * sizeof(int));
    int*   rowptr  = (int*)  alloc((size_t)(N + 1) * sizeof(int));
    float* ns      = (float*)alloc((size_t)N * sizeof(float));
    float* nd      = (float*)alloc((size_t)N * sizeof(float));
    int*   bsums   = (int*)  alloc(2048 * sizeof(int));
    float* acc     = (float*)alloc(160 * sizeof(float));

    // ---- bucket-sort CSR pipeline ----
    histo_kernel<<<NBLK, 512, 2 * NBK * sizeof(int), stream>>>(src, dst, bh, E, NBK, NBLK, LEN);
    int snb = (2 * LEN + SCAN_BLK - 1) / SCAN_BLK;
    scan1_kernel<<<snb, SCAN_BLK, 0, stream>>>(bh, bhs, bsums, 2 * LEN);
    scan2_kernel<<<1, SCAN_BLK, 0, stream>>>(bsums, snb);
    scan3_kernel<<<snb, SCAN_BLK, 0, stream>>>(bhs, bsums, 2 * LEN);
    scat_kernel<<<NBLK, 512, 2 * NBK * sizeof(int), stream>>>(src, dst, edata, mu, sigma,
                                                              bhs, srcb8, pay, E, NBK, NBLK, LEN);
    ns_kernel<<<NBK, 256, 0, stream>>>(srcb8, bhs, ns, N, NBLK);
    csr_kernel<<<NBK, 256, 0, stream>>>(pay, ns, bhs, rowptr, nd, es, N, E, NBK, NBLK, LEN);

    // ---- x -> bf16+fp8 ; W -> packed bf16 fragments ----
    long long x4 = (long long)N * 64 / 4;
    x2bf_kernel<<<(int)((x4 + 255) / 256), 256, 0, stream>>>(x, hb_main, h8_main, x4);
    for (int l = 0; l < 11; ++l) {
        int fip = (dims[l] + 31) / 32 * 32;
        int threads = (fip / 32) * (dims[l + 1] / 16) * 64;
        packW_kernel<<<(threads + 255) / 256, 256, 0, stream>>>(W[l], Wp + woff[l],
                                                                dims[l], dims[l + 1]);
    }

    // ---- 11 GCN layers (fixed buffer roles) ----
    const int mmgrid = (N + 63) / 64;

    #define DO_A(FI, FO, l) { \
        constexpr int jt = FI / 8; constexpr int ng = 256 / jt; \
        agg_kernel<0><<<(N + ng - 1) / ng, 256, 0, stream>>>( \
            h8_main, rowptr, es, nd, B[l], hb_t, nullptr, N, jt, ng); \
        mm_mfma_kernel<FI, FO, 1><<<mmgrid, 256, 0, stream>>>( \
            hb_t, nd, Wp + woff[l], B[l], hb_main, h8_main, N); }

    #define DO_B(FI, FO, l) { \
        mm_mfma_kernel<FI, FO, 0><<<mmgrid, 256, 0, stream>>>( \
            hb_main, nd, Wp + woff[l], B[l], nullptr, h8_t, N); \
        constexpr int jt = FO / 8; constexpr int ng = 256 / jt; \
        agg_kernel<1><<<(N + ng - 1) / ng, 256, 0, stream>>>( \
            h8_t, rowptr, es, nd, B[l], hb_main, h8_main, N, jt, ng); }

    DO_A(64, 80, 0)
    DO_A(80, 160, 1)
    DO_B(160, 112, 2)
    DO_A(112, 160, 3)
    DO_A(160, 176, 4)
    DO_B(176, 96, 5)
    DO_A(96, 144, 6)
    DO_B(144, 96, 7)
    DO_A(96, 128, 8)
    DO_B(128, 96, 9)
    DO_A(96, 160, 10)

    #undef DO_A
    #undef DO_B

    // ---- mean over nodes -> head ----
    hipMemsetAsync(acc, 0, 160 * sizeof(float), stream);
    mean_kernel<<<256, 160, 0, stream>>>(hb_main, acc, N, 160);
    head_kernel<<<1, 256, 0, stream>>>(acc, Wd1, bd1, Wd2, bd2, out, N);
}

// Round 10
// 1346.324 us; speedup vs baseline: 14.4864x; 1.0022x over previous
//
#include <hip/hip_runtime.h>

#define LEAKY(v) ((v) > 0.0f ? (v) : 0.01f * (v))
#define SCAN_BLK 1024
#define EPB 4096          // edges per block in bucket pipeline
#define BKN 256           // nodes per bucket

typedef __bf16 bf16x8 __attribute__((ext_vector_type(8)));
typedef float f32x4 __attribute__((ext_vector_type(4)));

// ---------------- bf16 helpers (RNE) ----------------
__device__ inline float bflo(unsigned int u) { return __uint_as_float(u << 16); }
__device__ inline float bfhi(unsigned int u) { return __uint_as_float(u & 0xFFFF0000u); }
__device__ inline unsigned int pack2bf(float lo, float hi) {
    unsigned int a = __float_as_uint(lo);
    unsigned int b = __float_as_uint(hi);
    a = (a + 0x7FFFu + ((a >> 16) & 1u)) >> 16;
    b = (b + 0x7FFFu + ((b >> 16) & 1u)) & 0xFFFF0000u;
    return a | b;
}
__device__ inline unsigned short f2bf(float f) {
    unsigned int u = __float_as_uint(f);
    return (unsigned short)((u + 0x7FFFu + ((u >> 16) & 1u)) >> 16);
}

// ---------------- fp8 e4m3 helpers (HW cvt, OCP on gfx950) ----------------
__device__ inline unsigned char f2f8(float v) {
    return (unsigned char)(__builtin_amdgcn_cvt_pk_fp8_f32(v, 0.0f, 0u, false) & 0xFFu);
}

// ================= bucket-sort CSR pipeline (no global atomics) =================

__global__ void histo_kernel(const int* __restrict__ src, const int* __restrict__ dst,
                             int* __restrict__ bh, int E, int NBK, int NBLK, int LEN) {
    extern __shared__ int lds[];           // 2*NBK ints
    int* hs = lds;
    int* hd = lds + NBK;
    for (int j = threadIdx.x; j < 2 * NBK; j += 512) lds[j] = 0;
    __syncthreads();
    int b = blockIdx.x;
    int e0 = b * EPB, e1 = min(e0 + EPB, E);
    for (int e = e0 + threadIdx.x; e < e1; e += 512) {
        atomicAdd(&hs[src[e] >> 8], 1);
        atomicAdd(&hd[dst[e] >> 8], 1);
    }
    __syncthreads();
    for (int j = threadIdx.x; j < NBK; j += 512) {
        bh[j * NBLK + b] = hs[j];
        bh[LEN + j * NBLK + b] = hd[j];
    }
}

__global__ void scan1_kernel(const int* __restrict__ deg, int* __restrict__ out,
                             int* __restrict__ bsums, int n) {
    __shared__ int sh[SCAN_BLK];
    int gid = blockIdx.x * SCAN_BLK + threadIdx.x;
    int v = (gid < n) ? deg[gid] : 0;
    sh[threadIdx.x] = v;
    __syncthreads();
    for (int off = 1; off < SCAN_BLK; off <<= 1) {
        int t = (threadIdx.x >= off) ? sh[threadIdx.x - off] : 0;
        __syncthreads();
        sh[threadIdx.x] += t;
        __syncthreads();
    }
    if (gid < n) out[gid + 1] = sh[threadIdx.x];
    if (threadIdx.x == SCAN_BLK - 1) bsums[blockIdx.x] = sh[threadIdx.x];
    if (gid == 0) out[0] = 0;
}

__global__ void scan2_kernel(int* __restrict__ bsums, int nb) {
    __shared__ int sh[SCAN_BLK];
    int v = (threadIdx.x < nb) ? bsums[threadIdx.x] : 0;
    sh[threadIdx.x] = v;
    __syncthreads();
    for (int off = 1; off < SCAN_BLK; off <<= 1) {
        int t = (threadIdx.x >= off) ? sh[threadIdx.x - off] : 0;
        __syncthreads();
        sh[threadIdx.x] += t;
        __syncthreads();
    }
    if (threadIdx.x < nb) bsums[threadIdx.x] = sh[threadIdx.x] - v;
}

__global__ void scan3_kernel(int* __restrict__ out, const int* __restrict__ bsums, int n) {
    int gid = blockIdx.x * SCAN_BLK + threadIdx.x;
    if (gid < n) out[gid + 1] += bsums[blockIdx.x];
}

__global__ void scat_kernel(const int* __restrict__ src, const int* __restrict__ dst,
                            const float* __restrict__ edata,
                            const float* __restrict__ mu, const float* __restrict__ sigma,
                            const int* __restrict__ bhs, unsigned char* __restrict__ srcb8,
                            int2* __restrict__ pay, int E, int NBK, int NBLK, int LEN) {
    extern __shared__ int cur[];           // 2*NBK ints
    int* cs = cur;
    int* cd = cur + NBK;
    int b = blockIdx.x;
    for (int j = threadIdx.x; j < NBK; j += 512) {
        cs[j] = bhs[j * NBLK + b];
        cd[j] = bhs[LEN + j * NBLK + b] - E;
    }
    __syncthreads();
    int e0 = b * EPB, e1 = min(e0 + EPB, E);
    for (int e = e0 + threadIdx.x; e < e1; e += 512) {
        int s = src[e];
        int d = dst[e];
        float ed = edata[e];
        float dd = ed - mu[0];
        float w = (ed == 1.0f) ? ed : expf(-(dd * dd) / sigma[0]);
        int ps = atomicAdd(&cs[s >> 8], 1);
        srcb8[ps] = (unsigned char)(s & 255);
        int pd = atomicAdd(&cd[d >> 8], 1);
        pay[pd] = make_int2(s | ((d & 255) << 24), __float_as_int(w));
    }
}

__global__ void ns_kernel(const unsigned char* __restrict__ srcb8, const int* __restrict__ bhs,
                          float* __restrict__ ns, int n, int NBLK) {
    __shared__ int cnt[BKN];
    int b = blockIdx.x;
    int j = threadIdx.x;
    cnt[j] = 0;
    __syncthreads();
    int base = bhs[b * NBLK];
    int endp = bhs[(b + 1) * NBLK];
    for (int e = base + j; e < endp; e += 256)
        atomicAdd(&cnt[srcb8[e]], 1);
    __syncthreads();
    int node = b * BKN + j;
    if (node < n) {
        int c = cnt[j];
        ns[node] = (c > 0) ? rsqrtf((float)c) : 0.0f;
    }
}

__global__ void csr_kernel(const int2* __restrict__ pay, const float* __restrict__ ns,
                           const int* __restrict__ bhs, int* __restrict__ rowptr,
                           float* __restrict__ nd, int2* __restrict__ es,
                           int n, int E, int NBK, int NBLK, int LEN) {
    __shared__ int cnt[BKN];
    __shared__ int cur[BKN];
    int b = blockIdx.x;
    int j = threadIdx.x;
    cnt[j] = 0;
    __syncthreads();
    int base = bhs[LEN + b * NBLK] - E;
    int endp = bhs[LEN + (b + 1) * NBLK] - E;
    for (int e = base + j; e < endp; e += 256)
        atomicAdd(&cnt[(pay[e].x >> 24) & 255], 1);
    __syncthreads();
    int c0 = cnt[j];
    for (int off = 1; off < 256; off <<= 1) {
        int t = (j >= off) ? cnt[j - off] : 0;
        __syncthreads();
        cnt[j] += t;
        __syncthreads();
    }
    int excl = cnt[j] - c0;
    cur[j] = base + excl;
    int node = b * BKN + j;
    if (node < n) {
        rowptr[node] = base + excl;
        nd[node] = (c0 > 0) ? rsqrtf((float)c0) : 0.0f;
    }
    if (b == NBK - 1 && j == 0) rowptr[n] = E;
    __syncthreads();
    for (int e = base + j; e < endp; e += 256) {
        int2 p = pay[e];
        int s = p.x & 0x00FFFFFF;
        float coef = ns[s] * __int_as_float(p.y);
        int pos = atomicAdd(&cur[(p.x >> 24) & 255], 1);
        es[pos] = make_int2(s, __float_as_int(coef));
    }
}

// ================= dense compute =================

__global__ void x2bf_kernel(const float* __restrict__ x, unsigned short* __restrict__ o16,
                            unsigned char* __restrict__ o8, long long total4) {
    long long i = (long long)blockIdx.x * blockDim.x + threadIdx.x;
    if (i < total4) {
        float4 v = *reinterpret_cast<const float4*>(&x[i * 4]);
        uint2 p;
        p.x = pack2bf(v.x, v.y);
        p.y = pack2bf(v.z, v.w);
        *reinterpret_cast<uint2*>(&o16[i * 4]) = p;
        unsigned int q = __builtin_amdgcn_cvt_pk_fp8_f32(v.x, v.y, 0u, false);
        q = __builtin_amdgcn_cvt_pk_fp8_f32(v.z, v.w, q, true);
        *reinterpret_cast<unsigned int*>(&o8[i * 4]) = q;
    }
}

__global__ void packW_kernel(const float* __restrict__ W, unsigned short* __restrict__ Wp,
                             int FI, int FO) {
    int KB = (FI + 31) / 32;
    int NB = FO / 16;
    int gid = blockIdx.x * blockDim.x + threadIdx.x;
    if (gid >= KB * NB * 64) return;
    int l = gid & 63;
    int tile = gid >> 6;
    int kb = tile % KB;
    int nb = tile / KB;
    int n = nb * 16 + (l & 15);
    int k0 = kb * 32 + (l >> 4) * 8;
    unsigned short tmp[8];
    #pragma unroll
    for (int j = 0; j < 8; ++j) {
        int k = k0 + j;
        tmp[j] = (k < FI) ? f2bf(W[(size_t)k * FO + n]) : (unsigned short)0;
    }
    *reinterpret_cast<uint4*>(&Wp[(size_t)gid * 8]) = *reinterpret_cast<uint4*>(tmp);
}

// ---------------- CSR gather-sum aggregation (fp8 in), 16 features/lane ----------------
// lane covers 16 features (uint4 = 16 fp8), 4-deep edge unroll.
#define F8ACC16(v, cc) { \
    auto q0 = __builtin_amdgcn_cvt_pk_f32_fp8((v).x, false); \
    auto q1 = __builtin_amdgcn_cvt_pk_f32_fp8((v).x, true);  \
    auto q2 = __builtin_amdgcn_cvt_pk_f32_fp8((v).y, false); \
    auto q3 = __builtin_amdgcn_cvt_pk_f32_fp8((v).y, true);  \
    auto q4 = __builtin_amdgcn_cvt_pk_f32_fp8((v).z, false); \
    auto q5 = __builtin_amdgcn_cvt_pk_f32_fp8((v).z, true);  \
    auto q6 = __builtin_amdgcn_cvt_pk_f32_fp8((v).w, false); \
    auto q7 = __builtin_amdgcn_cvt_pk_f32_fp8((v).w, true);  \
    a[0] = fmaf(q0[0], cc, a[0]);  a[1] = fmaf(q0[1], cc, a[1]); \
    a[2] = fmaf(q1[0], cc, a[2]);  a[3] = fmaf(q1[1], cc, a[3]); \
    a[4] = fmaf(q2[0], cc, a[4]);  a[5] = fmaf(q2[1], cc, a[5]); \
    a[6] = fmaf(q3[0], cc, a[6]);  a[7] = fmaf(q3[1], cc, a[7]); \
    a[8] = fmaf(q4[0], cc, a[8]);  a[9] = fmaf(q4[1], cc, a[9]); \
    a[10] = fmaf(q5[0], cc, a[10]); a[11] = fmaf(q5[1], cc, a[11]); \
    a[12] = fmaf(q6[0], cc, a[12]); a[13] = fmaf(q6[1], cc, a[13]); \
    a[14] = fmaf(q7[0], cc, a[14]); a[15] = fmaf(q7[1], cc, a[15]); }

template<int MODE>
__global__ void agg_kernel(const unsigned char* __restrict__ h8,
                           const int* __restrict__ rowptr, const int2* __restrict__ es,
                           const float* __restrict__ nd, const float* __restrict__ bias,
                           unsigned short* __restrict__ out16, unsigned char* __restrict__ out8,
                           int n, int jt, int ng) {
    int g = threadIdx.x / jt;
    if (g >= ng) return;
    int i = blockIdx.x * ng + g;
    if (i >= n) return;
    int c = (threadIdx.x - g * jt) << 4;   // feature offset (16 per lane)
    int F = jt << 4;
    int beg = rowptr[i], end = rowptr[i + 1];
    float a[16] = {};
    int e = beg;
    for (; e + 4 <= end; e += 4) {
        int2 e0 = es[e + 0], e1 = es[e + 1], e2 = es[e + 2], e3 = es[e + 3];
        uint4 v0 = *reinterpret_cast<const uint4*>(&h8[(size_t)e0.x * F + c]);
        uint4 v1 = *reinterpret_cast<const uint4*>(&h8[(size_t)e1.x * F + c]);
        uint4 v2 = *reinterpret_cast<const uint4*>(&h8[(size_t)e2.x * F + c]);
        uint4 v3 = *reinterpret_cast<const uint4*>(&h8[(size_t)e3.x * F + c]);
        float c0 = __int_as_float(e0.y), c1 = __int_as_float(e1.y);
        float c2 = __int_as_float(e2.y), c3 = __int_as_float(e3.y);
        F8ACC16(v0, c0)
        F8ACC16(v1, c1)
        F8ACC16(v2, c2)
        F8ACC16(v3, c3)
    }
    for (; e < end; ++e) {
        int2 e0 = es[e];
        uint4 v0 = *reinterpret_cast<const uint4*>(&h8[(size_t)e0.x * F + c]);
        float c0 = __int_as_float(e0.y);
        F8ACC16(v0, c0)
    }
    if (MODE) {
        float s = nd[i];
        #pragma unroll
        for (int j = 0; j < 16; ++j) {
            float v = a[j] * s + bias[c + j];
            a[j] = LEAKY(v);
        }
    }
    uint4 p0, p1;
    p0.x = pack2bf(a[0], a[1]);   p0.y = pack2bf(a[2], a[3]);
    p0.z = pack2bf(a[4], a[5]);   p0.w = pack2bf(a[6], a[7]);
    p1.x = pack2bf(a[8], a[9]);   p1.y = pack2bf(a[10], a[11]);
    p1.z = pack2bf(a[12], a[13]); p1.w = pack2bf(a[14], a[15]);
    *reinterpret_cast<uint4*>(&out16[(size_t)i * F + c]) = p0;
    *reinterpret_cast<uint4*>(&out16[(size_t)i * F + c + 8]) = p1;
    if (MODE) {
        uint4 q;
        q.x = __builtin_amdgcn_cvt_pk_fp8_f32(a[0], a[1], 0u, false);
        q.x = __builtin_amdgcn_cvt_pk_fp8_f32(a[2], a[3], q.x, true);
        q.y = __builtin_amdgcn_cvt_pk_fp8_f32(a[4], a[5], 0u, false);
        q.y = __builtin_amdgcn_cvt_pk_fp8_f32(a[6], a[7], q.y, true);
        q.z = __builtin_amdgcn_cvt_pk_fp8_f32(a[8], a[9], 0u, false);
        q.z = __builtin_amdgcn_cvt_pk_fp8_f32(a[10], a[11], q.z, true);
        q.w = __builtin_amdgcn_cvt_pk_fp8_f32(a[12], a[13], 0u, false);
        q.w = __builtin_amdgcn_cvt_pk_fp8_f32(a[14], a[15], q.w, true);
        *reinterpret_cast<uint4*>(&out8[(size_t)i * F + c]) = q;
    }
}

// ---------------- MFMA matmul: out[n x FO] = A[n x FI] @ W ----------------
template<int FI, int FO, int MODE>
__global__ __launch_bounds__(256) void mm_mfma_kernel(
    const unsigned short* __restrict__ Ab, const float* __restrict__ nd,
    const unsigned short* __restrict__ Wp, const float* __restrict__ bias,
    unsigned short* __restrict__ out16, unsigned char* __restrict__ out8, int n)
{
    constexpr int FIP = (FI + 31) / 32 * 32;
    constexpr int KB = FIP / 32;
    constexpr int NB = FO / 16;
    constexpr int LDA = FIP + 8;
    constexpr int RW = FIP / 8;
    __shared__ unsigned short As[64 * LDA];

    const int t = threadIdx.x;
    const int row0 = blockIdx.x * 64;

    for (int idx = t; idx < 64 * RW; idx += 256) {
        int r = idx / RW;
        int c8 = (idx - r * RW) * 8;
        int grow = row0 + r;
        uint4 v = make_uint4(0u, 0u, 0u, 0u);
        if (grow < n && c8 < FI)
            v = *reinterpret_cast<const uint4*>(&Ab[(size_t)grow * FI + c8]);
        *reinterpret_cast<uint4*>(&As[r * LDA + c8]) = v;
    }
    __syncthreads();

    const int w = t >> 6;
    const int l = t & 63;
    const int arow = (w << 4) + (l & 15);
    const int koff = (l >> 4) << 3;

    bf16x8 a[KB];
    #pragma unroll
    for (int kb = 0; kb < KB; ++kb)
        a[kb] = *reinterpret_cast<const bf16x8*>(&As[arow * LDA + kb * 32 + koff]);

    f32x4 acc[NB] = {};
    #pragma unroll
    for (int nb = 0; nb < NB; ++nb) {
        #pragma unroll
        for (int kb = 0; kb < KB; ++kb) {
            bf16x8 b = *reinterpret_cast<const bf16x8*>(&Wp[(size_t)((nb * KB + kb) * 64 + l) * 8]);
            acc[nb] = __builtin_amdgcn_mfma_f32_16x16x32_bf16(a[kb], b, acc[nb], 0, 0, 0);
        }
    }

    const int col = l & 15;
    const int rb = (l >> 4) << 2;
    #pragma unroll
    for (int r = 0; r < 4; ++r) {
        int grow = row0 + (w << 4) + rb + r;
        if (grow < n) {
            float s = MODE ? nd[grow] : 1.0f;
            #pragma unroll
            for (int nb = 0; nb < NB; ++nb) {
                float v = acc[nb][r];
                if (MODE) {
                    v = v * s + bias[nb * 16 + col];
                    v = LEAKY(v);
                    out16[(size_t)grow * FO + nb * 16 + col] = f2bf(v);
                    out8[(size_t)grow * FO + nb * 16 + col] = f2f8(v);
                } else {
                    out8[(size_t)grow * FO + nb * 16 + col] = f2f8(v);
                }
            }
        }
    }
}

// ---------------- mean over nodes (bf16 in, F=160), vectorized + LDS reduce ----------------
// 320 threads = 16 row-groups x 20 lanes; lane reads uint4 = 8 bf16.
__global__ __launch_bounds__(320) void mean_kernel(const unsigned short* __restrict__ h,
                                                   float* __restrict__ acc, int n) {
    __shared__ float lacc[160];
    int t = threadIdx.x;
    for (int j = t; j < 160; j += 320) lacc[j] = 0.0f;
    __syncthreads();
    int lane = t % 20;
    int rg = t / 20;
    float a0 = 0, a1 = 0, a2 = 0, a3 = 0, a4 = 0, a5 = 0, a6 = 0, a7 = 0;
    for (int i = blockIdx.x * 16 + rg; i < n; i += gridDim.x * 16) {
        uint4 v = *reinterpret_cast<const uint4*>(&h[(size_t)i * 160 + lane * 8]);
        a0 += bflo(v.x); a1 += bfhi(v.x);
        a2 += bflo(v.y); a3 += bfhi(v.y);
        a4 += bflo(v.z); a5 += bfhi(v.z);
        a6 += bflo(v.w); a7 += bfhi(v.w);
    }
    int c = lane * 8;
    atomicAdd(&lacc[c + 0], a0); atomicAdd(&lacc[c + 1], a1);
    atomicAdd(&lacc[c + 2], a2); atomicAdd(&lacc[c + 3], a3);
    atomicAdd(&lacc[c + 4], a4); atomicAdd(&lacc[c + 5], a5);
    atomicAdd(&lacc[c + 6], a6); atomicAdd(&lacc[c + 7], a7);
    __syncthreads();
    for (int j = t; j < 160; j += 320) atomicAdd(&acc[j], lacc[j]);
}

// ---------------- head ----------------
__global__ void head_kernel(const float* __restrict__ acc, const float* __restrict__ Wd1,
                            const float* __restrict__ bd1, const float* __restrict__ Wd2,
                            const float* __restrict__ bd2, float* __restrict__ out, int n) {
    __shared__ float gm[160];
    __shared__ float h1[140];
    int tid = threadIdx.x;
    if (tid < 160) {
        float v = acc[tid] / (float)n;
        gm[tid] = LEAKY(v);
    }
    __syncthreads();
    if (tid < 140) {
        float s = bd1[tid];
        for (int k = 0; k < 160; ++k) s += gm[k] * Wd1[k * 140 + tid];
        h1[tid] = LEAKY(s);
    }
    __syncthreads();
    if (tid < 2) {
        float s = bd2[tid];
        for (int k = 0; k < 140; ++k) s += h1[k] * Wd2[k * 2 + tid];
        out[tid] = 1.0f / (1.0f + expf(-s));
    }
}

extern "C" void kernel_launch(void* const* d_in, const int* in_sizes, int n_in,
                              void* d_out, int out_size, void* d_ws, size_t ws_size,
                              hipStream_t stream) {
    static const int dims[12] = {64, 80, 160, 112, 160, 176, 96, 144, 96, 128, 96, 160};

    const float* x     = (const float*)d_in[0];
    const int*   src   = (const int*)d_in[1];
    const int*   dst   = (const int*)d_in[2];
    const float* edata = (const float*)d_in[3];
    const float* W[11];
    const float* B[11];
    for (int i = 0; i < 11; ++i) {
        W[i] = (const float*)d_in[4 + 2 * i];
        B[i] = (const float*)d_in[5 + 2 * i];
    }
    const float* Wd1   = (const float*)d_in[26];
    const float* bd1   = (const float*)d_in[27];
    const float* Wd2   = (const float*)d_in[28];
    const float* bd2   = (const float*)d_in[29];
    const float* mu    = (const float*)d_in[30];
    const float* sigma = (const float*)d_in[31];
    float* out = (float*)d_out;

    const int N = in_sizes[0] / 64;
    const int E = in_sizes[1];
    const int FMAX = 176;

    const int NBK  = (N + BKN - 1) / BKN;
    const int NBLK = (E + EPB - 1) / EPB;
    const int LEN  = NBK * NBLK;

    size_t woff[11];
    size_t wtot = 0;
    for (int l = 0; l < 11; ++l) {
        woff[l] = wtot;
        int fip = (dims[l] + 31) / 32 * 32;
        wtot += (size_t)fip * dims[l + 1];
    }

    char* wsb = (char*)d_ws;
    size_t o = 0;
    auto alloc = [&](size_t bytes) { void* p = wsb + o; o += (bytes + 255) & ~(size_t)255; return p; };
    unsigned short* hb_main = (unsigned short*)alloc((size_t)N * FMAX * 2);
    unsigned short* hb_t    = (unsigned short*)alloc((size_t)N * FMAX * 2);
    unsigned char*  h8_main = (unsigned char*) alloc((size_t)N * FMAX);
    unsigned char*  h8_t    = (unsigned char*) alloc((size_t)N * FMAX);
    unsigned short* Wp  = (unsigned short*)alloc(wtot * 2);
    int2*  es      = (int2*) alloc((size_t)E * sizeof(int2));
    int2*  pay     = (int2*) alloc((size_t)E * sizeof(int2));
    unsigned char* srcb8 = (unsigned char*)alloc((size_t)E);
    int*   bh      = (int*)  alloc((size_t)(2 * LEN) * sizeof(int));
    int*   bhs     = (int*)  alloc((size_t)(2 * LEN + 1) * sizeof(int));
    int*   rowptr  = (int*)  alloc((size_t)(N + 1) * sizeof(int));
    float* ns      = (float*)alloc((size_t)N * sizeof(float));
    float* nd      = (float*)alloc((size_t)N * sizeof(float));
    int*   bsums   = (int*)  alloc(2048 * sizeof(int));
    float* acc     = (float*)alloc(160 * sizeof(float));

    // ---- bucket-sort CSR pipeline ----
    histo_kernel<<<NBLK, 512, 2 * NBK * sizeof(int), stream>>>(src, dst, bh, E, NBK, NBLK, LEN);
    int snb = (2 * LEN + SCAN_BLK - 1) / SCAN_BLK;
    scan1_kernel<<<snb, SCAN_BLK, 0, stream>>>(bh, bhs, bsums, 2 * LEN);
    scan2_kernel<<<1, SCAN_BLK, 0, stream>>>(bsums, snb);
    scan3_kernel<<<snb, SCAN_BLK, 0, stream>>>(bhs, bsums, 2 * LEN);
    scat_kernel<<<NBLK, 512, 2 * NBK * sizeof(int), stream>>>(src, dst, edata, mu, sigma,
                                                              bhs, srcb8, pay, E, NBK, NBLK, LEN);
    ns_kernel<<<NBK, 256, 0, stream>>>(srcb8, bhs, ns, N, NBLK);
    csr_kernel<<<NBK, 256, 0, stream>>>(pay, ns, bhs, rowptr, nd, es, N, E, NBK, NBLK, LEN);

    // ---- x -> bf16+fp8 ; W -> packed bf16 fragments ----
    long long x4 = (long long)N * 64 / 4;
    x2bf_kernel<<<(int)((x4 + 255) / 256), 256, 0, stream>>>(x, hb_main, h8_main, x4);
    for (int l = 0; l < 11; ++l) {
        int fip = (dims[l] + 31) / 32 * 32;
        int threads = (fip / 32) * (dims[l + 1] / 16) * 64;
        packW_kernel<<<(threads + 255) / 256, 256, 0, stream>>>(W[l], Wp + woff[l],
                                                                dims[l], dims[l + 1]);
    }

    // ---- 11 GCN layers (fixed buffer roles) ----
    const int mmgrid = (N + 63) / 64;

    #define DO_A(FI, FO, l) { \
        constexpr int jt = FI / 16; constexpr int ng = 256 / jt; \
        agg_kernel<0><<<(N + ng - 1) / ng, 256, 0, stream>>>( \
            h8_main, rowptr, es, nd, B[l], hb_t, nullptr, N, jt, ng); \
        mm_mfma_kernel<FI, FO, 1><<<mmgrid, 256, 0, stream>>>( \
            hb_t, nd, Wp + woff[l], B[l], hb_main, h8_main, N); }

    #define DO_B(FI, FO, l) { \
        mm_mfma_kernel<FI, FO, 0><<<mmgrid, 256, 0, stream>>>( \
            hb_main, nd, Wp + woff[l], B[l], nullptr, h8_t, N); \
        constexpr int jt = FO / 16; constexpr int ng = 256 / jt; \
        agg_kernel<1><<<(N + ng - 1) / ng, 256, 0, stream>>>( \
            h8_t, rowptr, es, nd, B[l], hb_main, h8_main, N, jt, ng); }

    DO_A(64, 80, 0)
    DO_A(80, 160, 1)
    DO_B(160, 112, 2)
    DO_A(112, 160, 3)
    DO_A(160, 176, 4)
    DO_B(176, 96, 5)
    DO_A(96, 144, 6)
    DO_B(144, 96, 7)
    DO_A(96, 128, 8)
    DO_B(128, 96, 9)
    DO_A(96, 160, 10)

    #undef DO_A
    #undef DO_B

    // ---- mean over nodes -> head ----
    hipMemsetAsync(acc, 0, 160 * sizeof(float), stream);
    mean_kernel<<<256, 320, 0, stream>>>(hb_main, acc, N);
    head_kernel<<<1, 256, 0, stream>>>(acc, Wd1, bd1, Wd2, bd2, out, N);
}

// Round 11
// 1198.816 us; speedup vs baseline: 16.2689x; 1.1230x over previous
//
#include <hip/hip_runtime.h>

#define LEAKY(v) ((v) > 0.0f ? (v) : 0.01f * (v))
#define SCAN_BLK 1024
#define EPB 8192          // edges per block in bucket pipeline
#define BKN 256           // nodes per bucket

typedef __bf16 bf16x8 __attribute__((ext_vector_type(8)));
typedef float f32x4 __attribute__((ext_vector_type(4)));

// ---------------- bf16 helpers (RNE) ----------------
__device__ inline float bflo(unsigned int u) { return __uint_as_float(u << 16); }
__device__ inline float bfhi(unsigned int u) { return __uint_as_float(u & 0xFFFF0000u); }
__device__ inline unsigned int pack2bf(float lo, float hi) {
    unsigned int a = __float_as_uint(lo);
    unsigned int b = __float_as_uint(hi);
    a = (a + 0x7FFFu + ((a >> 16) & 1u)) >> 16;
    b = (b + 0x7FFFu + ((b >> 16) & 1u)) & 0xFFFF0000u;
    return a | b;
}
__device__ inline unsigned short f2bf(float f) {
    unsigned int u = __float_as_uint(f);
    return (unsigned short)((u + 0x7FFFu + ((u >> 16) & 1u)) >> 16);
}

// ---------------- fp8 e4m3 helpers (HW cvt, OCP on gfx950) ----------------
__device__ inline unsigned char f2f8(float v) {
    return (unsigned char)(__builtin_amdgcn_cvt_pk_fp8_f32(v, 0.0f, 0u, false) & 0xFFu);
}

// fp8 row stride (bytes): keep every row inside whole 128B cache lines
constexpr int pad8(int F) { return (F <= 64) ? 64 : (F <= 128 ? 128 : 256); }

// ================= bucket-sort CSR pipeline (no global atomics) =================

__global__ void histo_kernel(const int* __restrict__ src, const int* __restrict__ dst,
                             int* __restrict__ bh, int E, int NBK, int NBLK, int LEN) {
    extern __shared__ int lds[];           // 2*NBK ints
    int* hs = lds;
    int* hd = lds + NBK;
    for (int j = threadIdx.x; j < 2 * NBK; j += 512) lds[j] = 0;
    __syncthreads();
    int b = blockIdx.x;
    int e0 = b * EPB, e1 = min(e0 + EPB, E);
    for (int e = e0 + threadIdx.x; e < e1; e += 512) {
        atomicAdd(&hs[src[e] >> 8], 1);
        atomicAdd(&hd[dst[e] >> 8], 1);
    }
    __syncthreads();
    for (int j = threadIdx.x; j < NBK; j += 512) {
        bh[j * NBLK + b] = hs[j];
        bh[LEN + j * NBLK + b] = hd[j];
    }
}

__global__ void scan1_kernel(const int* __restrict__ deg, int* __restrict__ out,
                             int* __restrict__ bsums, int n) {
    __shared__ int sh[SCAN_BLK];
    int gid = blockIdx.x * SCAN_BLK + threadIdx.x;
    int v = (gid < n) ? deg[gid] : 0;
    sh[threadIdx.x] = v;
    __syncthreads();
    for (int off = 1; off < SCAN_BLK; off <<= 1) {
        int t = (threadIdx.x >= off) ? sh[threadIdx.x - off] : 0;
        __syncthreads();
        sh[threadIdx.x] += t;
        __syncthreads();
    }
    if (gid < n) out[gid + 1] = sh[threadIdx.x];
    if (threadIdx.x == SCAN_BLK - 1) bsums[blockIdx.x] = sh[threadIdx.x];
    if (gid == 0) out[0] = 0;
}

__global__ void scan2_kernel(int* __restrict__ bsums, int nb) {
    __shared__ int sh[SCAN_BLK];
    int v = (threadIdx.x < nb) ? bsums[threadIdx.x] : 0;
    sh[threadIdx.x] = v;
    __syncthreads();
    for (int off = 1; off < SCAN_BLK; off <<= 1) {
        int t = (threadIdx.x >= off) ? sh[threadIdx.x - off] : 0;
        __syncthreads();
        sh[threadIdx.x] += t;
        __syncthreads();
    }
    if (threadIdx.x < nb) bsums[threadIdx.x] = sh[threadIdx.x] - v;
}

__global__ void scan3_kernel(int* __restrict__ out, const int* __restrict__ bsums, int n) {
    int gid = blockIdx.x * SCAN_BLK + threadIdx.x;
    if (gid < n) out[gid + 1] += bsums[blockIdx.x];
}

__global__ void scat_kernel(const int* __restrict__ src, const int* __restrict__ dst,
                            const float* __restrict__ edata,
                            const float* __restrict__ mu, const float* __restrict__ sigma,
                            const int* __restrict__ bhs, unsigned char* __restrict__ srcb8,
                            int2* __restrict__ pay, int E, int NBK, int NBLK, int LEN) {
    extern __shared__ int cur[];           // 2*NBK ints
    int* cs = cur;
    int* cd = cur + NBK;
    int b = blockIdx.x;
    for (int j = threadIdx.x; j < NBK; j += 512) {
        cs[j] = bhs[j * NBLK + b];
        cd[j] = bhs[LEN + j * NBLK + b] - E;
    }
    __syncthreads();
    int e0 = b * EPB, e1 = min(e0 + EPB, E);
    for (int e = e0 + threadIdx.x; e < e1; e += 512) {
        int s = src[e];
        int d = dst[e];
        float ed = edata[e];
        float dd = ed - mu[0];
        float w = (ed == 1.0f) ? ed : expf(-(dd * dd) / sigma[0]);
        int ps = atomicAdd(&cs[s >> 8], 1);
        srcb8[ps] = (unsigned char)(s & 255);
        int pd = atomicAdd(&cd[d >> 8], 1);
        pay[pd] = make_int2(s | ((d & 255) << 24), __float_as_int(w));
    }
}

__global__ void ns_kernel(const unsigned char* __restrict__ srcb8, const int* __restrict__ bhs,
                          float* __restrict__ ns, int n, int NBLK) {
    __shared__ int cnt[BKN];
    int b = blockIdx.x;
    int j = threadIdx.x;
    cnt[j] = 0;
    __syncthreads();
    int base = bhs[b * NBLK];
    int endp = bhs[(b + 1) * NBLK];
    for (int e = base + j; e < endp; e += 256)
        atomicAdd(&cnt[srcb8[e]], 1);
    __syncthreads();
    int node = b * BKN + j;
    if (node < n) {
        int c = cnt[j];
        ns[node] = (c > 0) ? rsqrtf((float)c) : 0.0f;
    }
}

__global__ void csr_kernel(const int2* __restrict__ pay, const float* __restrict__ ns,
                           const int* __restrict__ bhs, int* __restrict__ rowptr,
                           float* __restrict__ nd, int2* __restrict__ es,
                           int n, int E, int NBK, int NBLK, int LEN) {
    __shared__ int cnt[BKN];
    __shared__ int cur[BKN];
    int b = blockIdx.x;
    int j = threadIdx.x;
    cnt[j] = 0;
    __syncthreads();
    int base = bhs[LEN + b * NBLK] - E;
    int endp = bhs[LEN + (b + 1) * NBLK] - E;
    for (int e = base + j; e < endp; e += 256)
        atomicAdd(&cnt[(pay[e].x >> 24) & 255], 1);
    __syncthreads();
    int c0 = cnt[j];
    for (int off = 1; off < 256; off <<= 1) {
        int t = (j >= off) ? cnt[j - off] : 0;
        __syncthreads();
        cnt[j] += t;
        __syncthreads();
    }
    int excl = cnt[j] - c0;
    cur[j] = base + excl;
    int node = b * BKN + j;
    if (node < n) {
        rowptr[node] = base + excl;
        nd[node] = (c0 > 0) ? rsqrtf((float)c0) : 0.0f;
    }
    if (b == NBK - 1 && j == 0) rowptr[n] = E;
    __syncthreads();
    for (int e = base + j; e < endp; e += 256) {
        int2 p = pay[e];
        int s = p.x & 0x00FFFFFF;
        float coef = ns[s] * __int_as_float(p.y);
        int pos = atomicAdd(&cur[(p.x >> 24) & 255], 1);
        es[pos] = make_int2(s, __float_as_int(coef));
    }
}

// ================= dense compute =================

// x -> fp8 only (bf16 copy of x is never read)
__global__ void x2f8_kernel(const float* __restrict__ x, unsigned char* __restrict__ o8,
                            long long total4) {
    long long i = (long long)blockIdx.x * blockDim.x + threadIdx.x;
    if (i < total4) {
        float4 v = *reinterpret_cast<const float4*>(&x[i * 4]);
        unsigned int q = __builtin_amdgcn_cvt_pk_fp8_f32(v.x, v.y, 0u, false);
        q = __builtin_amdgcn_cvt_pk_fp8_f32(v.z, v.w, q, true);
        *reinterpret_cast<unsigned int*>(&o8[i * 4]) = q;
    }
}

__global__ void packW_kernel(const float* __restrict__ W, unsigned short* __restrict__ Wp,
                             int FI, int FO) {
    int KB = (FI + 31) / 32;
    int NB = FO / 16;
    int gid = blockIdx.x * blockDim.x + threadIdx.x;
    if (gid >= KB * NB * 64) return;
    int l = gid & 63;
    int tile = gid >> 6;
    int kb = tile % KB;
    int nb = tile / KB;
    int n = nb * 16 + (l & 15);
    int k0 = kb * 32 + (l >> 4) * 8;
    unsigned short tmp[8];
    #pragma unroll
    for (int j = 0; j < 8; ++j) {
        int k = k0 + j;
        tmp[j] = (k < FI) ? f2bf(W[(size_t)k * FO + n]) : (unsigned short)0;
    }
    *reinterpret_cast<uint4*>(&Wp[(size_t)gid * 8]) = *reinterpret_cast<uint4*>(tmp);
}

// ---------------- CSR gather-sum aggregation (fp8 in, padded stride) ----------------
#define F8ACC16(v, cc) { \
    auto q0 = __builtin_amdgcn_cvt_pk_f32_fp8((v).x, false); \
    auto q1 = __builtin_amdgcn_cvt_pk_f32_fp8((v).x, true);  \
    auto q2 = __builtin_amdgcn_cvt_pk_f32_fp8((v).y, false); \
    auto q3 = __builtin_amdgcn_cvt_pk_f32_fp8((v).y, true);  \
    auto q4 = __builtin_amdgcn_cvt_pk_f32_fp8((v).z, false); \
    auto q5 = __builtin_amdgcn_cvt_pk_f32_fp8((v).z, true);  \
    auto q6 = __builtin_amdgcn_cvt_pk_f32_fp8((v).w, false); \
    auto q7 = __builtin_amdgcn_cvt_pk_f32_fp8((v).w, true);  \
    a[0] = fmaf(q0[0], cc, a[0]);  a[1] = fmaf(q0[1], cc, a[1]); \
    a[2] = fmaf(q1[0], cc, a[2]);  a[3] = fmaf(q1[1], cc, a[3]); \
    a[4] = fmaf(q2[0], cc, a[4]);  a[5] = fmaf(q2[1], cc, a[5]); \
    a[6] = fmaf(q3[0], cc, a[6]);  a[7] = fmaf(q3[1], cc, a[7]); \
    a[8] = fmaf(q4[0], cc, a[8]);  a[9] = fmaf(q4[1], cc, a[9]); \
    a[10] = fmaf(q5[0], cc, a[10]); a[11] = fmaf(q5[1], cc, a[11]); \
    a[12] = fmaf(q6[0], cc, a[12]); a[13] = fmaf(q6[1], cc, a[13]); \
    a[14] = fmaf(q7[0], cc, a[14]); a[15] = fmaf(q7[1], cc, a[15]); }

// MODE 0: out16 = bf16(agg)         (dense row-major stride F)
// MODE 1: out16+out8 = leaky(agg*nd+b)  (out8 stride s8out)
template<int MODE>
__global__ void agg_kernel(const unsigned char* __restrict__ h8,
                           const int* __restrict__ rowptr, const int2* __restrict__ es,
                           const float* __restrict__ nd, const float* __restrict__ bias,
                           unsigned short* __restrict__ out16, unsigned char* __restrict__ out8,
                           int n, int jt, int ng, int s8in, int s8out) {
    int g = threadIdx.x / jt;
    if (g >= ng) return;
    int i = blockIdx.x * ng + g;
    if (i >= n) return;
    int c = (threadIdx.x - g * jt) << 4;   // feature offset (16 per lane)
    int F = jt << 4;
    int beg = rowptr[i], end = rowptr[i + 1];
    float a[16] = {};
    int e = beg;
    for (; e + 4 <= end; e += 4) {
        int2 e0 = es[e + 0], e1 = es[e + 1], e2 = es[e + 2], e3 = es[e + 3];
        uint4 v0 = *reinterpret_cast<const uint4*>(&h8[(size_t)e0.x * s8in + c]);
        uint4 v1 = *reinterpret_cast<const uint4*>(&h8[(size_t)e1.x * s8in + c]);
        uint4 v2 = *reinterpret_cast<const uint4*>(&h8[(size_t)e2.x * s8in + c]);
        uint4 v3 = *reinterpret_cast<const uint4*>(&h8[(size_t)e3.x * s8in + c]);
        float c0 = __int_as_float(e0.y), c1 = __int_as_float(e1.y);
        float c2 = __int_as_float(e2.y), c3 = __int_as_float(e3.y);
        F8ACC16(v0, c0)
        F8ACC16(v1, c1)
        F8ACC16(v2, c2)
        F8ACC16(v3, c3)
    }
    for (; e < end; ++e) {
        int2 e0 = es[e];
        uint4 v0 = *reinterpret_cast<const uint4*>(&h8[(size_t)e0.x * s8in + c]);
        float c0 = __int_as_float(e0.y);
        F8ACC16(v0, c0)
    }
    if (MODE) {
        float s = nd[i];
        #pragma unroll
        for (int j = 0; j < 16; ++j) {
            float v = a[j] * s + bias[c + j];
            a[j] = LEAKY(v);
        }
    }
    uint4 p0, p1;
    p0.x = pack2bf(a[0], a[1]);   p0.y = pack2bf(a[2], a[3]);
    p0.z = pack2bf(a[4], a[5]);   p0.w = pack2bf(a[6], a[7]);
    p1.x = pack2bf(a[8], a[9]);   p1.y = pack2bf(a[10], a[11]);
    p1.z = pack2bf(a[12], a[13]); p1.w = pack2bf(a[14], a[15]);
    *reinterpret_cast<uint4*>(&out16[(size_t)i * F + c]) = p0;
    *reinterpret_cast<uint4*>(&out16[(size_t)i * F + c + 8]) = p1;
    if (MODE) {
        uint4 q;
        q.x = __builtin_amdgcn_cvt_pk_fp8_f32(a[0], a[1], 0u, false);
        q.x = __builtin_amdgcn_cvt_pk_fp8_f32(a[2], a[3], q.x, true);
        q.y = __builtin_amdgcn_cvt_pk_fp8_f32(a[4], a[5], 0u, false);
        q.y = __builtin_amdgcn_cvt_pk_fp8_f32(a[6], a[7], q.y, true);
        q.z = __builtin_amdgcn_cvt_pk_fp8_f32(a[8], a[9], 0u, false);
        q.z = __builtin_amdgcn_cvt_pk_fp8_f32(a[10], a[11], q.z, true);
        q.w = __builtin_amdgcn_cvt_pk_fp8_f32(a[12], a[13], 0u, false);
        q.w = __builtin_amdgcn_cvt_pk_fp8_f32(a[14], a[15], q.w, true);
        *reinterpret_cast<uint4*>(&out8[(size_t)i * s8out + c]) = q;
    }
}

// ---------------- MFMA matmul: out[n x FO] = A[n x FI] @ W ----------------
// MODE 0: plain, fp8 out only (stride s8)
// MODE 1: fused leaky((A@W)*nd+b), bf16 + fp8 out
// MODE 2: fused leaky((A@W)*nd+b), bf16 out only
template<int FI, int FO, int MODE>
__global__ __launch_bounds__(256) void mm_mfma_kernel(
    const unsigned short* __restrict__ Ab, const float* __restrict__ nd,
    const unsigned short* __restrict__ Wp, const float* __restrict__ bias,
    unsigned short* __restrict__ out16, unsigned char* __restrict__ out8, int n, int s8)
{
    constexpr int FIP = (FI + 31) / 32 * 32;
    constexpr int KB = FIP / 32;
    constexpr int NB = FO / 16;
    constexpr int LDA = FIP + 8;
    constexpr int RW = FIP / 8;
    __shared__ unsigned short As[64 * LDA];

    const int t = threadIdx.x;
    const int row0 = blockIdx.x * 64;

    for (int idx = t; idx < 64 * RW; idx += 256) {
        int r = idx / RW;
        int c8 = (idx - r * RW) * 8;
        int grow = row0 + r;
        uint4 v = make_uint4(0u, 0u, 0u, 0u);
        if (grow < n && c8 < FI)
            v = *reinterpret_cast<const uint4*>(&Ab[(size_t)grow * FI + c8]);
        *reinterpret_cast<uint4*>(&As[r * LDA + c8]) = v;
    }
    __syncthreads();

    const int w = t >> 6;
    const int l = t & 63;
    const int arow = (w << 4) + (l & 15);
    const int koff = (l >> 4) << 3;

    bf16x8 a[KB];
    #pragma unroll
    for (int kb = 0; kb < KB; ++kb)
        a[kb] = *reinterpret_cast<const bf16x8*>(&As[arow * LDA + kb * 32 + koff]);

    f32x4 acc[NB] = {};
    #pragma unroll
    for (int nb = 0; nb < NB; ++nb) {
        #pragma unroll
        for (int kb = 0; kb < KB; ++kb) {
            bf16x8 b = *reinterpret_cast<const bf16x8*>(&Wp[(size_t)((nb * KB + kb) * 64 + l) * 8]);
            acc[nb] = __builtin_amdgcn_mfma_f32_16x16x32_bf16(a[kb], b, acc[nb], 0, 0, 0);
        }
    }

    const int col = l & 15;
    const int rb = (l >> 4) << 2;
    #pragma unroll
    for (int r = 0; r < 4; ++r) {
        int grow = row0 + (w << 4) + rb + r;
        if (grow < n) {
            float s = (MODE != 0) ? nd[grow] : 1.0f;
            #pragma unroll
            for (int nb = 0; nb < NB; ++nb) {
                float v = acc[nb][r];
                if (MODE != 0) {
                    v = v * s + bias[nb * 16 + col];
                    v = LEAKY(v);
                    out16[(size_t)grow * FO + nb * 16 + col] = f2bf(v);
                    if (MODE == 1)
                        out8[(size_t)grow * s8 + nb * 16 + col] = f2f8(v);
                } else {
                    out8[(size_t)grow * s8 + nb * 16 + col] = f2f8(v);
                }
            }
        }
    }
}

// ---------------- mean over nodes (bf16 in, F=160), vectorized + LDS reduce ----------------
__global__ __launch_bounds__(320) void mean_kernel(const unsigned short* __restrict__ h,
                                                   float* __restrict__ acc, int n) {
    __shared__ float lacc[160];
    int t = threadIdx.x;
    for (int j = t; j < 160; j += 320) lacc[j] = 0.0f;
    __syncthreads();
    int lane = t % 20;
    int rg = t / 20;
    float a0 = 0, a1 = 0, a2 = 0, a3 = 0, a4 = 0, a5 = 0, a6 = 0, a7 = 0;
    for (int i = blockIdx.x * 16 + rg; i < n; i += gridDim.x * 16) {
        uint4 v = *reinterpret_cast<const uint4*>(&h[(size_t)i * 160 + lane * 8]);
        a0 += bflo(v.x); a1 += bfhi(v.x);
        a2 += bflo(v.y); a3 += bfhi(v.y);
        a4 += bflo(v.z); a5 += bfhi(v.z);
        a6 += bflo(v.w); a7 += bfhi(v.w);
    }
    int c = lane * 8;
    atomicAdd(&lacc[c + 0], a0); atomicAdd(&lacc[c + 1], a1);
    atomicAdd(&lacc[c + 2], a2); atomicAdd(&lacc[c + 3], a3);
    atomicAdd(&lacc[c + 4], a4); atomicAdd(&lacc[c + 5], a5);
    atomicAdd(&lacc[c + 6], a6); atomicAdd(&lacc[c + 7], a7);
    __syncthreads();
    for (int j = t; j < 160; j += 320) atomicAdd(&acc[j], lacc[j]);
}

// ---------------- head ----------------
__global__ void head_kernel(const float* __restrict__ acc, const float* __restrict__ Wd1,
                            const float* __restrict__ bd1, const float* __restrict__ Wd2,
                            const float* __restrict__ bd2, float* __restrict__ out, int n) {
    __shared__ float gm[160];
    __shared__ float h1[140];
    int tid = threadIdx.x;
    if (tid < 160) {
        float v = acc[tid] / (float)n;
        gm[tid] = LEAKY(v);
    }
    __syncthreads();
    if (tid < 140) {
        float s = bd1[tid];
        for (int k = 0; k < 160; ++k) s += gm[k] * Wd1[k * 140 + tid];
        h1[tid] = LEAKY(s);
    }
    __syncthreads();
    if (tid < 2) {
        float s = bd2[tid];
        for (int k = 0; k < 140; ++k) s += h1[k] * Wd2[k * 2 + tid];
        out[tid] = 1.0f / (1.0f + expf(-s));
    }
}

extern "C" void kernel_launch(void* const* d_in, const int* in_sizes, int n_in,
                              void* d_out, int out_size, void* d_ws, size_t ws_size,
                              hipStream_t stream) {
    static const int dims[12] = {64, 80, 160, 112, 160, 176, 96, 144, 96, 128, 96, 160};

    const float* x     = (const float*)d_in[0];
    const int*   src   = (const int*)d_in[1];
    const int*   dst   = (const int*)d_in[2];
    const float* edata = (const float*)d_in[3];
    const float* W[11];
    const float* B[11];
    for (int i = 0; i < 11; ++i) {
        W[i] = (const float*)d_in[4 + 2 * i];
        B[i] = (const float*)d_in[5 + 2 * i];
    }
    const float* Wd1   = (const float*)d_in[26];
    const float* bd1   = (const float*)d_in[27];
    const float* Wd2   = (const float*)d_in[28];
    const float* bd2   = (const float*)d_in[29];
    const float* mu    = (const float*)d_in[30];
    const float* sigma = (const float*)d_in[31];
    float* out = (float*)d_out;

    const int N = in_sizes[0] / 64;
    const int E = in_sizes[1];
    const int FMAX = 176;

    const int NBK  = (N + BKN - 1) / BKN;
    const int NBLK = (E + EPB - 1) / EPB;
    const int LEN  = NBK * NBLK;

    size_t woff[11];
    size_t wtot = 0;
    for (int l = 0; l < 11; ++l) {
        woff[l] = wtot;
        int fip = (dims[l] + 31) / 32 * 32;
        wtot += (size_t)fip * dims[l + 1];
    }

    char* wsb = (char*)d_ws;
    size_t o = 0;
    auto alloc = [&](size_t bytes) { void* p = wsb + o; o += (bytes + 255) & ~(size_t)255; return p; };
    unsigned short* hb_main = (unsigned short*)alloc((size_t)N * FMAX * 2);
    unsigned short* hb_t    = (unsigned short*)alloc((size_t)N * FMAX * 2);
    unsigned char*  h8_main = (unsigned char*) alloc((size_t)N * 256);   // padded stride
    unsigned char*  h8_t    = (unsigned char*) alloc((size_t)N * 256);
    unsigned short* Wp  = (unsigned short*)alloc(wtot * 2);
    int2*  es      = (int2*) alloc((size_t)E * sizeof(int2));
    int2*  pay     = (int2*) alloc((size_t)E * sizeof(int2));
    unsigned char* srcb8 = (unsigned char*)alloc((size_t)E);
    int*   bh      = (int*)  alloc((size_t)(2 * LEN) * sizeof(int));
    int*   bhs     = (int*)  alloc((size_t)(2 * LEN + 1) * sizeof(int));
    int*   rowptr  = (int*)  alloc((size_t)(N + 1) * sizeof(int));
    float* ns      = (float*)alloc((size_t)N * sizeof(float));
    float* nd      = (float*)alloc((size_t)N * sizeof(float));
    int*   bsums   = (int*)  alloc(2048 * sizeof(int));
    float* acc     = (float*)alloc(160 * sizeof(float));

    // ---- bucket-sort CSR pipeline ----
    histo_kernel<<<NBLK, 512, 2 * NBK * sizeof(int), stream>>>(src, dst, bh, E, NBK, NBLK, LEN);
    int snb = (2 * LEN + SCAN_BLK - 1) / SCAN_BLK;
    scan1_kernel<<<snb, SCAN_BLK, 0, stream>>>(bh, bhs, bsums, 2 * LEN);
    scan2_kernel<<<1, SCAN_BLK, 0, stream>>>(bsums, snb);
    scan3_kernel<<<snb, SCAN_BLK, 0, stream>>>(bhs, bsums, 2 * LEN);
    scat_kernel<<<NBLK, 512, 2 * NBK * sizeof(int), stream>>>(src, dst, edata, mu, sigma,
                                                              bhs, srcb8, pay, E, NBK, NBLK, LEN);
    ns_kernel<<<NBK, 256, 0, stream>>>(srcb8, bhs, ns, N, NBLK);
    csr_kernel<<<NBK, 256, 0, stream>>>(pay, ns, bhs, rowptr, nd, es, N, E, NBK, NBLK, LEN);

    // ---- x -> fp8 (stride 64 == F, line-safe) ; W -> packed bf16 fragments ----
    long long x4 = (long long)N * 64 / 4;
    x2f8_kernel<<<(int)((x4 + 255) / 256), 256, 0, stream>>>(x, h8_main, x4);
    for (int l = 0; l < 11; ++l) {
        int fip = (dims[l] + 31) / 32 * 32;
        int threads = (fip / 32) * (dims[l + 1] / 16) * 64;
        packW_kernel<<<(threads + 255) / 256, 256, 0, stream>>>(W[l], Wp + woff[l],
                                                                dims[l], dims[l + 1]);
    }

    // ---- 11 GCN layers ----
    const int mmgrid = (N + 63) / 64;

    // order A (FO >= FI): agg gathers h8_main (stride pad8(FI)) -> hb_t;
    //   mm fused epilogue -> hb_main (+ h8_main stride pad8(FO) iff next layer gathers it)
    #define DO_A(FI, FO, l, MM)  { \
        constexpr int jt = FI / 16; constexpr int ng = 256 / jt; \
        agg_kernel<0><<<(N + ng - 1) / ng, 256, 0, stream>>>( \
            h8_main, rowptr, es, nd, B[l], hb_t, nullptr, N, jt, ng, pad8(FI), 0); \
        mm_mfma_kernel<FI, FO, MM><<<mmgrid, 256, 0, stream>>>( \
            hb_t, nd, Wp + woff[l], B[l], hb_main, h8_main, N, pad8(FO)); }

    // order B (FO < FI): mm plain -> h8_t (stride pad8(FO));
    //   agg fused epilogue -> hb_main + h8_main (stride pad8(FO))
    #define DO_B(FI, FO, l) { \
        mm_mfma_kernel<FI, FO, 0><<<mmgrid, 256, 0, stream>>>( \
            hb_main, nd, Wp + woff[l], B[l], nullptr, h8_t, N, pad8(FO)); \
        constexpr int jt = FO / 16; constexpr int ng = 256 / jt; \
        agg_kernel<1><<<(N + ng - 1) / ng, 256, 0, stream>>>( \
            h8_t, rowptr, es, nd, B[l], hb_main, h8_main, N, jt, ng, pad8(FO), pad8(FO)); }

    DO_A(64, 80, 0, 1)      // next L1 is A: write fp8
    DO_A(80, 160, 1, 2)     // next L2 is B: bf16 only
    DO_B(160, 112, 2)
    DO_A(112, 160, 3, 1)    // next L4 is A
    DO_A(160, 176, 4, 2)    // next L5 is B
    DO_B(176, 96, 5)
    DO_A(96, 144, 6, 2)     // next L7 is B
    DO_B(144, 96, 7)
    DO_A(96, 128, 8, 2)     // next L9 is B
    DO_B(128, 96, 9)
    DO_A(96, 160, 10, 2)    // next is mean: bf16 only

    #undef DO_A
    #undef DO_B

    // ---- mean over nodes -> head ----
    hipMemsetAsync(acc, 0, 160 * sizeof(float), stream);
    mean_kernel<<<256, 320, 0, stream>>>(hb_main, acc, N);
    head_kernel<<<1, 256, 0, stream>>>(acc, Wd1, bd1, Wd2, bd2, out, N);
}